// Round 1
// baseline (794.568 us; speedup 1.0000x reference)
//
#include <hip/hip_runtime.h>
#include <math.h>

// Problem constants: B=8, C=64, H=W=192, HW=36864, MODES=32, NB=4, BS=16, E=16
#define TPI 6.283185307179586f

__device__ __forceinline__ float gelu_f(float v){
  return 0.5f*v*(1.0f+erff(v*0.7071067811865475f));
}

// ---------------- GroupNorm stats (8 groups of 8 channels) ----------------
// 512 blocks: blk = group*8 + chunk; each reduces 36864 contiguous floats.
__global__ __launch_bounds__(256) void gn_partial(const float* __restrict__ x, float* __restrict__ part){
  int blk = blockIdx.x;
  const float4* p4 = (const float4*)(x + blk*36864);
  float s=0.f, ss=0.f;
  for(int i=threadIdx.x;i<9216;i+=256){
    float4 v=p4[i];
    s+=v.x+v.y+v.z+v.w;
    ss+=v.x*v.x+v.y*v.y+v.z*v.z+v.w*v.w;
  }
  #pragma unroll
  for(int o=32;o>0;o>>=1){ s+=__shfl_down(s,o); ss+=__shfl_down(ss,o); }
  __shared__ float ls[4], lss[4];
  int wid=threadIdx.x>>6;
  if((threadIdx.x&63)==0){ ls[wid]=s; lss[wid]=ss; }
  __syncthreads();
  if(threadIdx.x==0){
    float S=0,SS=0;
    for(int i=0;i<4;i++){S+=ls[i];SS+=lss[i];}
    part[blk*2]=S; part[blk*2+1]=SS;
  }
}

// 64 threads: one per (b, group). Emit per-channel scale/bias (b*64+c).
__global__ void gn_finalize(const float* __restrict__ part, const float* __restrict__ gw,
                            const float* __restrict__ gb, float2* __restrict__ sb){
  int g=threadIdx.x; if(g>=64) return;
  float S=0,SS=0;
  for(int j=0;j<8;j++){ S+=part[(g*8+j)*2]; SS+=part[(g*8+j)*2+1]; }
  const float inv=1.0f/294912.0f;
  float mean=S*inv, var=SS*inv-mean*mean;
  float rstd=rsqrtf(var+1e-5f);
  int b=g>>3, gg=g&7;
  for(int k=0;k<8;k++){
    int c=gg*8+k;
    float sc=rstd*gw[c];
    sb[b*64+c]=make_float2(sc, gb[c]-mean*sc);
  }
}

// ---------------- forward W-DFT: per (b,c,h) row, 192 -> 32 complex -------
// XW layout: [(b*64+c)*32 + kw]*192 + h   (float2)
__global__ __launch_bounds__(256) void wdft(const float* __restrict__ x, const float2* __restrict__ sb,
                                            float2* __restrict__ XW){
  __shared__ float ct[192], st[192];
  __shared__ float xl[8][192];
  int t=threadIdx.x;
  if(t<192){ float a=(float)t*(TPI/192.0f); ct[t]=cosf(a); st[t]=sinf(a); }
  int r = blockIdx.x*8 + (t>>5);      // (b*64+c)*192 + h
  int lane = t&31;
  int bc = r/192; int h = r - bc*192;
  float2 s = sb[bc];
  const float* xp = x + bc*36864 + h*192;
  float* xrow = xl[t>>5];
  #pragma unroll
  for(int j=0;j<6;j++){ int w=lane+32*j; xrow[w]=xp[w]*s.x+s.y; }
  __syncthreads();
  int kw=lane;
  float ar=0.f, ai=0.f; int idx=0;
  for(int w=0;w<192;w++){
    float xv=xrow[w];
    ar=fmaf(xv, ct[idx], ar);
    ai=fmaf(xv,-st[idx], ai);
    idx+=kw; if(idx>=192) idx-=192;
  }
  XW[(bc*32+kw)*192 + h]=make_float2(ar,ai);
}

// ---------------- forward H-DFT: per (b,c,kw), 192 -> 32 complex ----------
// Xm layout: [((b*32+kh)*32+kw)*64 + c]  (float2), scaled by 1/192 (ortho fwd)
__global__ __launch_bounds__(256) void hdft(const float2* __restrict__ XW, float2* __restrict__ Xm){
  __shared__ float ct[192], st[192];
  __shared__ float2 xl[8][192];
  int t=threadIdx.x;
  if(t<192){ float a=(float)t*(TPI/192.0f); ct[t]=cosf(a); st[t]=sinf(a); }
  int r = blockIdx.x*8 + (t>>5);      // (b*64+c)*32 + kw
  int lane=t&31;
  const float2* xp = XW + r*192;
  float2* xrow = xl[t>>5];
  #pragma unroll
  for(int j=0;j<6;j++){ int h=lane+32*j; xrow[h]=xp[h]; }
  __syncthreads();
  int kh=lane;
  float ar=0.f, ai=0.f; int idx=0;
  for(int h=0;h<192;h++){
    float2 v=xrow[h];
    // (vx + i vy) * e^{-i th} = (vx*c + vy*s) + i(vy*c - vx*s)
    ar=fmaf(v.x, ct[idx], fmaf(v.y, st[idx], ar));
    ai=fmaf(v.y, ct[idx], fmaf(-v.x, st[idx], ai));
    idx+=kh; if(idx>=192) idx-=192;
  }
  int kw=r&31, bc=r>>5, c=bc&63, b=bc>>6;
  const float sc=1.0f/192.0f;
  Xm[((b*32+kh)*32+kw)*64 + c]=make_float2(ar*sc, ai*sc);
}

// ---------------- block-diagonal complex 2-layer MLP on modes -------------
// 4 positions per 256-thread block; 64 threads/position: n=tl>>4, o=tl&15.
__global__ __launch_bounds__(256) void mode_mlp(const float2* __restrict__ Xm,
    const float* __restrict__ w1, const float* __restrict__ b1,
    const float* __restrict__ w2, const float* __restrict__ b2,
    float2* __restrict__ S){
  __shared__ float w10[1024], w11[1024], w20[1024], w21[1024];
  __shared__ float b10[64], b11[64], b20[64], b21[64];
  __shared__ float xr[4][64], xi[4][64], o1r[4][64], o1i[4][64];
  int t=threadIdx.x;
  for(int i=t;i<1024;i+=256){ w10[i]=w1[i]; w11[i]=w1[1024+i]; w20[i]=w2[i]; w21[i]=w2[1024+i]; }
  if(t<64){ b10[t]=b1[t]; b11[t]=b1[64+t]; b20[t]=b2[t]; b21[t]=b2[64+t]; }
  int p=t>>6, tl=t&63;
  int pos=blockIdx.x*4+p;
  float2 v=Xm[pos*64+tl];
  xr[p][tl]=v.x; xi[p][tl]=v.y;
  __syncthreads();
  int n=tl>>4, o=tl&15;
  int wb=n*256+o;
  float a_r=b10[tl], a_i=b11[tl];
  #pragma unroll
  for(int i=0;i<16;i++){
    float rr=xr[p][n*16+i], im=xi[p][n*16+i];
    float W0=w10[wb+i*16], W1=w11[wb+i*16];
    a_r=fmaf(rr,W0,fmaf(-im,W1,a_r));
    a_i=fmaf(im,W0,fmaf( rr,W1,a_i));
  }
  o1r[p][tl]=gelu_f(a_r); o1i[p][tl]=gelu_f(a_i);
  __syncthreads();
  float c_r=b20[tl], c_i=b21[tl];
  #pragma unroll
  for(int i=0;i<16;i++){
    float rr=o1r[p][n*16+i], im=o1i[p][n*16+i];
    float W0=w20[wb+i*16], W1=w21[wb+i*16];
    c_r=fmaf(rr,W0,fmaf(-im,W1,c_r));
    c_i=fmaf(im,W0,fmaf( rr,W1,c_i));
  }
  S[pos*64+tl]=make_float2(c_r,c_i);
}

// ---------------- inverse H (complex ifft over 32 kept modes) -------------
// G layout: [(b*64+c)*32 + kw]*192 + h  (float2)
__global__ __launch_bounds__(192) void ihdft(const float2* __restrict__ S, float2* __restrict__ G){
  __shared__ float ct[192], st[192];
  __shared__ float2 sv[32];
  int t=threadIdx.x;
  if(t<192){ float a=(float)t*(TPI/192.0f); ct[t]=cosf(a); st[t]=sinf(a); }
  int r=blockIdx.x;                    // (b*64+c)*32 + kw
  int kw=r&31, bc=r>>5, c=bc&63, b=bc>>6;
  if(t<32) sv[t]=S[((b*32+t)*32+kw)*64+c];
  __syncthreads();
  int h=t;
  float ar=0.f, ai=0.f; int idx=0;
  #pragma unroll
  for(int kh=0;kh<32;kh++){
    float2 v=sv[kh];
    // (vx + i vy) * e^{+i th}
    ar=fmaf(v.x, ct[idx], fmaf(-v.y, st[idx], ar));
    ai=fmaf(v.y, ct[idx], fmaf( v.x, st[idx], ai));
    idx+=h; if(idx>=192) idx-=192;
  }
  G[r*192+h]=make_float2(ar,ai);
}

// ---------------- inverse W (c2r) + AFNO residual + outer residual --------
// h2[b,c,h,w] = irfft_val + (x*sc1+bi1) + x      (h2 stored in d_out)
__global__ __launch_bounds__(256) void iwdft(const float2* __restrict__ G, const float* __restrict__ x,
                                             const float2* __restrict__ sb, float* __restrict__ h2){
  __shared__ float ct[192], st[192];
  __shared__ float gr[32][32], gi[32][32];   // [kw][hh]
  int t=threadIdx.x;
  if(t<192){ float a=(float)t*(TPI/192.0f); ct[t]=cosf(a); st[t]=sinf(a); }
  int blk=blockIdx.x; int bc=blk/6; int ht=blk-bc*6; int h0=ht*32;
  for(int i=t;i<1024;i+=256){
    int kw=i>>5, hh=i&31;
    float2 v=G[(bc*32+kw)*192 + h0+hh];
    gr[kw][hh]=v.x; gi[kw][hh]=v.y;
  }
  float2 s=sb[bc];
  __syncthreads();
  for(int j=0;j<24;j++){
    int p=t+256*j;
    int hh=p/192; int w=p-hh*192;
    float acc=0.5f*gr[0][hh];            // DC column counted once, Re only (c2r)
    int idx=0;
    #pragma unroll 4
    for(int k=1;k<32;k++){
      idx+=w; if(idx>=192) idx-=192;
      acc=fmaf(gr[k][hh], ct[idx], fmaf(-gi[k][hh], st[idx], acc));
    }
    acc*=(2.0f/192.0f);
    int gaddr=bc*36864 + h0*192 + p;
    float xv=x[gaddr];
    h2[gaddr]=acc + (xv*s.x+s.y) + xv;
  }
}

// ---------------- feats = gelu(fe_w @ gn2(h2) + fe_b), BHWC layout --------
__global__ __launch_bounds__(256) void feats_k(const float* __restrict__ h2, const float2* __restrict__ sb,
                                               const float* __restrict__ fw, const float* __restrict__ fb,
                                               float* __restrict__ feats){
  __shared__ float ft[64*66];
  __shared__ float wt[64*72];
  __shared__ float bias[64];
  int t=threadIdx.x;
  int blk=blockIdx.x; int b=blk/576; int tile=blk-b*576; int hw0=tile*64;
  {
    int c0=t>>6, px=t&63;
    for(int cc=c0;cc<64;cc+=4){
      float2 s=sb[b*64+cc];
      ft[cc*66+px]=h2[(b*64+cc)*36864 + hw0+px]*s.x + s.y;
    }
  }
  for(int i=t;i<4096;i+=256){ int oc=i>>6, c=i&63; wt[c*72+oc]=fw[i]; }
  if(t<64) bias[t]=fb[t];
  __syncthreads();
  int ocg=t>>5, pxp=t&31;
  int oc0=ocg*8, px=pxp*2;
  float acc0[8]={}, acc1[8]={};
  for(int c=0;c<64;c++){
    float2 xv=*(const float2*)&ft[c*66+px];
    float w8[8];
    *(float4*)&w8[0]=*(const float4*)&wt[c*72+oc0];
    *(float4*)&w8[4]=*(const float4*)&wt[c*72+oc0+4];
    #pragma unroll
    for(int k=0;k<8;k++){ acc0[k]=fmaf(xv.x,w8[k],acc0[k]); acc1[k]=fmaf(xv.y,w8[k],acc1[k]); }
  }
  float v0[8], v1[8];
  #pragma unroll
  for(int k=0;k<8;k++){ v0[k]=gelu_f(acc0[k]+bias[oc0+k]); v1[k]=gelu_f(acc1[k]+bias[oc0+k]); }
  float4* o0=(float4*)&feats[(b*36864+hw0+px)*64+oc0];
  o0[0]=make_float4(v0[0],v0[1],v0[2],v0[3]); o0[1]=make_float4(v0[4],v0[5],v0[6],v0[7]);
  float4* o1=(float4*)&feats[(b*36864+hw0+px+1)*64+oc0];
  o1[0]=make_float4(v1[0],v1[1],v1[2],v1[3]); o1[1]=make_float4(v1[4],v1[5],v1[6],v1[7]);
}

// ---------------- gf partial sums: mean of feats over HW ------------------
__global__ __launch_bounds__(256) void gf_part(const float* __restrict__ feats, float* __restrict__ gfp){
  int blk=blockIdx.x; int b=blk/36; int ch=blk-b*36;
  int t=threadIdx.x; int c=t&63; int pg=t>>6;
  float s=0.f;
  for(int j=0;j<256;j++){
    int px=ch*1024 + pg + 4*j;
    s+=feats[(b*36864+px)*64+c];
  }
  __shared__ float red[4][64];
  red[pg][c]=s; __syncthreads();
  if(t<64) gfp[blk*64+t]=red[0][t]+red[1][t]+red[2][t]+red[3][t];
}

// ---------------- gating MLP + top-4 softmax (single block) ---------------
__global__ __launch_bounds__(128) void gating(const float* __restrict__ gfp,
  const float* __restrict__ g1w, const float* __restrict__ g1b,
  const float* __restrict__ bn1g, const float* __restrict__ bn1b, const float* __restrict__ bn1m, const float* __restrict__ bn1v,
  const float* __restrict__ cw1, const float* __restrict__ cb1, const float* __restrict__ cw2, const float* __restrict__ cb2,
  const float* __restrict__ g2w, const float* __restrict__ g2b,
  const float* __restrict__ bn2g, const float* __restrict__ bn2b, const float* __restrict__ bn2m, const float* __restrict__ bn2v,
  const float* __restrict__ g3w, const float* __restrict__ g3b, float* __restrict__ gate){
  __shared__ float gf[8][64];
  __shared__ float h1[8][128];
  __shared__ float a1[8][8];
  __shared__ float h2g[8][64];
  __shared__ float sc[8][16];
  int t=threadIdx.x;
  for(int i=t;i<512;i+=128){
    int b=i>>6, c=i&63; float s=0.f;
    for(int ch=0;ch<36;ch++) s+=gfp[(b*36+ch)*64+c];
    gf[b][c]=s*(1.0f/36864.0f);
  }
  __syncthreads();
  for(int i=t;i<1024;i+=128){
    int b=i>>7, j=i&127;
    float s=g1b[j];
    for(int c=0;c<64;c++) s=fmaf(gf[b][c], g1w[j*64+c], s);
    s=(s-bn1m[j])*rsqrtf(bn1v[j]+1e-5f)*bn1g[j]+bn1b[j];
    h1[b][j]=gelu_f(s);
  }
  __syncthreads();
  if(t<64){
    int b=t>>3, k=t&7; float s=cb1[k];
    for(int j=0;j<128;j++) s=fmaf(h1[b][j], cw1[k*128+j], s);
    a1[b][k]=gelu_f(s);
  }
  __syncthreads();
  for(int i=t;i<1024;i+=128){
    int b=i>>7, j=i&127;
    float s=cb2[j];
    for(int k=0;k<8;k++) s=fmaf(a1[b][k], cw2[j*8+k], s);
    h1[b][j]=h1[b][j]/(1.0f+expf(-2.0f*s));
  }
  __syncthreads();
  for(int i=t;i<512;i+=128){
    int b=i>>6, j=i&63;
    float s=g2b[j];
    for(int k=0;k<128;k++) s=fmaf(h1[b][k], g2w[j*128+k], s);
    s=(s-bn2m[j])*rsqrtf(bn2v[j]+1e-5f)*bn2g[j]+bn2b[j];
    h2g[b][j]=gelu_f(s);
  }
  __syncthreads();
  {
    int b=t>>4, e=t&15;
    float s=g3b[e];
    for(int c=0;c<64;c++) s=fmaf(h2g[b][c], g3w[e*64+c], s);
    sc[b][e]=s;
  }
  __syncthreads();
  if(t<8){
    int b=t;
    float v[16], out[16];
    for(int e=0;e<16;e++){ v[e]=sc[b][e]; out[e]=0.0f; }
    float vals[4]; int idx[4];
    for(int k=0;k<4;k++){
      float best=-1e30f; int bi=0;
      for(int e=0;e<16;e++) if(v[e]>best){best=v[e];bi=e;}
      vals[k]=best; idx[k]=bi; v[bi]=-1e30f;
    }
    float m=vals[0], ssum=0.f, w[4];
    for(int k=0;k<4;k++){ w[k]=expf((vals[k]-m)*0.5f); ssum+=w[k]; }
    for(int k=0;k<4;k++) out[idx[k]]=w[k]/ssum;
    for(int e=0;e<16;e++) gate[b*16+e]=out[e];
  }
}

// ---------------- shared experts + gated experts + residual ---------------
// out[b,c,hw] = sum_s gelu(Ws f + bs)/2 + sum_{e: g!=0} g*gelu(We f + be) + h2
__global__ __launch_bounds__(256) void final_k(const float* __restrict__ feats, const float* __restrict__ h2,
  const float* __restrict__ shw, const float* __restrict__ shb,
  const float* __restrict__ exw, const float* __restrict__ exb,
  const float* __restrict__ gate, float* __restrict__ out){
  __shared__ float ft[64*66];
  __shared__ float wt[64*72];
  __shared__ float bias[64];
  int t=threadIdx.x;
  int blk=blockIdx.x; int b=blk/576; int tile=blk-b*576; int hw0=tile*64;
  for(int i=t;i<4096;i+=256){ int px=i>>6, c=i&63; ft[c*66+px]=feats[(b*36864+hw0+px)*64+c]; }
  int ocg=t>>5, pxp=t&31;
  int oc0=ocg*8, px=pxp*2;
  float oa0[8]={}, oa1[8]={};
  for(int term=0;term<18;term++){
    float g; const float* wsrc; const float* bsrc;
    if(term<2){ g=0.5f; wsrc=shw+term*4096; bsrc=shb+term*64; }
    else { int e=term-2; g=gate[b*16+e]; wsrc=exw+e*4096; bsrc=exb+e*64; }
    if(g==0.0f) continue;                   // block-uniform branch
    __syncthreads();
    for(int i=t;i<4096;i+=256){ int oc=i>>6, c=i&63; wt[c*72+oc]=wsrc[i]; }
    if(t<64) bias[t]=bsrc[t];
    __syncthreads();
    float acc0[8]={}, acc1[8]={};
    for(int c=0;c<64;c++){
      float2 xv=*(const float2*)&ft[c*66+px];
      float w8[8];
      *(float4*)&w8[0]=*(const float4*)&wt[c*72+oc0];
      *(float4*)&w8[4]=*(const float4*)&wt[c*72+oc0+4];
      #pragma unroll
      for(int k=0;k<8;k++){ acc0[k]=fmaf(xv.x,w8[k],acc0[k]); acc1[k]=fmaf(xv.y,w8[k],acc1[k]); }
    }
    #pragma unroll
    for(int k=0;k<8;k++){
      oa0[k]=fmaf(g, gelu_f(acc0[k]+bias[oc0+k]), oa0[k]);
      oa1[k]=fmaf(g, gelu_f(acc1[k]+bias[oc0+k]), oa1[k]);
    }
  }
  #pragma unroll
  for(int k=0;k<8;k++){
    int base=(b*64+oc0+k)*36864 + hw0 + px;
    float2 r=*(const float2*)&h2[base];
    float2 o; o.x=oa0[k]+r.x; o.y=oa1[k]+r.y;
    *(float2*)&out[base]=o;
  }
}

extern "C" void kernel_launch(void* const* d_in, const int* in_sizes, int n_in,
                              void* d_out, int out_size, void* d_ws, size_t ws_size,
                              hipStream_t stream){
  const float* x    =(const float*)d_in[0];
  const float* gn1w =(const float*)d_in[1];
  const float* gn1b =(const float*)d_in[2];
  const float* aw1  =(const float*)d_in[3];
  const float* ab1  =(const float*)d_in[4];
  const float* aw2  =(const float*)d_in[5];
  const float* ab2  =(const float*)d_in[6];
  const float* gn2w =(const float*)d_in[7];
  const float* gn2b =(const float*)d_in[8];
  const float* few  =(const float*)d_in[9];
  const float* feb  =(const float*)d_in[10];
  const float* g1w  =(const float*)d_in[11];
  const float* g1b  =(const float*)d_in[12];
  const float* bn1g =(const float*)d_in[13];
  const float* bn1b =(const float*)d_in[14];
  const float* bn1m =(const float*)d_in[15];
  const float* bn1v =(const float*)d_in[16];
  const float* cw1  =(const float*)d_in[17];
  const float* cb1  =(const float*)d_in[18];
  const float* cw2  =(const float*)d_in[19];
  const float* cb2  =(const float*)d_in[20];
  const float* g2w  =(const float*)d_in[21];
  const float* g2b  =(const float*)d_in[22];
  const float* bn2g =(const float*)d_in[23];
  const float* bn2b =(const float*)d_in[24];
  const float* bn2m =(const float*)d_in[25];
  const float* bn2v =(const float*)d_in[26];
  const float* g3w  =(const float*)d_in[27];
  const float* g3b  =(const float*)d_in[28];
  const float* shw  =(const float*)d_in[29];
  const float* shb  =(const float*)d_in[30];
  const float* exw  =(const float*)d_in[31];
  const float* exb  =(const float*)d_in[32];

  float* out=(float*)d_out;
  float* ws=(float*)d_ws;

  // workspace layout (float offsets)
  float*  part1 = ws;                         // 1024
  float*  part2 = ws+1024;                    // 1024
  float2* sb1   = (float2*)(ws+2048);         // 512 float2
  float2* sb2   = (float2*)(ws+3072);         // 512 float2
  float*  gate  = ws+4096;                    // 128
  float*  gfp   = ws+4224;                    // 18432
  float2* Xm    = (float2*)(ws+22656);        // 524288 float2
  float2* S     = (float2*)(ws+22656+1048576);// 524288 float2
  float2* XW    = (float2*)(ws+22656+2097152);// 3145728 float2 (reused as G)
  float*  feats = ws+8411264;                 // 18874368  -> total ~109 MB

  // GN1 stats
  gn_partial <<<512,256,0,stream>>>(x, part1);
  gn_finalize<<<1,64,0,stream>>>(part1, gn1w, gn1b, sb1);
  // AFNO: truncated 2D DFT -> block MLP -> truncated inverse + residuals
  wdft   <<<12288,256,0,stream>>>(x, sb1, XW);
  hdft   <<<2048,256,0,stream>>>(XW, Xm);
  mode_mlp<<<2048,256,0,stream>>>(Xm, aw1, ab1, aw2, ab2, S);
  ihdft  <<<16384,192,0,stream>>>(S, XW);          // G overlays XW
  iwdft  <<<3072,256,0,stream>>>(XW, x, sb1, out); // h2 lives in d_out
  // GN2 stats on h2
  gn_partial <<<512,256,0,stream>>>(out, part2);
  gn_finalize<<<1,64,0,stream>>>(part2, gn2w, gn2b, sb2);
  // feature extractor (BHWC feats)
  feats_k<<<4608,256,0,stream>>>(out, sb2, few, feb, feats);
  // gate
  gf_part<<<288,256,0,stream>>>(feats, gfp);
  gating <<<1,128,0,stream>>>(gfp, g1w,g1b, bn1g,bn1b,bn1m,bn1v,
                              cw1,cb1,cw2,cb2, g2w,g2b, bn2g,bn2b,bn2m,bn2v,
                              g3w,g3b, gate);
  // shared + active experts + residual (in-place on d_out)
  final_k<<<4608,256,0,stream>>>(feats, out, shw, shb, exw, exb, gate, out);
}

// Round 2
// 437.788 us; speedup vs baseline: 1.8150x; 1.8150x over previous
//
#include <hip/hip_runtime.h>
#include <math.h>

// Problem constants: B=8, C=64, H=W=192, HW=36864, MODES=32, NB=4, BS=16, E=16
#define TPI 6.283185307179586f

typedef __attribute__((ext_vector_type(8))) short bf8v;   // 8 bf16 (4 VGPRs)
typedef __attribute__((ext_vector_type(4))) float f4v;    // 4 fp32 acc

__device__ __forceinline__ float gelu_f(float v){
  return 0.5f*v*(1.0f+erff(v*0.7071067811865475f));
}
__device__ __forceinline__ unsigned short f2b(float f){   // f32 -> bf16 (RNE)
  union{float f; unsigned u;} v; v.f=f;
  unsigned r=v.u + 0x7FFFu + ((v.u>>16)&1u);
  return (unsigned short)(r>>16);
}
__device__ __forceinline__ float b2f(unsigned short h){
  union{unsigned u; float f;} v; v.u=((unsigned)h)<<16; return v.f;
}

// ---------------- GroupNorm stats (8 groups of 8 channels) ----------------
__global__ __launch_bounds__(256) void gn_partial(const float* __restrict__ x, float* __restrict__ part){
  int blk = blockIdx.x;
  const float4* p4 = (const float4*)(x + blk*36864);
  float s=0.f, ss=0.f;
  for(int i=threadIdx.x;i<9216;i+=256){
    float4 v=p4[i];
    s+=v.x+v.y+v.z+v.w;
    ss+=v.x*v.x+v.y*v.y+v.z*v.z+v.w*v.w;
  }
  #pragma unroll
  for(int o=32;o>0;o>>=1){ s+=__shfl_down(s,o); ss+=__shfl_down(ss,o); }
  __shared__ float ls[4], lss[4];
  int wid=threadIdx.x>>6;
  if((threadIdx.x&63)==0){ ls[wid]=s; lss[wid]=ss; }
  __syncthreads();
  if(threadIdx.x==0){
    float S=0,SS=0;
    for(int i=0;i<4;i++){S+=ls[i];SS+=lss[i];}
    part[blk*2]=S; part[blk*2+1]=SS;
  }
}

__global__ void gn_finalize(const float* __restrict__ part, const float* __restrict__ gw,
                            const float* __restrict__ gb, float2* __restrict__ sb){
  int g=threadIdx.x; if(g>=64) return;
  float S=0,SS=0;
  for(int j=0;j<8;j++){ S+=part[(g*8+j)*2]; SS+=part[(g*8+j)*2+1]; }
  const float inv=1.0f/294912.0f;
  float mean=S*inv, var=SS*inv-mean*mean;
  float rstd=rsqrtf(var+1e-5f);
  int b=g>>3, gg=g&7;
  for(int k=0;k<8;k++){
    int c=gg*8+k;
    float sc=rstd*gw[c];
    sb[b*64+c]=make_float2(sc, gb[c]-mean*sc);
  }
}

// ---------------- forward W-DFT: per (b,c,h) row, 192 -> 32 complex -------
// twiddles via per-lane rotation recurrence (no LDS gathers)
__global__ __launch_bounds__(256) void wdft(const float* __restrict__ x, const float2* __restrict__ sb,
                                            float2* __restrict__ XW){
  __shared__ float xl[8][192];
  int t=threadIdx.x, rg=t>>5, lane=t&31;
  int r = blockIdx.x*8 + rg;
  int bc = r/192, h = r - bc*192;
  float2 s = sb[bc];
  const float* xp = x + bc*36864 + h*192;
  float* xrow = xl[rg];
  #pragma unroll
  for(int j=0;j<6;j++){ int w=lane+32*j; xrow[w]=xp[w]*s.x+s.y; }
  __syncthreads();
  float a=(float)lane*(TPI/192.0f);
  float cs,sn; sincosf(a,&sn,&cs);   // step e^{-i a}: keep (cos, sin), accum with signs
  float cr=1.f, ci=0.f, ar=0.f, ai=0.f;
  #pragma unroll 4
  for(int w=0;w<192;w++){
    float xv=xrow[w];
    ar=fmaf(xv,cr,ar);
    ai=fmaf(-xv,ci,ai);
    float nr=fmaf(cr,cs,-(ci*sn));
    ci=fmaf(ci,cs,cr*sn);
    cr=nr;
  }
  XW[(bc*32+lane)*192 + h]=make_float2(ar,ai);
}

// ---------------- forward H-DFT: per (b,c,kw), 192 -> 32 complex ----------
__global__ __launch_bounds__(256) void hdft(const float2* __restrict__ XW, float2* __restrict__ Xm){
  __shared__ float2 xl[8][192];
  int t=threadIdx.x, rg=t>>5, lane=t&31;
  int r = blockIdx.x*8 + rg;            // (b*64+c)*32 + kw
  const float2* xp = XW + (size_t)r*192;
  float2* xrow = xl[rg];
  #pragma unroll
  for(int j=0;j<6;j++){ int h=lane+32*j; xrow[h]=xp[h]; }
  __syncthreads();
  float a=(float)lane*(TPI/192.0f);
  float cs,sn; sincosf(a,&sn,&cs);
  float cr=1.f, ci=0.f, ar=0.f, ai=0.f;
  #pragma unroll 4
  for(int h=0;h<192;h++){
    float2 v=xrow[h];
    ar=fmaf(v.x,cr,fmaf(v.y,ci,ar));     // (vx+ivy)*e^{-i th}
    ai=fmaf(v.y,cr,fmaf(-v.x,ci,ai));
    float nr=fmaf(cr,cs,-(ci*sn));
    ci=fmaf(ci,cs,cr*sn);
    cr=nr;
  }
  int kw=r&31, bc=r>>5, c=bc&63, b=bc>>6;
  const float sc=1.0f/192.0f;
  Xm[((b*32+lane)*32+kw)*64 + c]=make_float2(ar*sc, ai*sc);
}

// ---------------- block-diagonal complex 2-layer MLP on modes -------------
__global__ __launch_bounds__(256) void mode_mlp(const float2* __restrict__ Xm,
    const float* __restrict__ w1, const float* __restrict__ b1,
    const float* __restrict__ w2, const float* __restrict__ b2,
    float2* __restrict__ S){
  __shared__ float w10[1024], w11[1024], w20[1024], w21[1024];
  __shared__ float b10[64], b11[64], b20[64], b21[64];
  __shared__ float xr[4][64], xi[4][64], o1r[4][64], o1i[4][64];
  int t=threadIdx.x;
  for(int i=t;i<1024;i+=256){ w10[i]=w1[i]; w11[i]=w1[1024+i]; w20[i]=w2[i]; w21[i]=w2[1024+i]; }
  if(t<64){ b10[t]=b1[t]; b11[t]=b1[64+t]; b20[t]=b2[t]; b21[t]=b2[64+t]; }
  int p=t>>6, tl=t&63;
  int pos=blockIdx.x*4+p;
  float2 v=Xm[pos*64+tl];
  xr[p][tl]=v.x; xi[p][tl]=v.y;
  __syncthreads();
  int n=tl>>4, o=tl&15;
  int wb=n*256+o;
  float a_r=b10[tl], a_i=b11[tl];
  #pragma unroll
  for(int i=0;i<16;i++){
    float rr=xr[p][n*16+i], im=xi[p][n*16+i];
    float W0=w10[wb+i*16], W1=w11[wb+i*16];
    a_r=fmaf(rr,W0,fmaf(-im,W1,a_r));
    a_i=fmaf(im,W0,fmaf( rr,W1,a_i));
  }
  o1r[p][tl]=gelu_f(a_r); o1i[p][tl]=gelu_f(a_i);
  __syncthreads();
  float c_r=b20[tl], c_i=b21[tl];
  #pragma unroll
  for(int i=0;i<16;i++){
    float rr=o1r[p][n*16+i], im=o1i[p][n*16+i];
    float W0=w20[wb+i*16], W1=w21[wb+i*16];
    c_r=fmaf(rr,W0,fmaf(-im,W1,c_r));
    c_i=fmaf(im,W0,fmaf( rr,W1,c_i));
  }
  S[pos*64+tl]=make_float2(c_r,c_i);
}

// ---------------- inverse H (complex ifft over 32 kept modes) -------------
__global__ __launch_bounds__(192) void ihdft(const float2* __restrict__ S, float2* __restrict__ G){
  __shared__ float2 sv[32];
  int t=threadIdx.x;
  int r=blockIdx.x;                    // (b*64+c)*32 + kw
  int kw=r&31, bc=r>>5, c=bc&63, b=bc>>6;
  if(t<32) sv[t]=S[((b*32+t)*32+kw)*64+c];
  __syncthreads();
  float a=(float)t*(TPI/192.0f);
  float cs,sn; sincosf(a,&sn,&cs);     // step e^{+i a}
  float cr=1.f, ci=0.f, ar=0.f, ai=0.f;
  #pragma unroll
  for(int kh=0;kh<32;kh++){
    float2 v=sv[kh];
    ar=fmaf(v.x,cr,fmaf(-v.y,ci,ar));  // (vx+ivy)*e^{+i th}
    ai=fmaf(v.y,cr,fmaf( v.x,ci,ai));
    float nr=fmaf(cr,cs,-(ci*sn));
    ci=fmaf(ci,cs,cr*sn);
    cr=nr;
  }
  G[(size_t)r*192+t]=make_float2(ar,ai);
}

// ---------------- inverse W (c2r) + AFNO residual + outer residual --------
__global__ __launch_bounds__(256) void iwdft(const float2* __restrict__ G, const float* __restrict__ x,
                                             const float2* __restrict__ sb, float* __restrict__ h2){
  __shared__ float gr[32][33], gi[32][33];   // [kw][hh]
  int t=threadIdx.x;
  int blk=blockIdx.x; int bc=blk/6; int ht=blk-bc*6; int h0=ht*32;
  for(int i=t;i<1024;i+=256){
    int kw=i>>5, hh=i&31;
    float2 v=G[((size_t)bc*32+kw)*192 + h0+hh];
    gr[kw][hh]=v.x; gi[kw][hh]=v.y;
  }
  float2 s=sb[bc];
  __syncthreads();
  for(int j=0;j<24;j++){
    int p=t+256*j;
    int hh=p/192; int w=p-hh*192;
    float a=(float)w*(TPI/192.0f);
    float cs,sn; sincosf(a,&sn,&cs);
    float cr=cs, ci=sn;                 // twiddle for k=1
    float acc=0.5f*gr[0][hh];           // DC column counted once, Re only (c2r)
    #pragma unroll 4
    for(int k=1;k<32;k++){
      acc=fmaf(gr[k][hh],cr,fmaf(-gi[k][hh],ci,acc));
      float nr=fmaf(cr,cs,-(ci*sn));
      ci=fmaf(ci,cs,cr*sn);
      cr=nr;
    }
    acc*=(2.0f/192.0f);
    int gaddr=bc*36864 + h0*192 + p;
    float xv=x[gaddr];
    h2[gaddr]=acc + (xv*s.x+s.y) + xv;
  }
}

// ---------------- feats = gelu(fe_w @ gn2(h2) + fe_b), bf16 BHWC, MFMA ----
__global__ __launch_bounds__(256) void feats_k(const float* __restrict__ h2, const float2* __restrict__ sb,
                                               const float* __restrict__ fw, const float* __restrict__ fb,
                                               unsigned short* __restrict__ feats){
  __shared__ unsigned short A[64][72];   // [px][c^swz] bf16, 16B-aligned rows
  __shared__ unsigned short Bt[64][72];  // [oc][c] bf16
  int t=threadIdx.x;
  int blk=blockIdx.x; int b=blk/576; int tile=blk-b*576; int hw0=tile*64;
  // stage A from CHW h2, apply gn2 on the fly; swizzle c by ((px>>4)&3)<<3
  for(int i=t;i<4096;i+=256){
    int c=i>>6, px=i&63;
    float2 s=sb[b*64+c];
    float v=h2[(b*64+c)*36864 + hw0+px]*s.x + s.y;
    A[px][c ^ (((px>>4)&3)<<3)] = f2b(v);
  }
  // stage Bt: fe_w already [oc][c] row-major
  for(int i=t;i<4096;i+=256) Bt[i>>6][i&63]=f2b(fw[i]);
  __syncthreads();
  int wid=t>>6, l=t&63;
  int wm=wid>>1, wn=wid&1;
  int lr=l&15, lg=l>>4;
  f4v acc[2][2];
  #pragma unroll
  for(int fm=0;fm<2;fm++)
    #pragma unroll
    for(int fn=0;fn<2;fn++) acc[fm][fn]=f4v{0.f,0.f,0.f,0.f};
  #pragma unroll
  for(int ks=0;ks<2;ks++){
    int k0=ks*32+lg*8;
    bf8v af[2], bfv[2];
    #pragma unroll
    for(int fm=0;fm<2;fm++){
      int row=32*wm+16*fm+lr;
      af[fm]=*(const bf8v*)&A[row][k0 ^ (((row>>4)&3)<<3)];
    }
    #pragma unroll
    for(int fn=0;fn<2;fn++) bfv[fn]=*(const bf8v*)&Bt[32*wn+16*fn+lr][k0];
    #pragma unroll
    for(int fm=0;fm<2;fm++)
      #pragma unroll
      for(int fn=0;fn<2;fn++)
        acc[fm][fn]=__builtin_amdgcn_mfma_f32_16x16x32_bf16(af[fm],bfv[fn],acc[fm][fn],0,0,0);
  }
  #pragma unroll
  for(int fm=0;fm<2;fm++){
    #pragma unroll
    for(int fn=0;fn<2;fn++){
      int oc=32*wn+16*fn+lr;
      float bs=fb[oc];
      #pragma unroll
      for(int j=0;j<4;j++){
        int px=32*wm+16*fm+4*lg+j;
        feats[(b*36864+hw0+px)*64+oc]=f2b(gelu_f(acc[fm][fn][j]+bs));
      }
    }
  }
}

// ---------------- gf partial sums: mean of feats over HW (bf16 in) --------
__global__ __launch_bounds__(256) void gf_part(const unsigned short* __restrict__ feats, float* __restrict__ gfp){
  int blk=blockIdx.x; int b=blk/36; int ch=blk-b*36;
  int t=threadIdx.x; int c=t&63; int pg=t>>6;
  float s=0.f;
  for(int j=0;j<256;j++){
    int px=ch*1024 + pg + 4*j;
    s+=b2f(feats[(b*36864+px)*64+c]);
  }
  __shared__ float red[4][64];
  red[pg][c]=s; __syncthreads();
  if(t<64) gfp[blk*64+t]=red[0][t]+red[1][t]+red[2][t]+red[3][t];
}

// ---------------- gating MLP + top-4 softmax (single block) ---------------
__global__ __launch_bounds__(128) void gating(const float* __restrict__ gfp,
  const float* __restrict__ g1w, const float* __restrict__ g1b,
  const float* __restrict__ bn1g, const float* __restrict__ bn1b, const float* __restrict__ bn1m, const float* __restrict__ bn1v,
  const float* __restrict__ cw1, const float* __restrict__ cb1, const float* __restrict__ cw2, const float* __restrict__ cb2,
  const float* __restrict__ g2w, const float* __restrict__ g2b,
  const float* __restrict__ bn2g, const float* __restrict__ bn2b, const float* __restrict__ bn2m, const float* __restrict__ bn2v,
  const float* __restrict__ g3w, const float* __restrict__ g3b, float* __restrict__ gate){
  __shared__ float gf[8][64];
  __shared__ float h1[8][128];
  __shared__ float a1[8][8];
  __shared__ float h2g[8][64];
  __shared__ float sc[8][16];
  int t=threadIdx.x;
  for(int i=t;i<512;i+=128){
    int b=i>>6, c=i&63; float s=0.f;
    for(int ch=0;ch<36;ch++) s+=gfp[(b*36+ch)*64+c];
    gf[b][c]=s*(1.0f/36864.0f);
  }
  __syncthreads();
  for(int i=t;i<1024;i+=128){
    int b=i>>7, j=i&127;
    float s=g1b[j];
    for(int c=0;c<64;c++) s=fmaf(gf[b][c], g1w[j*64+c], s);
    s=(s-bn1m[j])*rsqrtf(bn1v[j]+1e-5f)*bn1g[j]+bn1b[j];
    h1[b][j]=gelu_f(s);
  }
  __syncthreads();
  if(t<64){
    int b=t>>3, k=t&7; float s=cb1[k];
    for(int j=0;j<128;j++) s=fmaf(h1[b][j], cw1[k*128+j], s);
    a1[b][k]=gelu_f(s);
  }
  __syncthreads();
  for(int i=t;i<1024;i+=128){
    int b=i>>7, j=i&127;
    float s=cb2[j];
    for(int k=0;k<8;k++) s=fmaf(a1[b][k], cw2[j*8+k], s);
    h1[b][j]=h1[b][j]/(1.0f+expf(-2.0f*s));
  }
  __syncthreads();
  for(int i=t;i<512;i+=128){
    int b=i>>6, j=i&63;
    float s=g2b[j];
    for(int k=0;k<128;k++) s=fmaf(h1[b][k], g2w[j*128+k], s);
    s=(s-bn2m[j])*rsqrtf(bn2v[j]+1e-5f)*bn2g[j]+bn2b[j];
    h2g[b][j]=gelu_f(s);
  }
  __syncthreads();
  {
    int b=t>>4, e=t&15;
    float s=g3b[e];
    for(int c=0;c<64;c++) s=fmaf(h2g[b][c], g3w[e*64+c], s);
    sc[b][e]=s;
  }
  __syncthreads();
  if(t<8){
    int b=t;
    float v[16], out[16];
    for(int e=0;e<16;e++){ v[e]=sc[b][e]; out[e]=0.0f; }
    float vals[4]; int idx[4];
    for(int k=0;k<4;k++){
      float best=-1e30f; int bi=0;
      for(int e=0;e<16;e++) if(v[e]>best){best=v[e];bi=e;}
      vals[k]=best; idx[k]=bi; v[bi]=-1e30f;
    }
    float m=vals[0], ssum=0.f, w[4];
    for(int k=0;k<4;k++){ w[k]=expf((vals[k]-m)*0.5f); ssum+=w[k]; }
    for(int k=0;k<4;k++) out[idx[k]]=w[k]/ssum;
    for(int e=0;e<16;e++) gate[b*16+e]=out[e];
  }
}

// ---------------- shared experts + gated experts + residual (MFMA) --------
__global__ __launch_bounds__(256) void final_k(const unsigned short* __restrict__ feats,
  const float* __restrict__ shw, const float* __restrict__ shb,
  const float* __restrict__ exw, const float* __restrict__ exb,
  const float* __restrict__ gate, float* __restrict__ out){
  __shared__ unsigned short A[64][72];
  __shared__ unsigned short Bt[64][72];
  __shared__ float bias[64];
  int t=threadIdx.x;
  int blk=blockIdx.x; int b=blk/576; int tile=blk-b*576; int hw0=tile*64;
  for(int i=t;i<4096;i+=256){
    int px=i>>6, c=i&63;
    A[px][c ^ (((px>>4)&3)<<3)] = feats[(b*36864+hw0+px)*64+c];
  }
  int wid=t>>6, l=t&63;
  int wm=wid>>1, wn=wid&1;
  int lr=l&15, lg=l>>4;
  float oa[2][2][4]={};
  for(int term=0;term<18;term++){
    float g; const float* wsrc; const float* bsrc;
    if(term<2){ g=0.5f; wsrc=shw+term*4096; bsrc=shb+term*64; }
    else { int e=term-2; g=gate[b*16+e]; wsrc=exw+e*4096; bsrc=exb+e*64; }
    if(g==0.0f) continue;                   // block-uniform branch
    __syncthreads();
    for(int i=t;i<4096;i+=256) Bt[i>>6][i&63]=f2b(wsrc[i]);
    if(t<64) bias[t]=bsrc[t];
    __syncthreads();
    f4v acc[2][2];
    #pragma unroll
    for(int fm=0;fm<2;fm++)
      #pragma unroll
      for(int fn=0;fn<2;fn++) acc[fm][fn]=f4v{0.f,0.f,0.f,0.f};
    #pragma unroll
    for(int ks=0;ks<2;ks++){
      int k0=ks*32+lg*8;
      bf8v af[2], bfv[2];
      #pragma unroll
      for(int fm=0;fm<2;fm++){
        int row=32*wm+16*fm+lr;
        af[fm]=*(const bf8v*)&A[row][k0 ^ (((row>>4)&3)<<3)];
      }
      #pragma unroll
      for(int fn=0;fn<2;fn++) bfv[fn]=*(const bf8v*)&Bt[32*wn+16*fn+lr][k0];
      #pragma unroll
      for(int fm=0;fm<2;fm++)
        #pragma unroll
        for(int fn=0;fn<2;fn++)
          acc[fm][fn]=__builtin_amdgcn_mfma_f32_16x16x32_bf16(af[fm],bfv[fn],acc[fm][fn],0,0,0);
    }
    #pragma unroll
    for(int fm=0;fm<2;fm++)
      #pragma unroll
      for(int fn=0;fn<2;fn++){
        float bs=bias[32*wn+16*fn+lr];
        #pragma unroll
        for(int j=0;j<4;j++)
          oa[fm][fn][j]=fmaf(g, gelu_f(acc[fm][fn][j]+bs), oa[fm][fn][j]);
      }
  }
  #pragma unroll
  for(int fm=0;fm<2;fm++)
    #pragma unroll
    for(int fn=0;fn<2;fn++){
      int oc=32*wn+16*fn+lr;
      int base=(b*64+oc)*36864 + hw0 + 32*wm+16*fm+4*lg;
      float4 r=*(const float4*)&out[base];
      float4 o=make_float4(oa[fm][fn][0]+r.x, oa[fm][fn][1]+r.y,
                           oa[fm][fn][2]+r.z, oa[fm][fn][3]+r.w);
      *(float4*)&out[base]=o;
    }
}

extern "C" void kernel_launch(void* const* d_in, const int* in_sizes, int n_in,
                              void* d_out, int out_size, void* d_ws, size_t ws_size,
                              hipStream_t stream){
  const float* x    =(const float*)d_in[0];
  const float* gn1w =(const float*)d_in[1];
  const float* gn1b =(const float*)d_in[2];
  const float* aw1  =(const float*)d_in[3];
  const float* ab1  =(const float*)d_in[4];
  const float* aw2  =(const float*)d_in[5];
  const float* ab2  =(const float*)d_in[6];
  const float* gn2w =(const float*)d_in[7];
  const float* gn2b =(const float*)d_in[8];
  const float* few  =(const float*)d_in[9];
  const float* feb  =(const float*)d_in[10];
  const float* g1w  =(const float*)d_in[11];
  const float* g1b  =(const float*)d_in[12];
  const float* bn1g =(const float*)d_in[13];
  const float* bn1b =(const float*)d_in[14];
  const float* bn1m =(const float*)d_in[15];
  const float* bn1v =(const float*)d_in[16];
  const float* cw1  =(const float*)d_in[17];
  const float* cb1  =(const float*)d_in[18];
  const float* cw2  =(const float*)d_in[19];
  const float* cb2  =(const float*)d_in[20];
  const float* g2w  =(const float*)d_in[21];
  const float* g2b  =(const float*)d_in[22];
  const float* bn2g =(const float*)d_in[23];
  const float* bn2b =(const float*)d_in[24];
  const float* bn2m =(const float*)d_in[25];
  const float* bn2v =(const float*)d_in[26];
  const float* g3w  =(const float*)d_in[27];
  const float* g3b  =(const float*)d_in[28];
  const float* shw  =(const float*)d_in[29];
  const float* shb  =(const float*)d_in[30];
  const float* exw  =(const float*)d_in[31];
  const float* exb  =(const float*)d_in[32];

  float* out=(float*)d_out;
  float* ws=(float*)d_ws;

  // workspace layout (float offsets)
  float*  part1 = ws;                         // 1024
  float*  part2 = ws+1024;                    // 1024
  float2* sb1   = (float2*)(ws+2048);         // 512 float2
  float2* sb2   = (float2*)(ws+3072);         // 512 float2
  float*  gate  = ws+4096;                    // 128
  float*  gfp   = ws+4224;                    // 18432
  float2* Xm    = (float2*)(ws+22656);        // 524288 float2
  float2* S     = (float2*)(ws+22656+1048576);// 524288 float2
  float2* XW    = (float2*)(ws+22656+2097152);// 3145728 float2 (reused as G)
  unsigned short* feats = (unsigned short*)(ws+8411264); // 18874368 bf16 (~37.7MB)

  // GN1 stats
  gn_partial <<<512,256,0,stream>>>(x, part1);
  gn_finalize<<<1,64,0,stream>>>(part1, gn1w, gn1b, sb1);
  // AFNO: truncated 2D DFT -> block MLP -> truncated inverse + residuals
  wdft   <<<12288,256,0,stream>>>(x, sb1, XW);
  hdft   <<<2048,256,0,stream>>>(XW, Xm);
  mode_mlp<<<2048,256,0,stream>>>(Xm, aw1, ab1, aw2, ab2, S);
  ihdft  <<<16384,192,0,stream>>>(S, XW);          // G overlays XW
  iwdft  <<<3072,256,0,stream>>>(XW, x, sb1, out); // h2 lives in d_out
  // GN2 stats on h2
  gn_partial <<<512,256,0,stream>>>(out, part2);
  gn_finalize<<<1,64,0,stream>>>(part2, gn2w, gn2b, sb2);
  // feature extractor (bf16 BHWC feats, MFMA)
  feats_k<<<4608,256,0,stream>>>(out, sb2, few, feb, feats);
  // gate
  gf_part<<<288,256,0,stream>>>(feats, gfp);
  gating <<<1,128,0,stream>>>(gfp, g1w,g1b, bn1g,bn1b,bn1m,bn1v,
                              cw1,cb1,cw2,cb2, g2w,g2b, bn2g,bn2b,bn2m,bn2v,
                              g3w,g3b, gate);
  // shared + active experts + residual (in-place on d_out, MFMA)
  final_k<<<4608,256,0,stream>>>(feats, shw, shb, exw, exb, gate, out);
}

// Round 4
// 244.353 us; speedup vs baseline: 3.2517x; 1.7916x over previous
//
#include <hip/hip_runtime.h>
#include <math.h>

// Problem constants: B=8, C=64, H=W=192, HW=36864, MODES=32, NB=4, BS=16, E=16
#define TPI 6.283185307179586f

typedef __attribute__((ext_vector_type(8))) short bf8v;   // 8 bf16 (4 VGPRs)
typedef __attribute__((ext_vector_type(4))) float f4v;    // 4 fp32 acc

#define MFMA(a,b,c) __builtin_amdgcn_mfma_f32_16x16x32_bf16((a),(b),(c),0,0,0)

__device__ __forceinline__ float gelu_f(float v){
  return 0.5f*v*(1.0f+erff(v*0.7071067811865475f));
}
__device__ __forceinline__ unsigned short f2b(float f){   // f32 -> bf16 (RNE)
  union{float f; unsigned u;} v; v.f=f;
  unsigned r=v.u + 0x7FFFu + ((v.u>>16)&1u);
  return (unsigned short)(r>>16);
}
__device__ __forceinline__ float b2f(unsigned short h){
  union{unsigned u; float f;} v; v.u=((unsigned)h)<<16; return v.f;
}

// ---------------- twiddle tables (bf16, in workspace) ----------------------
// TBf1[64][192]: fwd stage1 B^T:  [2kw+c][w]   : c? -sin(kw*w*a) : cos(kw*w*a)
// TBf2[64][384]: fwd stage2 B^T:  [2kh+d][2h+c]: (d,c)=(0,0)cos (0,1)sin (1,0)-sin (1,1)cos, *1/192
// TAi [192][64]: inv stage1 A  :  [h][2kh+c]   : c? sin(h*kh*a) : cos(h*kh*a)
// TBi [192][64]: inv stage2 B^T:  [w][2kw+d]   : d? -f*sin(w*kw*a) : f*cos(w*kw*a), f(0)=1/192,f(k)=2/192
__global__ __launch_bounds__(256) void tables_init(unsigned short* __restrict__ T){
  const float a = TPI/192.0f;
  for(int i=blockIdx.x*256+threadIdx.x; i<61440; i+=gridDim.x*256){
    float v;
    if(i<12288){
      int n1=i/192, w=i%192; int kw=n1>>1, c=n1&1;
      int m=(kw*w)%192; float cs,sn; sincosf((float)m*a,&sn,&cs);
      v = c ? -sn : cs;
    } else if(i<36864){
      int j=i-12288; int n1=j/384, k1=j%384; int kh=n1>>1, d=n1&1; int h=k1>>1, c=k1&1;
      int m=(kh*h)%192; float cs,sn; sincosf((float)m*a,&sn,&cs);
      float e = d ? (c ? cs : -sn) : (c ? sn : cs);
      v = e*(1.0f/192.0f);
    } else if(i<49152){
      int j=i-36864; int h=j/64, k1=j%64; int kh=k1>>1, c=k1&1;
      int m=(h*kh)%192; float cs,sn; sincosf((float)m*a,&sn,&cs);
      v = c ? sn : cs;
    } else {
      int j=i-49152; int w=j/64, k1=j%64; int kw=k1>>1, d=k1&1;
      float f = kw ? (2.0f/192.0f) : (1.0f/192.0f);
      int m=(w*kw)%192; float cs,sn; sincosf((float)m*a,&sn,&cs);
      v = d ? -f*sn : f*cs;
    }
    T[i]=f2b(v);
  }
}

// ---------------- GroupNorm stats (8 groups of 8 channels) ----------------
__global__ __launch_bounds__(256) void gn_partial(const float* __restrict__ x, float* __restrict__ part){
  int blk = blockIdx.x;
  const float4* p4 = (const float4*)(x + (size_t)blk*36864);
  float s=0.f, ss=0.f;
  for(int i=threadIdx.x;i<9216;i+=256){
    float4 v=p4[i];
    s+=v.x+v.y+v.z+v.w;
    ss+=v.x*v.x+v.y*v.y+v.z*v.z+v.w*v.w;
  }
  #pragma unroll
  for(int o=32;o>0;o>>=1){ s+=__shfl_down(s,o); ss+=__shfl_down(ss,o); }
  __shared__ float ls[4], lss[4];
  int wid=threadIdx.x>>6;
  if((threadIdx.x&63)==0){ ls[wid]=s; lss[wid]=ss; }
  __syncthreads();
  if(threadIdx.x==0){
    float S=0,SS=0;
    for(int i=0;i<4;i++){S+=ls[i];SS+=lss[i];}
    part[blk*2]=S; part[blk*2+1]=SS;
  }
}

__global__ void gn_finalize(const float* __restrict__ part, const float* __restrict__ gw,
                            const float* __restrict__ gb, float2* __restrict__ sb){
  int g=threadIdx.x; if(g>=64) return;
  float S=0,SS=0;
  for(int j=0;j<8;j++){ S+=part[(g*8+j)*2]; SS+=part[(g*8+j)*2+1]; }
  const float inv=1.0f/294912.0f;
  float mean=S*inv, var=SS*inv-mean*mean;
  float rstd=rsqrtf(var+1e-5f);
  int b=g>>3, gg=g&7;
  for(int k=0;k<8;k++){
    int c=gg*8+k;
    float sc=rstd*gw[c];
    sb[b*64+c]=make_float2(sc, gb[c]-mean*sc);
  }
}

// ---------------- fwd DFT (both axes) via MFMA, one block per (b,c) -------
// stage1: t[h][2kw+c] = sum_w xn[h][w]*TBf1[2kw+c][w]          (M=192,N=64,K=192)
// stage2: Xm[kh][kw]re/im via C'[kw][2kh+d] = sum_{k'} tL[kw][k']*TBf2[2kh+d][k'] (M=32,N=64,K=384)
// Xm2 layout: bc-major planar: Xm2[bc*2048 + (kh*32+kw)*2 + comp]
__global__ __launch_bounds__(256) void fwd_dft(const float* __restrict__ x, const float2* __restrict__ sb,
                                               const unsigned short* __restrict__ TBf1,
                                               const unsigned short* __restrict__ TBf2,
                                               float* __restrict__ Xm2){
  __shared__ __align__(16) unsigned short ldsA[64*200];  // Bt1 [64][200]; later tL [32][392]
  __shared__ __align__(16) float sX[2048];
  int t=threadIdx.x, bc=blockIdx.x;
  int wave=t>>6, l=t&63, lr=l&15, lg=l>>4;
  float2 s = sb[bc];
  // pin uniform scale/bias into VGPRs: avoids v_fma_f32 with 2 SGPR operands
  // (gfx950 constant-bus restriction; backend fails to legalize otherwise)
  float sx=s.x, sy=s.y;
  asm volatile("" : "+v"(sx), "+v"(sy));
  const float* xch = x + (size_t)bc*36864;
  // stage Bt1 from global table
  for(int i=t;i<1536;i+=256){
    int row=i/24, chunk=i%24;
    *(uint4*)&ldsA[row*200 + chunk*8] = *(const uint4*)(TBf1 + row*192 + chunk*8);
  }
  __syncthreads();
  // ---- stage 1 ----
  f4v acc1[3][4];
  for(int mt=0;mt<3;mt++){
    int m0=(wave+mt*4)*16;
    const float* xrow = xch + (m0+lr)*192 + lg*8;
    bf8v af[6];
    #pragma unroll
    for(int ks=0;ks<6;ks++){
      float4 u0=*(const float4*)(xrow+ks*32);
      float4 u1=*(const float4*)(xrow+ks*32+4);
      bf8v a;
      a[0]=(short)f2b(fmaf(u0.x,sx,sy)); a[1]=(short)f2b(fmaf(u0.y,sx,sy));
      a[2]=(short)f2b(fmaf(u0.z,sx,sy)); a[3]=(short)f2b(fmaf(u0.w,sx,sy));
      a[4]=(short)f2b(fmaf(u1.x,sx,sy)); a[5]=(short)f2b(fmaf(u1.y,sx,sy));
      a[6]=(short)f2b(fmaf(u1.z,sx,sy)); a[7]=(short)f2b(fmaf(u1.w,sx,sy));
      af[ks]=a;
    }
    #pragma unroll
    for(int nt=0;nt<4;nt++){
      f4v acc={0.f,0.f,0.f,0.f};
      #pragma unroll
      for(int ks=0;ks<6;ks++){
        bf8v b=*(const bf8v*)&ldsA[(nt*16+lr)*200 + ks*32 + lg*8];
        acc=MFMA(af[ks],b,acc);
      }
      acc1[mt][nt]=acc;
    }
  }
  __syncthreads();            // all Bt1 reads done; reuse ldsA as tL[32][392]
  for(int mt=0;mt<3;mt++){
    int m0=(wave+mt*4)*16;
    #pragma unroll
    for(int nt=0;nt<4;nt++){
      int n1=nt*16+lr; int kw=n1>>1, c=n1&1;
      #pragma unroll
      for(int reg=0;reg<4;reg++){
        int h=m0+4*lg+reg;
        ldsA[kw*392 + 2*h + c]=f2b(acc1[mt][nt][reg]);
      }
    }
  }
  __syncthreads();
  // ---- stage 2 ----
  for(int pp=0;pp<2;pp++){
    int p=wave+pp*4;
    int m0=(p>>2)*16, n0=(p&3)*16;
    f4v acc={0.f,0.f,0.f,0.f};
    #pragma unroll
    for(int ks=0;ks<12;ks++){
      bf8v a=*(const bf8v*)&ldsA[(m0+lr)*392 + ks*32 + lg*8];
      bf8v b=*(const bf8v*)(TBf2 + (n0+lr)*384 + ks*32 + lg*8);
      acc=MFMA(a,b,acc);
    }
    int n1=n0+lr; int kh=n1>>1, d=n1&1;
    #pragma unroll
    for(int reg=0;reg<4;reg++){
      int kw=m0+4*lg+reg;
      sX[(kh*32+kw)*2 + d]=acc[reg];
    }
  }
  __syncthreads();
  float* dst=Xm2+(size_t)bc*2048;
  for(int i=t;i<512;i+=256) *(float4*)(dst+i*4)=*(const float4*)(sX+i*4);
}

// ---------------- block-diagonal complex 2-layer MLP on modes -------------
// block = (b, kh): 256 blocks; planar bc-major I/O (Xm2 -> S2)
__global__ __launch_bounds__(256) void mode_mlp(const float* __restrict__ Xm2,
    const float* __restrict__ w1, const float* __restrict__ b1,
    const float* __restrict__ w2, const float* __restrict__ b2,
    float* __restrict__ S2){
  __shared__ float w10[1024], w11[1024], w20[1024], w21[1024];
  __shared__ float b10[64], b11[64], b20[64], b21[64];
  __shared__ float xr[32][64], xi[32][64];     // [kw][c]; reused as output
  __shared__ float o1r[32][64], o1i[32][64];
  int t=threadIdx.x;
  int b=blockIdx.x>>5, kh=blockIdx.x&31;
  for(int i=t;i<1024;i+=256){ w10[i]=w1[i]; w11[i]=w1[1024+i]; w20[i]=w2[i]; w21[i]=w2[1024+i]; }
  if(t<64){ b10[t]=b1[t]; b11[t]=b1[64+t]; b20[t]=b2[t]; b21[t]=b2[64+t]; }
  for(int q=0;q<16;q++){
    int idx=q*256+t; int c=idx>>6, jj=idx&63;
    float v=Xm2[((size_t)(b*64+c))*2048 + kh*64 + jj];
    if(jj&1) xi[jj>>1][c]=v; else xr[jj>>1][c]=v;
  }
  __syncthreads();
  int tl=t&63, n=tl>>4, o=tl&15, wb=n*256+o;
  #pragma unroll
  for(int it=0;it<8;it++){
    int kw=(t>>6)+it*4;
    float a_r=b10[tl], a_i=b11[tl];
    #pragma unroll
    for(int i=0;i<16;i++){
      float rr=xr[kw][n*16+i], im=xi[kw][n*16+i];
      float W0=w10[wb+i*16], W1=w11[wb+i*16];
      a_r=fmaf(rr,W0,fmaf(-im,W1,a_r));
      a_i=fmaf(im,W0,fmaf( rr,W1,a_i));
    }
    o1r[kw][tl]=gelu_f(a_r); o1i[kw][tl]=gelu_f(a_i);
  }
  __syncthreads();
  #pragma unroll
  for(int it=0;it<8;it++){
    int kw=(t>>6)+it*4;
    float c_r=b20[tl], c_i=b21[tl];
    #pragma unroll
    for(int i=0;i<16;i++){
      float rr=o1r[kw][n*16+i], im=o1i[kw][n*16+i];
      float W0=w20[wb+i*16], W1=w21[wb+i*16];
      c_r=fmaf(rr,W0,fmaf(-im,W1,c_r));
      c_i=fmaf(im,W0,fmaf( rr,W1,c_i));
    }
    xr[kw][tl]=c_r; xi[kw][tl]=c_i;    // reuse as output stage
  }
  __syncthreads();
  for(int q=0;q<16;q++){
    int idx=q*256+t; int c=idx>>6, jj=idx&63;
    float v = (jj&1) ? xi[jj>>1][c] : xr[jj>>1][c];
    S2[((size_t)(b*64+c))*2048 + kh*64 + jj]=v;
  }
}

// ---------------- inverse DFT (both axes) + residuals + gn2 stats ---------
// stage1: G[h][2kw+d] = sum_{k'=2kh+c} TAi[h][k']*Bs[2kw+d][k']   (M=192,N=64,K=64)
// stage2: out[h][w]   = sum_{k''}      GL[h][k'']*TBi[w][k'']     (M=192,N=192,K=64)
// h2 = irfft + (sc+1)*x + bi ; also emits per-channel (sum,sumsq) for gn2
__global__ __launch_bounds__(256) void inv_dft(const float* __restrict__ S2,
      const unsigned short* __restrict__ TAi, const unsigned short* __restrict__ TBi,
      const float* __restrict__ x, const float2* __restrict__ sb,
      float* __restrict__ h2, float* __restrict__ part2){
  __shared__ __align__(16) unsigned short Bs[64*72];
  __shared__ __align__(16) unsigned short GL[192*72];
  __shared__ float red[8];
  int t=threadIdx.x, bc=blockIdx.x;
  int wave=t>>6, l=t&63, lr=l&15, lg=l>>4;
  const float* sp=S2+(size_t)bc*2048;
  for(int i=t;i<1024;i+=256){
    int kh=i>>5, kw=i&31;
    float Sr=sp[(kh*32+kw)*2], Si=sp[(kh*32+kw)*2+1];
    unsigned short br=f2b(Sr), bi_=f2b(Si), nbi=f2b(-Si);
    Bs[(2*kw+0)*72 + 2*kh+0]=br;
    Bs[(2*kw+0)*72 + 2*kh+1]=nbi;
    Bs[(2*kw+1)*72 + 2*kh+0]=bi_;
    Bs[(2*kw+1)*72 + 2*kh+1]=br;
  }
  __syncthreads();
  // ---- stage 1 ----
  for(int mt=0;mt<3;mt++){
    int m0=(wave+mt*4)*16;
    bf8v a0=*(const bf8v*)(TAi + (m0+lr)*64 + lg*8);
    bf8v a1=*(const bf8v*)(TAi + (m0+lr)*64 + 32 + lg*8);
    #pragma unroll
    for(int nt=0;nt<4;nt++){
      f4v acc={0.f,0.f,0.f,0.f};
      bf8v b0=*(const bf8v*)&Bs[(nt*16+lr)*72 + lg*8];
      bf8v b1=*(const bf8v*)&Bs[(nt*16+lr)*72 + 32 + lg*8];
      acc=MFMA(a0,b0,acc); acc=MFMA(a1,b1,acc);
      #pragma unroll
      for(int reg=0;reg<4;reg++)
        GL[(m0+4*lg+reg)*72 + nt*16+lr]=f2b(acc[reg]);
    }
  }
  __syncthreads();
  // ---- stage 2 + epilogue ----
  float2 sv=sb[bc];
  float cA=sv.x+1.0f, cB=sv.y;
  asm volatile("" : "+v"(cA), "+v"(cB));   // pin to VGPR (constant-bus fix)
  const float* xch=x+(size_t)bc*36864;
  float* och=h2+(size_t)bc*36864;
  float s_=0.f, ss_=0.f;
  for(int mt=0;mt<3;mt++){
    int m0=(wave+mt*4)*16;
    bf8v a0=*(const bf8v*)&GL[(m0+lr)*72 + lg*8];
    bf8v a1=*(const bf8v*)&GL[(m0+lr)*72 + 32 + lg*8];
    for(int nt=0;nt<12;nt++){
      int n0=nt*16;
      f4v acc={0.f,0.f,0.f,0.f};
      bf8v b0=*(const bf8v*)(TBi + (n0+lr)*64 + lg*8);
      bf8v b1=*(const bf8v*)(TBi + (n0+lr)*64 + 32 + lg*8);
      acc=MFMA(a0,b0,acc); acc=MFMA(a1,b1,acc);
      int w=n0+lr;
      #pragma unroll
      for(int reg=0;reg<4;reg++){
        int h=m0+4*lg+reg;
        int ga=h*192+w;
        float xv=xch[ga];
        float val=acc[reg]+fmaf(cA,xv,cB);
        och[ga]=val;
        s_+=val; ss_+=val*val;
      }
    }
  }
  #pragma unroll
  for(int o=32;o>0;o>>=1){ s_+=__shfl_down(s_,o); ss_+=__shfl_down(ss_,o); }
  if(l==0){ red[wave]=s_; red[4+wave]=ss_; }
  __syncthreads();
  if(t==0){
    part2[bc*2]  =red[0]+red[1]+red[2]+red[3];
    part2[bc*2+1]=red[4]+red[5]+red[6]+red[7];
  }
}

// ---------------- feats = gelu(fe_w @ gn2(h2) + fe_b), bf16 BHWC, MFMA ----
__global__ __launch_bounds__(256) void feats_k(const float* __restrict__ h2, const float2* __restrict__ sb,
                                               const float* __restrict__ fw, const float* __restrict__ fb,
                                               unsigned short* __restrict__ feats){
  __shared__ unsigned short A[64][72];
  __shared__ unsigned short Bt[64][72];
  int t=threadIdx.x;
  int blk=blockIdx.x; int b=blk/576; int tile=blk-b*576; int hw0=tile*64;
  for(int i=t;i<4096;i+=256){
    int c=i>>6, px=i&63;
    float2 s=sb[b*64+c];
    float v=h2[(size_t)(b*64+c)*36864 + hw0+px]*s.x + s.y;
    A[px][c ^ (((px>>4)&3)<<3)] = f2b(v);
  }
  for(int i=t;i<4096;i+=256) Bt[i>>6][i&63]=f2b(fw[i]);
  __syncthreads();
  int wid=t>>6, l=t&63;
  int wm=wid>>1, wn=wid&1;
  int lr=l&15, lg=l>>4;
  f4v acc[2][2];
  #pragma unroll
  for(int fm=0;fm<2;fm++)
    #pragma unroll
    for(int fn=0;fn<2;fn++) acc[fm][fn]=f4v{0.f,0.f,0.f,0.f};
  #pragma unroll
  for(int ks=0;ks<2;ks++){
    int k0=ks*32+lg*8;
    bf8v af[2], bfv[2];
    #pragma unroll
    for(int fm=0;fm<2;fm++){
      int row=32*wm+16*fm+lr;
      af[fm]=*(const bf8v*)&A[row][k0 ^ (((row>>4)&3)<<3)];
    }
    #pragma unroll
    for(int fn=0;fn<2;fn++) bfv[fn]=*(const bf8v*)&Bt[32*wn+16*fn+lr][k0];
    #pragma unroll
    for(int fm=0;fm<2;fm++)
      #pragma unroll
      for(int fn=0;fn<2;fn++)
        acc[fm][fn]=MFMA(af[fm],bfv[fn],acc[fm][fn]);
  }
  #pragma unroll
  for(int fm=0;fm<2;fm++){
    #pragma unroll
    for(int fn=0;fn<2;fn++){
      int oc=32*wn+16*fn+lr;
      float bs=fb[oc];
      #pragma unroll
      for(int j=0;j<4;j++){
        int px=32*wm+16*fm+4*lg+j;
        feats[(size_t)(b*36864+hw0+px)*64+oc]=f2b(gelu_f(acc[fm][fn][j]+bs));
      }
    }
  }
}

// ---------------- gf partial sums: mean of feats over HW (bf16 in) --------
__global__ __launch_bounds__(256) void gf_part(const unsigned short* __restrict__ feats, float* __restrict__ gfp){
  int blk=blockIdx.x; int b=blk/36; int ch=blk-b*36;
  int t=threadIdx.x; int c=t&63; int pg=t>>6;
  float s=0.f;
  for(int j=0;j<256;j++){
    int px=ch*1024 + pg + 4*j;
    s+=b2f(feats[(size_t)(b*36864+px)*64+c]);
  }
  __shared__ float red[4][64];
  red[pg][c]=s; __syncthreads();
  if(t<64) gfp[blk*64+t]=red[0][t]+red[1][t]+red[2][t]+red[3][t];
}

// ---------------- gating MLP + top-4 softmax (single block) ---------------
__global__ __launch_bounds__(128) void gating(const float* __restrict__ gfp,
  const float* __restrict__ g1w, const float* __restrict__ g1b,
  const float* __restrict__ bn1g, const float* __restrict__ bn1b, const float* __restrict__ bn1m, const float* __restrict__ bn1v,
  const float* __restrict__ cw1, const float* __restrict__ cb1, const float* __restrict__ cw2, const float* __restrict__ cb2,
  const float* __restrict__ g2w, const float* __restrict__ g2b,
  const float* __restrict__ bn2g, const float* __restrict__ bn2b, const float* __restrict__ bn2m, const float* __restrict__ bn2v,
  const float* __restrict__ g3w, const float* __restrict__ g3b, float* __restrict__ gate){
  __shared__ float gf[8][64];
  __shared__ float h1[8][128];
  __shared__ float a1[8][8];
  __shared__ float h2g[8][64];
  __shared__ float sc[8][16];
  int t=threadIdx.x;
  for(int i=t;i<512;i+=128){
    int b=i>>6, c=i&63; float s=0.f;
    for(int ch=0;ch<36;ch++) s+=gfp[(b*36+ch)*64+c];
    gf[b][c]=s*(1.0f/36864.0f);
  }
  __syncthreads();
  for(int i=t;i<1024;i+=128){
    int b=i>>7, j=i&127;
    float s=g1b[j];
    for(int c=0;c<64;c++) s=fmaf(gf[b][c], g1w[j*64+c], s);
    s=(s-bn1m[j])*rsqrtf(bn1v[j]+1e-5f)*bn1g[j]+bn1b[j];
    h1[b][j]=gelu_f(s);
  }
  __syncthreads();
  if(t<64){
    int b=t>>3, k=t&7; float s=cb1[k];
    for(int j=0;j<128;j++) s=fmaf(h1[b][j], cw1[k*128+j], s);
    a1[b][k]=gelu_f(s);
  }
  __syncthreads();
  for(int i=t;i<1024;i+=128){
    int b=i>>7, j=i&127;
    float s=cb2[j];
    for(int k=0;k<8;k++) s=fmaf(a1[b][k], cw2[j*8+k], s);
    h1[b][j]=h1[b][j]/(1.0f+expf(-2.0f*s));
  }
  __syncthreads();
  for(int i=t;i<512;i+=128){
    int b=i>>6, j=i&63;
    float s=g2b[j];
    for(int k=0;k<128;k++) s=fmaf(h1[b][k], g2w[j*128+k], s);
    s=(s-bn2m[j])*rsqrtf(bn2v[j]+1e-5f)*bn2g[j]+bn2b[j];
    h2g[b][j]=gelu_f(s);
  }
  __syncthreads();
  {
    int b=t>>4, e=t&15;
    float s=g3b[e];
    for(int c=0;c<64;c++) s=fmaf(h2g[b][c], g3w[e*64+c], s);
    sc[b][e]=s;
  }
  __syncthreads();
  if(t<8){
    int b=t;
    float v[16], out[16];
    for(int e=0;e<16;e++){ v[e]=sc[b][e]; out[e]=0.0f; }
    float vals[4]; int idx[4];
    for(int k=0;k<4;k++){
      float best=-1e30f; int bi=0;
      for(int e=0;e<16;e++) if(v[e]>best){best=v[e];bi=e;}
      vals[k]=best; idx[k]=bi; v[bi]=-1e30f;
    }
    float m=vals[0], ssum=0.f, w[4];
    for(int k=0;k<4;k++){ w[k]=expf((vals[k]-m)*0.5f); ssum+=w[k]; }
    for(int k=0;k<4;k++) out[idx[k]]=w[k]/ssum;
    for(int e=0;e<16;e++) gate[b*16+e]=out[e];
  }
}

// ---------------- shared experts + gated experts + residual (MFMA) --------
__global__ __launch_bounds__(256) void final_k(const unsigned short* __restrict__ feats,
  const float* __restrict__ shw, const float* __restrict__ shb,
  const float* __restrict__ exw, const float* __restrict__ exb,
  const float* __restrict__ gate, float* __restrict__ out){
  __shared__ unsigned short A[64][72];
  __shared__ unsigned short Bt[64][72];
  __shared__ float bias[64];
  int t=threadIdx.x;
  int blk=blockIdx.x; int b=blk/576; int tile=blk-b*576; int hw0=tile*64;
  for(int i=t;i<4096;i+=256){
    int px=i>>6, c=i&63;
    A[px][c ^ (((px>>4)&3)<<3)] = feats[(size_t)(b*36864+hw0+px)*64+c];
  }
  int wid=t>>6, l=t&63;
  int wm=wid>>1, wn=wid&1;
  int lr=l&15, lg=l>>4;
  float oa[2][2][4]={};
  for(int term=0;term<18;term++){
    float g; const float* wsrc; const float* bsrc;
    if(term<2){ g=0.5f; wsrc=shw+term*4096; bsrc=shb+term*64; }
    else { int e=term-2; g=gate[b*16+e]; wsrc=exw+e*4096; bsrc=exb+e*64; }
    if(g==0.0f) continue;                   // block-uniform branch
    __syncthreads();
    for(int i=t;i<4096;i+=256) Bt[i>>6][i&63]=f2b(wsrc[i]);
    if(t<64) bias[t]=bsrc[t];
    __syncthreads();
    f4v acc[2][2];
    #pragma unroll
    for(int fm=0;fm<2;fm++)
      #pragma unroll
      for(int fn=0;fn<2;fn++) acc[fm][fn]=f4v{0.f,0.f,0.f,0.f};
    #pragma unroll
    for(int ks=0;ks<2;ks++){
      int k0=ks*32+lg*8;
      bf8v af[2], bfv[2];
      #pragma unroll
      for(int fm=0;fm<2;fm++){
        int row=32*wm+16*fm+lr;
        af[fm]=*(const bf8v*)&A[row][k0 ^ (((row>>4)&3)<<3)];
      }
      #pragma unroll
      for(int fn=0;fn<2;fn++) bfv[fn]=*(const bf8v*)&Bt[32*wn+16*fn+lr][k0];
      #pragma unroll
      for(int fm=0;fm<2;fm++)
        #pragma unroll
        for(int fn=0;fn<2;fn++)
          acc[fm][fn]=MFMA(af[fm],bfv[fn],acc[fm][fn]);
    }
    #pragma unroll
    for(int fm=0;fm<2;fm++)
      #pragma unroll
      for(int fn=0;fn<2;fn++){
        float bs=bias[32*wn+16*fn+lr];
        #pragma unroll
        for(int j=0;j<4;j++)
          oa[fm][fn][j]=fmaf(g, gelu_f(acc[fm][fn][j]+bs), oa[fm][fn][j]);
      }
  }
  #pragma unroll
  for(int fm=0;fm<2;fm++)
    #pragma unroll
    for(int fn=0;fn<2;fn++){
      int oc=32*wn+16*fn+lr;
      size_t base=(size_t)(b*64+oc)*36864 + hw0 + 32*wm+16*fm+4*lg;
      float4 r=*(const float4*)&out[base];
      float4 o=make_float4(oa[fm][fn][0]+r.x, oa[fm][fn][1]+r.y,
                           oa[fm][fn][2]+r.z, oa[fm][fn][3]+r.w);
      *(float4*)&out[base]=o;
    }
}

extern "C" void kernel_launch(void* const* d_in, const int* in_sizes, int n_in,
                              void* d_out, int out_size, void* d_ws, size_t ws_size,
                              hipStream_t stream){
  const float* x    =(const float*)d_in[0];
  const float* gn1w =(const float*)d_in[1];
  const float* gn1b =(const float*)d_in[2];
  const float* aw1  =(const float*)d_in[3];
  const float* ab1  =(const float*)d_in[4];
  const float* aw2  =(const float*)d_in[5];
  const float* ab2  =(const float*)d_in[6];
  const float* gn2w =(const float*)d_in[7];
  const float* gn2b =(const float*)d_in[8];
  const float* few  =(const float*)d_in[9];
  const float* feb  =(const float*)d_in[10];
  const float* g1w  =(const float*)d_in[11];
  const float* g1b  =(const float*)d_in[12];
  const float* bn1g =(const float*)d_in[13];
  const float* bn1b =(const float*)d_in[14];
  const float* bn1m =(const float*)d_in[15];
  const float* bn1v =(const float*)d_in[16];
  const float* cw1  =(const float*)d_in[17];
  const float* cb1  =(const float*)d_in[18];
  const float* cw2  =(const float*)d_in[19];
  const float* cb2  =(const float*)d_in[20];
  const float* g2w  =(const float*)d_in[21];
  const float* g2b  =(const float*)d_in[22];
  const float* bn2g =(const float*)d_in[23];
  const float* bn2b =(const float*)d_in[24];
  const float* bn2m =(const float*)d_in[25];
  const float* bn2v =(const float*)d_in[26];
  const float* g3w  =(const float*)d_in[27];
  const float* g3b  =(const float*)d_in[28];
  const float* shw  =(const float*)d_in[29];
  const float* shb  =(const float*)d_in[30];
  const float* exw  =(const float*)d_in[31];
  const float* exb  =(const float*)d_in[32];

  float* out=(float*)d_out;
  float* ws=(float*)d_ws;

  // workspace layout (float offsets)
  float*  part1 = ws;                         // 1024
  float*  part2 = ws+1024;                    // 1024
  float2* sb1   = (float2*)(ws+2048);         // 512 float2
  float2* sb2   = (float2*)(ws+3072);         // 512 float2
  float*  gate  = ws+4096;                    // 128
  float*  gfp   = ws+4224;                    // 18432
  float*  Xm2   = ws+22656;                   // 1048576
  float*  S2    = ws+1071232;                 // 1048576
  unsigned short* Tbl = (unsigned short*)(ws+2119808);   // 61440 shorts (30720 f)
  const unsigned short* TBf1 = Tbl;
  const unsigned short* TBf2 = Tbl+12288;
  const unsigned short* TAi  = Tbl+36864;
  const unsigned short* TBi  = Tbl+49152;
  unsigned short* feats = (unsigned short*)(ws+2150528); // 18874368 shorts

  tables_init<<<64,256,0,stream>>>(Tbl);
  // GN1 stats
  gn_partial <<<512,256,0,stream>>>(x, part1);
  gn_finalize<<<1,64,0,stream>>>(part1, gn1w, gn1b, sb1);
  // AFNO: fused truncated 2D DFT (MFMA) -> block MLP -> fused inverse + residuals + gn2 stats
  fwd_dft <<<512,256,0,stream>>>(x, sb1, TBf1, TBf2, Xm2);
  mode_mlp<<<256,256,0,stream>>>(Xm2, aw1, ab1, aw2, ab2, S2);
  inv_dft <<<512,256,0,stream>>>(S2, TAi, TBi, x, sb1, out, part2);
  gn_finalize<<<1,64,0,stream>>>(part2, gn2w, gn2b, sb2);
  // feature extractor (bf16 BHWC feats, MFMA)
  feats_k<<<4608,256,0,stream>>>(out, sb2, few, feb, feats);
  // gate
  gf_part<<<288,256,0,stream>>>(feats, gfp);
  gating <<<1,128,0,stream>>>(gfp, g1w,g1b, bn1g,bn1b,bn1m,bn1v,
                              cw1,cb1,cw2,cb2, g2w,g2b, bn2g,bn2b,bn2m,bn2v,
                              g3w,g3b, gate);
  // shared + active experts + residual (in-place on d_out, MFMA)
  final_k<<<4608,256,0,stream>>>(feats, shw, shb, exw, exb, gate, out);
}

// Round 5
// 243.155 us; speedup vs baseline: 3.2677x; 1.0049x over previous
//
#include <hip/hip_runtime.h>
#include <math.h>

// Problem constants: B=8, C=64, H=W=192, HW=36864, MODES=32, NB=4, BS=16, E=16
#define TPI 6.283185307179586f

typedef __attribute__((ext_vector_type(8))) short bf8v;   // 8 bf16 (4 VGPRs)
typedef __attribute__((ext_vector_type(4))) float f4v;    // 4 fp32 acc

#define MFMA(a,b,c) __builtin_amdgcn_mfma_f32_16x16x32_bf16((a),(b),(c),0,0,0)

__device__ __forceinline__ float gelu_f(float v){          // exact (erf)
  return 0.5f*v*(1.0f+erff(v*0.7071067811865475f));
}
__device__ __forceinline__ float gelu_fast(float x){       // tanh approx, ~1e-3 abs err
  float x3=x*x*x;
  float y=fmaf(0.044715f,x3,x)*0.7978845608f;
  float e=__expf(2.0f*y);
  float th=1.0f-2.0f/(e+1.0f);
  return 0.5f*x*(1.0f+th);
}
__device__ __forceinline__ unsigned short f2b(float f){   // f32 -> bf16 (RNE)
  union{float f; unsigned u;} v; v.f=f;
  unsigned r=v.u + 0x7FFFu + ((v.u>>16)&1u);
  return (unsigned short)(r>>16);
}

// ---------------- prep: twiddle tables + bf16 weights + zero gfp -----------
// TBf1[64][192]: fwd stage1 B^T:  [2kw+c][w]   : c? -sin : cos
// TBf2[64][384]: fwd stage2 B^T:  [2kh+d][2h+c], *1/192
// TAi [192][64]: inv stage1 A  :  [h][2kh+c]
// TBi [192][64]: inv stage2 B^T:  [w][2kw+d], f(0)=1/192,f(k)=2/192
__global__ __launch_bounds__(256) void prep(const float* __restrict__ shw, const float* __restrict__ exw,
    const float* __restrict__ shb, const float* __restrict__ exb, const float* __restrict__ few,
    unsigned short* __restrict__ T, unsigned short* __restrict__ wall, float* __restrict__ ball,
    unsigned short* __restrict__ wfe, float* __restrict__ gfp){
  const float a = TPI/192.0f;
  int stride=gridDim.x*256;
  for(int i=blockIdx.x*256+threadIdx.x; i<61440; i+=stride){
    float v;
    if(i<12288){
      int n1=i/192, w=i%192; int kw=n1>>1, c=n1&1;
      int m=(kw*w)%192; float cs,sn; sincosf((float)m*a,&sn,&cs);
      v = c ? -sn : cs;
    } else if(i<36864){
      int j=i-12288; int n1=j/384, k1=j%384; int kh=n1>>1, d=n1&1; int h=k1>>1, c=k1&1;
      int m=(kh*h)%192; float cs,sn; sincosf((float)m*a,&sn,&cs);
      float e = d ? (c ? cs : -sn) : (c ? sn : cs);
      v = e*(1.0f/192.0f);
    } else if(i<49152){
      int j=i-36864; int h=j/64, k1=j%64; int kh=k1>>1, c=k1&1;
      int m=(h*kh)%192; float cs,sn; sincosf((float)m*a,&sn,&cs);
      v = c ? sn : cs;
    } else {
      int j=i-49152; int w=j/64, k1=j%64; int kw=k1>>1, d=k1&1;
      float f = kw ? (2.0f/192.0f) : (1.0f/192.0f);
      int m=(w*kw)%192; float cs,sn; sincosf((float)m*a,&sn,&cs);
      v = d ? -f*sn : f*cs;
    }
    T[i]=f2b(v);
  }
  for(int i=blockIdx.x*256+threadIdx.x;i<73728;i+=stride) wall[i]=f2b(i<8192?shw[i]:exw[i-8192]);
  for(int i=blockIdx.x*256+threadIdx.x;i<1152;i+=stride)  ball[i]=(i<128)?shb[i]:exb[i-128];
  for(int i=blockIdx.x*256+threadIdx.x;i<4096;i+=stride)  wfe[i]=f2b(few[i]);
  for(int i=blockIdx.x*256+threadIdx.x;i<512;i+=stride)   gfp[i]=0.f;
}

__global__ void gn_finalize(const float* __restrict__ part, const float* __restrict__ gw,
                            const float* __restrict__ gb, float2* __restrict__ sb){
  int g=threadIdx.x; if(g>=64) return;
  float S=0,SS=0;
  for(int j=0;j<8;j++){ S+=part[(g*8+j)*2]; SS+=part[(g*8+j)*2+1]; }
  const float inv=1.0f/294912.0f;
  float mean=S*inv, var=SS*inv-mean*mean;
  float rstd=rsqrtf(var+1e-5f);
  int b=g>>3, gg=g&7;
  for(int k=0;k<8;k++){
    int c=gg*8+k;
    float sc=rstd*gw[c];
    sb[b*64+c]=make_float2(sc, gb[c]-mean*sc);
  }
}

// ---------------- fwd DFT on RAW x (gn1 folded out via linearity) ---------
// also emits per-channel (sum,sumsq) of x for gn1 stats.
__global__ __launch_bounds__(256) void fwd_dft(const float* __restrict__ x,
      const unsigned short* __restrict__ TBf1, const unsigned short* __restrict__ TBf2,
      float* __restrict__ Xm2, float* __restrict__ part1){
  __shared__ __align__(16) unsigned short ldsA[64*200];  // Bt1 [64][200]; later tL [32][392]
  __shared__ __align__(16) float sX[2048];
  __shared__ float red[8];
  int t=threadIdx.x, bc=blockIdx.x;
  int wave=t>>6, l=t&63, lr=l&15, lg=l>>4;
  const float* xch = x + (size_t)bc*36864;
  for(int i=t;i<1536;i+=256){
    int row=i/24, chunk=i%24;
    *(uint4*)&ldsA[row*200 + chunk*8] = *(const uint4*)(TBf1 + row*192 + chunk*8);
  }
  __syncthreads();
  float s_=0.f, ss_=0.f;
  // ---- stage 1 ----
  f4v acc1[3][4];
  for(int mt=0;mt<3;mt++){
    int m0=(wave+mt*4)*16;
    const float* xrow = xch + (m0+lr)*192 + lg*8;
    bf8v af[6];
    #pragma unroll
    for(int ks=0;ks<6;ks++){
      float4 u0=*(const float4*)(xrow+ks*32);
      float4 u1=*(const float4*)(xrow+ks*32+4);
      s_ += u0.x+u0.y+u0.z+u0.w+u1.x+u1.y+u1.z+u1.w;
      ss_+= u0.x*u0.x+u0.y*u0.y+u0.z*u0.z+u0.w*u0.w
           +u1.x*u1.x+u1.y*u1.y+u1.z*u1.z+u1.w*u1.w;
      bf8v a;
      a[0]=(short)f2b(u0.x); a[1]=(short)f2b(u0.y); a[2]=(short)f2b(u0.z); a[3]=(short)f2b(u0.w);
      a[4]=(short)f2b(u1.x); a[5]=(short)f2b(u1.y); a[6]=(short)f2b(u1.z); a[7]=(short)f2b(u1.w);
      af[ks]=a;
    }
    #pragma unroll
    for(int nt=0;nt<4;nt++){
      f4v acc={0.f,0.f,0.f,0.f};
      #pragma unroll
      for(int ks=0;ks<6;ks++){
        bf8v b=*(const bf8v*)&ldsA[(nt*16+lr)*200 + ks*32 + lg*8];
        acc=MFMA(af[ks],b,acc);
      }
      acc1[mt][nt]=acc;
    }
  }
  __syncthreads();            // reuse ldsA as tL [32][392]
  for(int mt=0;mt<3;mt++){
    int m0=(wave+mt*4)*16;
    #pragma unroll
    for(int nt=0;nt<4;nt++){
      int n1=nt*16+lr; int kw=n1>>1, c=n1&1;
      #pragma unroll
      for(int reg=0;reg<4;reg++){
        int h=m0+4*lg+reg;
        ldsA[kw*392 + 2*h + c]=f2b(acc1[mt][nt][reg]);
      }
    }
  }
  __syncthreads();
  // ---- stage 2 ----
  for(int pp=0;pp<2;pp++){
    int p=wave+pp*4;
    int m0=(p>>2)*16, n0=(p&3)*16;
    f4v acc={0.f,0.f,0.f,0.f};
    #pragma unroll
    for(int ks=0;ks<12;ks++){
      bf8v a=*(const bf8v*)&ldsA[(m0+lr)*392 + ks*32 + lg*8];
      bf8v b=*(const bf8v*)(TBf2 + (n0+lr)*384 + ks*32 + lg*8);
      acc=MFMA(a,b,acc);
    }
    int n1=n0+lr; int kh=n1>>1, d=n1&1;
    #pragma unroll
    for(int reg=0;reg<4;reg++){
      int kw=m0+4*lg+reg;
      sX[(kh*32+kw)*2 + d]=acc[reg];
    }
  }
  __syncthreads();
  float* dst=Xm2+(size_t)bc*2048;
  for(int i=t;i<512;i+=256) *(float4*)(dst+i*4)=*(const float4*)(sX+i*4);
  // ---- gn1 stats ----
  #pragma unroll
  for(int o=32;o>0;o>>=1){ s_+=__shfl_down(s_,o); ss_+=__shfl_down(ss_,o); }
  if(l==0){ red[wave]=s_; red[4+wave]=ss_; }
  __syncthreads();
  if(t==0){
    part1[bc*2]  =red[0]+red[1]+red[2]+red[3];
    part1[bc*2+1]=red[4]+red[5]+red[6]+red[7];
  }
}

// ---------------- block-diagonal complex 2-layer MLP on modes -------------
// applies gn1 normalization on load: Xn = s*Xraw + delta_DC * 192*t
__global__ __launch_bounds__(256) void mode_mlp(const float* __restrict__ Xm2, const float2* __restrict__ sb1,
    const float* __restrict__ w1, const float* __restrict__ b1,
    const float* __restrict__ w2, const float* __restrict__ b2,
    float* __restrict__ S2){
  __shared__ float w10[1024], w11[1024], w20[1024], w21[1024];
  __shared__ float b10[64], b11[64], b20[64], b21[64];
  __shared__ float2 sbl[64];
  __shared__ float xr[32][64], xi[32][64];
  __shared__ float o1r[32][64], o1i[32][64];
  int t=threadIdx.x;
  int b=blockIdx.x>>5, kh=blockIdx.x&31;
  for(int i=t;i<1024;i+=256){ w10[i]=w1[i]; w11[i]=w1[1024+i]; w20[i]=w2[i]; w21[i]=w2[1024+i]; }
  if(t<64){ b10[t]=b1[t]; b11[t]=b1[64+t]; b20[t]=b2[t]; b21[t]=b2[64+t]; sbl[t]=sb1[b*64+t]; }
  __syncthreads();
  for(int q=0;q<16;q++){
    int idx=q*256+t; int c=idx>>6, jj=idx&63;
    float2 s=sbl[c];
    float v=Xm2[((size_t)(b*64+c))*2048 + kh*64 + jj]*s.x;
    if(kh==0 && jj==0) v += 192.0f*s.y;
    if(jj&1) xi[jj>>1][c]=v; else xr[jj>>1][c]=v;
  }
  __syncthreads();
  int tl=t&63, n=tl>>4, o=tl&15, wb=n*256+o;
  #pragma unroll
  for(int it=0;it<8;it++){
    int kw=(t>>6)+it*4;
    float a_r=b10[tl], a_i=b11[tl];
    #pragma unroll
    for(int i=0;i<16;i++){
      float rr=xr[kw][n*16+i], im=xi[kw][n*16+i];
      float W0=w10[wb+i*16], W1=w11[wb+i*16];
      a_r=fmaf(rr,W0,fmaf(-im,W1,a_r));
      a_i=fmaf(im,W0,fmaf( rr,W1,a_i));
    }
    o1r[kw][tl]=gelu_f(a_r); o1i[kw][tl]=gelu_f(a_i);
  }
  __syncthreads();
  #pragma unroll
  for(int it=0;it<8;it++){
    int kw=(t>>6)+it*4;
    float c_r=b20[tl], c_i=b21[tl];
    #pragma unroll
    for(int i=0;i<16;i++){
      float rr=o1r[kw][n*16+i], im=o1i[kw][n*16+i];
      float W0=w20[wb+i*16], W1=w21[wb+i*16];
      c_r=fmaf(rr,W0,fmaf(-im,W1,c_r));
      c_i=fmaf(im,W0,fmaf( rr,W1,c_i));
    }
    xr[kw][tl]=c_r; xi[kw][tl]=c_i;
  }
  __syncthreads();
  for(int q=0;q<16;q++){
    int idx=q*256+t; int c=idx>>6, jj=idx&63;
    float v = (jj&1) ? xi[jj>>1][c] : xr[jj>>1][c];
    S2[((size_t)(b*64+c))*2048 + kh*64 + jj]=v;
  }
}

// ---------------- inverse DFT + residuals + gn2 stats ---------------------
__global__ __launch_bounds__(256) void inv_dft(const float* __restrict__ S2,
      const unsigned short* __restrict__ TAi, const unsigned short* __restrict__ TBi,
      const float* __restrict__ x, const float2* __restrict__ sb,
      float* __restrict__ h2, float* __restrict__ part2){
  __shared__ __align__(16) unsigned short Bs[64*72];
  __shared__ __align__(16) unsigned short GL[192*72];
  __shared__ float red[8];
  int t=threadIdx.x, bc=blockIdx.x;
  int wave=t>>6, l=t&63, lr=l&15, lg=l>>4;
  const float* sp=S2+(size_t)bc*2048;
  for(int i=t;i<1024;i+=256){
    int kh=i>>5, kw=i&31;
    float Sr=sp[(kh*32+kw)*2], Si=sp[(kh*32+kw)*2+1];
    unsigned short br=f2b(Sr), bi_=f2b(Si), nbi=f2b(-Si);
    Bs[(2*kw+0)*72 + 2*kh+0]=br;
    Bs[(2*kw+0)*72 + 2*kh+1]=nbi;
    Bs[(2*kw+1)*72 + 2*kh+0]=bi_;
    Bs[(2*kw+1)*72 + 2*kh+1]=br;
  }
  __syncthreads();
  for(int mt=0;mt<3;mt++){
    int m0=(wave+mt*4)*16;
    bf8v a0=*(const bf8v*)(TAi + (m0+lr)*64 + lg*8);
    bf8v a1=*(const bf8v*)(TAi + (m0+lr)*64 + 32 + lg*8);
    #pragma unroll
    for(int nt=0;nt<4;nt++){
      f4v acc={0.f,0.f,0.f,0.f};
      bf8v b0=*(const bf8v*)&Bs[(nt*16+lr)*72 + lg*8];
      bf8v b1=*(const bf8v*)&Bs[(nt*16+lr)*72 + 32 + lg*8];
      acc=MFMA(a0,b0,acc); acc=MFMA(a1,b1,acc);
      #pragma unroll
      for(int reg=0;reg<4;reg++)
        GL[(m0+4*lg+reg)*72 + nt*16+lr]=f2b(acc[reg]);
    }
  }
  __syncthreads();
  float2 sv=sb[bc];
  float cA=sv.x+1.0f, cB=sv.y;
  asm volatile("" : "+v"(cA), "+v"(cB));   // pin to VGPR (constant-bus fix)
  const float* xch=x+(size_t)bc*36864;
  float* och=h2+(size_t)bc*36864;
  float s_=0.f, ss_=0.f;
  for(int mt=0;mt<3;mt++){
    int m0=(wave+mt*4)*16;
    bf8v a0=*(const bf8v*)&GL[(m0+lr)*72 + lg*8];
    bf8v a1=*(const bf8v*)&GL[(m0+lr)*72 + 32 + lg*8];
    for(int nt=0;nt<12;nt++){
      int n0=nt*16;
      f4v acc={0.f,0.f,0.f,0.f};
      bf8v b0=*(const bf8v*)(TBi + (n0+lr)*64 + lg*8);
      bf8v b1=*(const bf8v*)(TBi + (n0+lr)*64 + 32 + lg*8);
      acc=MFMA(a0,b0,acc); acc=MFMA(a1,b1,acc);
      int w=n0+lr;
      #pragma unroll
      for(int reg=0;reg<4;reg++){
        int h=m0+4*lg+reg;
        int ga=h*192+w;
        float xv=xch[ga];
        float val=acc[reg]+fmaf(cA,xv,cB);
        och[ga]=val;
        s_+=val; ss_+=val*val;
      }
    }
  }
  #pragma unroll
  for(int o=32;o>0;o>>=1){ s_+=__shfl_down(s_,o); ss_+=__shfl_down(ss_,o); }
  if(l==0){ red[wave]=s_; red[4+wave]=ss_; }
  __syncthreads();
  if(t==0){
    part2[bc*2]  =red[0]+red[1]+red[2]+red[3];
    part2[bc*2+1]=red[4]+red[5]+red[6]+red[7];
  }
}

// ---------------- feats = gelu(fe_w @ gn2(h2) + fe_b) + fused gf sum ------
__global__ __launch_bounds__(256) void feats_k(const float* __restrict__ h2, const float2* __restrict__ sb,
    const unsigned short* __restrict__ wfe, const float* __restrict__ feb,
    unsigned short* __restrict__ feats, float* __restrict__ gfp){
  __shared__ __align__(16) unsigned short A[128*72];
  __shared__ float sgf[64];
  int t=threadIdx.x;
  int blk=blockIdx.x, b=blk/288, tile=blk-b*288, hw0=tile*128;
  if(t<64) sgf[t]=0.f;
  for(int i=t;i<2048;i+=256){
    int c=i>>5, q=i&31;
    float2 s=sb[b*64+c];
    float4 v=*(const float4*)&h2[(size_t)(b*64+c)*36864 + hw0 + q*4];
    int px0=q*4, sw=((px0>>4)&3)<<3, cc=c^sw;
    A[(px0+0)*72+cc]=f2b(fmaf(v.x,s.x,s.y));
    A[(px0+1)*72+cc]=f2b(fmaf(v.y,s.x,s.y));
    A[(px0+2)*72+cc]=f2b(fmaf(v.z,s.x,s.y));
    A[(px0+3)*72+cc]=f2b(fmaf(v.w,s.x,s.y));
  }
  __syncthreads();
  int wave=t>>6, l=t&63, lr=l&15, lg=l>>4;
  int pxb=wave*32;
  bf8v af[2][2], bfv[4][2];
  #pragma unroll
  for(int fm=0;fm<2;fm++){
    int row=pxb+fm*16+lr, sw=((row>>4)&3)<<3;
    #pragma unroll
    for(int ks=0;ks<2;ks++) af[fm][ks]=*(const bf8v*)&A[row*72+((ks*32+lg*8)^sw)];
  }
  #pragma unroll
  for(int fn=0;fn<4;fn++)
    #pragma unroll
    for(int ks=0;ks<2;ks++)
      bfv[fn][ks]=*(const bf8v*)(wfe+(fn*16+lr)*64+ks*32+lg*8);
  float gsum[4]={0.f,0.f,0.f,0.f};
  #pragma unroll
  for(int fm=0;fm<2;fm++)
    #pragma unroll
    for(int fn=0;fn<4;fn++){
      f4v acc={0.f,0.f,0.f,0.f};
      acc=MFMA(af[fm][0],bfv[fn][0],acc);
      acc=MFMA(af[fm][1],bfv[fn][1],acc);
      int oc=fn*16+lr;
      float bs=feb[oc];
      #pragma unroll
      for(int r=0;r<4;r++){
        float g=gelu_f(acc[r]+bs);
        gsum[fn]+=g;
        int px=hw0+pxb+fm*16+4*lg+r;
        feats[(size_t)(b*36864+px)*64+oc]=f2b(g);
      }
    }
  #pragma unroll
  for(int fn=0;fn<4;fn++){
    float v=gsum[fn];
    v+=__shfl_xor(v,16); v+=__shfl_xor(v,32);
    if(lg==0) atomicAdd(&sgf[fn*16+lr], v);
  }
  __syncthreads();
  if(t<64) atomicAdd(&gfp[b*64+t], sgf[t]);
}

// ---------------- gating MLP + top-4 softmax -> active-term list ----------
__global__ __launch_bounds__(128) void gating(const float* __restrict__ gfp,
  const float* __restrict__ g1w, const float* __restrict__ g1b,
  const float* __restrict__ bn1g, const float* __restrict__ bn1b, const float* __restrict__ bn1m, const float* __restrict__ bn1v,
  const float* __restrict__ cw1, const float* __restrict__ cb1, const float* __restrict__ cw2, const float* __restrict__ cb2,
  const float* __restrict__ g2w, const float* __restrict__ g2b,
  const float* __restrict__ bn2g, const float* __restrict__ bn2b, const float* __restrict__ bn2m, const float* __restrict__ bn2v,
  const float* __restrict__ g3w, const float* __restrict__ g3b, float2* __restrict__ act){
  __shared__ float gf[8][64];
  __shared__ float h1[8][128];
  __shared__ float a1[8][8];
  __shared__ float h2g[8][64];
  __shared__ float sc[8][16];
  int t=threadIdx.x;
  for(int i=t;i<512;i+=128) gf[i>>6][i&63]=gfp[i]*(1.0f/36864.0f);
  __syncthreads();
  for(int i=t;i<1024;i+=128){
    int b=i>>7, j=i&127;
    float s=g1b[j];
    for(int c=0;c<64;c++) s=fmaf(gf[b][c], g1w[j*64+c], s);
    s=(s-bn1m[j])*rsqrtf(bn1v[j]+1e-5f)*bn1g[j]+bn1b[j];
    h1[b][j]=gelu_f(s);
  }
  __syncthreads();
  if(t<64){
    int b=t>>3, k=t&7; float s=cb1[k];
    for(int j=0;j<128;j++) s=fmaf(h1[b][j], cw1[k*128+j], s);
    a1[b][k]=gelu_f(s);
  }
  __syncthreads();
  for(int i=t;i<1024;i+=128){
    int b=i>>7, j=i&127;
    float s=cb2[j];
    for(int k=0;k<8;k++) s=fmaf(a1[b][k], cw2[j*8+k], s);
    h1[b][j]=h1[b][j]/(1.0f+expf(-2.0f*s));
  }
  __syncthreads();
  for(int i=t;i<512;i+=128){
    int b=i>>6, j=i&63;
    float s=g2b[j];
    for(int k=0;k<128;k++) s=fmaf(h1[b][k], g2w[j*128+k], s);
    s=(s-bn2m[j])*rsqrtf(bn2v[j]+1e-5f)*bn2g[j]+bn2b[j];
    h2g[b][j]=gelu_f(s);
  }
  __syncthreads();
  {
    int b=t>>4, e=t&15;
    float s=g3b[e];
    for(int c=0;c<64;c++) s=fmaf(h2g[b][c], g3w[e*64+c], s);
    sc[b][e]=s;
  }
  __syncthreads();
  if(t<8){
    int b=t;
    float v[16];
    for(int e=0;e<16;e++) v[e]=sc[b][e];
    float vals[4]; int idx[4];
    for(int k=0;k<4;k++){
      float best=-1e30f; int bi=0;
      for(int e=0;e<16;e++) if(v[e]>best){best=v[e];bi=e;}
      vals[k]=best; idx[k]=bi; v[bi]=-1e30f;
    }
    float m=vals[0], ssum=0.f, w[4];
    for(int k=0;k<4;k++){ w[k]=expf((vals[k]-m)*0.5f); ssum+=w[k]; }
    act[b*6+0]=make_float2(0.5f, __int_as_float(0));
    act[b*6+1]=make_float2(0.5f, __int_as_float(1));
    for(int k=0;k<4;k++) act[b*6+2+k]=make_float2(w[k]/ssum, __int_as_float(2+idx[k]));
  }
}

// ---------------- shared + gated experts + residual (MFMA, fast gelu) -----
__global__ __launch_bounds__(256) void final_k(const unsigned short* __restrict__ feats,
  const unsigned short* __restrict__ wall, const float* __restrict__ ball,
  const float2* __restrict__ act, float* __restrict__ out){
  __shared__ __align__(16) unsigned short A[128*72];  // 18432 B; reused as float Fo[32][132]
  int t=threadIdx.x;
  int blk=blockIdx.x, b=blk/288, tile=blk-b*288, hw0=tile*128;
  for(int i=t;i<1024;i+=256){
    int px=i>>3, c0=(i&7)*8, sw=((px>>4)&3)<<3;
    *(uint4*)&A[px*72+(c0^sw)]=*(const uint4*)&feats[(size_t)(b*36864+hw0+px)*64+c0];
  }
  __syncthreads();
  int wave=t>>6, l=t&63, lr=l&15, lg=l>>4;
  int pxb=wave*32;
  bf8v af[2][2];
  #pragma unroll
  for(int fm=0;fm<2;fm++){
    int row=pxb+fm*16+lr, sw=((row>>4)&3)<<3;
    #pragma unroll
    for(int ks=0;ks<2;ks++) af[fm][ks]=*(const bf8v*)&A[row*72+((ks*32+lg*8)^sw)];
  }
  float oa[2][4][4]={};
  #pragma unroll 2
  for(int j=0;j<6;j++){
    float2 aw=act[b*6+j];
    int term=__float_as_int(aw.y);
    float g=aw.x;
    const unsigned short* wp=wall+term*4096;
    const float* bp=ball+term*64;
    bf8v bfv[4][2];
    #pragma unroll
    for(int fn=0;fn<4;fn++)
      #pragma unroll
      for(int ks=0;ks<2;ks++)
        bfv[fn][ks]=*(const bf8v*)(wp+(fn*16+lr)*64+ks*32+lg*8);
    #pragma unroll
    for(int fm=0;fm<2;fm++)
      #pragma unroll
      for(int fn=0;fn<4;fn++){
        f4v acc={0.f,0.f,0.f,0.f};
        acc=MFMA(af[fm][0],bfv[fn][0],acc);
        acc=MFMA(af[fm][1],bfv[fn][1],acc);
        float bs=bp[fn*16+lr];
        #pragma unroll
        for(int r=0;r<4;r++)
          oa[fm][fn][r]=fmaf(g, gelu_fast(acc[r]+bs), oa[fm][fn][r]);
      }
  }
  // coalesced output: repack via LDS, 2 halves of 32 oc
  float* Fo=(float*)A;          // needs 32*132=4224 floats <= 4608
  #pragma unroll
  for(int half=0;half<2;half++){
    __syncthreads();
    #pragma unroll
    for(int fm=0;fm<2;fm++)
      #pragma unroll
      for(int fn2=0;fn2<2;fn2++){
        int fn=half*2+fn2;
        int ocl=fn2*16+lr;
        *(float4*)&Fo[ocl*132 + pxb + fm*16 + 4*lg] =
            make_float4(oa[fm][fn][0],oa[fm][fn][1],oa[fm][fn][2],oa[fm][fn][3]);
      }
    __syncthreads();
    for(int i=t;i<1024;i+=256){
      int ocl=i>>5, px0=(i&31)*4;
      int oc=half*32+ocl;
      size_t base=(size_t)(b*64+oc)*36864 + hw0 + px0;
      float4 rv=*(const float4*)&out[base];
      float4 ov=*(const float4*)&Fo[ocl*132+px0];
      *(float4*)&out[base]=make_float4(ov.x+rv.x,ov.y+rv.y,ov.z+rv.z,ov.w+rv.w);
    }
  }
}

extern "C" void kernel_launch(void* const* d_in, const int* in_sizes, int n_in,
                              void* d_out, int out_size, void* d_ws, size_t ws_size,
                              hipStream_t stream){
  const float* x    =(const float*)d_in[0];
  const float* gn1w =(const float*)d_in[1];
  const float* gn1b =(const float*)d_in[2];
  const float* aw1  =(const float*)d_in[3];
  const float* ab1  =(const float*)d_in[4];
  const float* aw2  =(const float*)d_in[5];
  const float* ab2  =(const float*)d_in[6];
  const float* gn2w =(const float*)d_in[7];
  const float* gn2b =(const float*)d_in[8];
  const float* few  =(const float*)d_in[9];
  const float* feb  =(const float*)d_in[10];
  const float* g1w  =(const float*)d_in[11];
  const float* g1b  =(const float*)d_in[12];
  const float* bn1g =(const float*)d_in[13];
  const float* bn1b =(const float*)d_in[14];
  const float* bn1m =(const float*)d_in[15];
  const float* bn1v =(const float*)d_in[16];
  const float* cw1  =(const float*)d_in[17];
  const float* cb1  =(const float*)d_in[18];
  const float* cw2  =(const float*)d_in[19];
  const float* cb2  =(const float*)d_in[20];
  const float* g2w  =(const float*)d_in[21];
  const float* g2b  =(const float*)d_in[22];
  const float* bn2g =(const float*)d_in[23];
  const float* bn2b =(const float*)d_in[24];
  const float* bn2m =(const float*)d_in[25];
  const float* bn2v =(const float*)d_in[26];
  const float* g3w  =(const float*)d_in[27];
  const float* g3b  =(const float*)d_in[28];
  const float* shw  =(const float*)d_in[29];
  const float* shb  =(const float*)d_in[30];
  const float* exw  =(const float*)d_in[31];
  const float* exb  =(const float*)d_in[32];

  float* out=(float*)d_out;
  float* ws=(float*)d_ws;

  // workspace layout (float offsets)
  float*  part1 = ws;                         // 1024
  float*  part2 = ws+1024;                    // 1024
  float2* sb1   = (float2*)(ws+2048);         // 512 float2
  float2* sb2   = (float2*)(ws+3072);         // 512 float2
  float2* act   = (float2*)(ws+4096);         // 48 float2
  float*  gfp   = ws+4224;                    // 512
  float*  Xm2   = ws+8192;                    // 1048576
  float*  S2    = ws+1056768;                 // 1048576
  unsigned short* Tbl  = (unsigned short*)(ws+2105344);  // 61440 shorts
  unsigned short* wall = (unsigned short*)(ws+2136064);  // 73728 shorts
  float*          ball = ws+2172928;                     // 1152
  unsigned short* wfe  = (unsigned short*)(ws+2174080);  // 4096 shorts
  unsigned short* feats= (unsigned short*)(ws+2176128);  // 18874368 shorts
  const unsigned short* TBf1 = Tbl;
  const unsigned short* TBf2 = Tbl+12288;
  const unsigned short* TAi  = Tbl+36864;
  const unsigned short* TBi  = Tbl+49152;

  prep<<<64,256,0,stream>>>(shw, exw, shb, exb, few, Tbl, wall, ball, wfe, gfp);
  // AFNO on raw x (gn1 via linearity), emits gn1 stats
  fwd_dft <<<512,256,0,stream>>>(x, TBf1, TBf2, Xm2, part1);
  gn_finalize<<<1,64,0,stream>>>(part1, gn1w, gn1b, sb1);
  mode_mlp<<<256,256,0,stream>>>(Xm2, sb1, aw1, ab1, aw2, ab2, S2);
  inv_dft <<<512,256,0,stream>>>(S2, TAi, TBi, x, sb1, out, part2);  // h2 in d_out + gn2 stats
  gn_finalize<<<1,64,0,stream>>>(part2, gn2w, gn2b, sb2);
  // feature extractor + fused gf sums
  feats_k<<<2304,256,0,stream>>>(out, sb2, wfe, feb, feats, gfp);
  gating <<<1,128,0,stream>>>(gfp, g1w,g1b, bn1g,bn1b,bn1m,bn1v,
                              cw1,cb1,cw2,cb2, g2w,g2b, bn2g,bn2b,bn2m,bn2v,
                              g3w,g3b, act);
  // shared + active experts + residual (in-place on d_out)
  final_k<<<2304,256,0,stream>>>(feats, wall, ball, act, out);
}

// Round 6
// 238.710 us; speedup vs baseline: 3.3286x; 1.0186x over previous
//
#include <hip/hip_runtime.h>
#include <math.h>

// Problem constants: B=8, C=64, H=W=192, HW=36864, MODES=32, NB=4, BS=16, E=16
#define TPI 6.283185307179586f

typedef __attribute__((ext_vector_type(8))) short bf8v;   // 8 bf16 (4 VGPRs)
typedef __attribute__((ext_vector_type(4))) float f4v;    // 4 fp32 acc

#define MFMA(a,b,c) __builtin_amdgcn_mfma_f32_16x16x32_bf16((a),(b),(c),0,0,0)

__device__ __forceinline__ float gelu_f(float v){          // exact (erf)
  return 0.5f*v*(1.0f+erff(v*0.7071067811865475f));
}
// tanh-form gelu via fast exp + fast rcp (no IEEE div): err <= ~3e-3 abs
__device__ __forceinline__ float gelu_fast(float x){
  float x2=x*x;
  float inner=fmaf(0.044715f*x2, x, x);
  float e=__expf(1.5957691216057308f*inner);   // exp(2*0.7978845608*inner)
  float r=__builtin_amdgcn_rcpf(1.0f+e);
  return fmaf(-x, r, x);                        // x*(1-r)
}
__device__ __forceinline__ unsigned short f2b(float f){   // f32 -> bf16 (RNE)
  union{float f; unsigned u;} v; v.f=f;
  unsigned r=v.u + 0x7FFFu + ((v.u>>16)&1u);
  return (unsigned short)(r>>16);
}

// ---------------- prep: twiddle tables + bf16 weights + zero gfp -----------
__global__ __launch_bounds__(256) void prep(const float* __restrict__ shw, const float* __restrict__ exw,
    const float* __restrict__ shb, const float* __restrict__ exb, const float* __restrict__ few,
    unsigned short* __restrict__ T, unsigned short* __restrict__ wall, float* __restrict__ ball,
    unsigned short* __restrict__ wfe, float* __restrict__ gfp){
  const float a = TPI/192.0f;
  int stride=gridDim.x*256;
  for(int i=blockIdx.x*256+threadIdx.x; i<61440; i+=stride){
    float v;
    if(i<12288){
      int n1=i/192, w=i%192; int kw=n1>>1, c=n1&1;
      int m=(kw*w)%192; float cs,sn; sincosf((float)m*a,&sn,&cs);
      v = c ? -sn : cs;
    } else if(i<36864){
      int j=i-12288; int n1=j/384, k1=j%384; int kh=n1>>1, d=n1&1; int h=k1>>1, c=k1&1;
      int m=(kh*h)%192; float cs,sn; sincosf((float)m*a,&sn,&cs);
      float e = d ? (c ? cs : -sn) : (c ? sn : cs);
      v = e*(1.0f/192.0f);
    } else if(i<49152){
      int j=i-36864; int h=j/64, k1=j%64; int kh=k1>>1, c=k1&1;
      int m=(h*kh)%192; float cs,sn; sincosf((float)m*a,&sn,&cs);
      v = c ? sn : cs;
    } else {
      int j=i-49152; int w=j/64, k1=j%64; int kw=k1>>1, d=k1&1;
      float f = kw ? (2.0f/192.0f) : (1.0f/192.0f);
      int m=(w*kw)%192; float cs,sn; sincosf((float)m*a,&sn,&cs);
      v = d ? -f*sn : f*cs;
    }
    T[i]=f2b(v);
  }
  for(int i=blockIdx.x*256+threadIdx.x;i<73728;i+=stride) wall[i]=f2b(i<8192?shw[i]:exw[i-8192]);
  for(int i=blockIdx.x*256+threadIdx.x;i<1152;i+=stride)  ball[i]=(i<128)?shb[i]:exb[i-128];
  for(int i=blockIdx.x*256+threadIdx.x;i<4096;i+=stride)  wfe[i]=f2b(few[i]);
  for(int i=blockIdx.x*256+threadIdx.x;i<512;i+=stride)   gfp[i]=0.f;
}

__global__ void gn_finalize(const float* __restrict__ part, const float* __restrict__ gw,
                            const float* __restrict__ gb, float2* __restrict__ sb){
  int g=threadIdx.x; if(g>=64) return;
  float S=0,SS=0;
  for(int j=0;j<8;j++){ S+=part[(g*8+j)*2]; SS+=part[(g*8+j)*2+1]; }
  const float inv=1.0f/294912.0f;
  float mean=S*inv, var=SS*inv-mean*mean;
  float rstd=rsqrtf(var+1e-5f);
  int b=g>>3, gg=g&7;
  for(int k=0;k<8;k++){
    int c=gg*8+k;
    float sc=rstd*gw[c];
    sb[b*64+c]=make_float2(sc, gb[c]-mean*sc);
  }
}

// ---------------- fwd DFT on RAW x (gn1 folded out via linearity) ---------
__global__ __launch_bounds__(256) void fwd_dft(const float* __restrict__ x,
      const unsigned short* __restrict__ TBf1, const unsigned short* __restrict__ TBf2,
      float* __restrict__ Xm2, float* __restrict__ part1){
  __shared__ __align__(16) unsigned short ldsA[64*200];  // Bt1 [64][200]; later tL [32][392]
  __shared__ __align__(16) float sX[2048];
  __shared__ float red[8];
  int t=threadIdx.x, bc=blockIdx.x;
  int wave=t>>6, l=t&63, lr=l&15, lg=l>>4;
  const float* xch = x + (size_t)bc*36864;
  for(int i=t;i<1536;i+=256){
    int row=i/24, chunk=i%24;
    *(uint4*)&ldsA[row*200 + chunk*8] = *(const uint4*)(TBf1 + row*192 + chunk*8);
  }
  __syncthreads();
  float s_=0.f, ss_=0.f;
  // ---- stage 1 ----
  f4v acc1[3][4];
  for(int mt=0;mt<3;mt++){
    int m0=(wave+mt*4)*16;
    const float* xrow = xch + (m0+lr)*192 + lg*8;
    bf8v af[6];
    #pragma unroll
    for(int ks=0;ks<6;ks++){
      float4 u0=*(const float4*)(xrow+ks*32);
      float4 u1=*(const float4*)(xrow+ks*32+4);
      s_ += u0.x+u0.y+u0.z+u0.w+u1.x+u1.y+u1.z+u1.w;
      ss_+= u0.x*u0.x+u0.y*u0.y+u0.z*u0.z+u0.w*u0.w
           +u1.x*u1.x+u1.y*u1.y+u1.z*u1.z+u1.w*u1.w;
      bf8v a;
      a[0]=(short)f2b(u0.x); a[1]=(short)f2b(u0.y); a[2]=(short)f2b(u0.z); a[3]=(short)f2b(u0.w);
      a[4]=(short)f2b(u1.x); a[5]=(short)f2b(u1.y); a[6]=(short)f2b(u1.z); a[7]=(short)f2b(u1.w);
      af[ks]=a;
    }
    #pragma unroll
    for(int nt=0;nt<4;nt++){
      f4v acc={0.f,0.f,0.f,0.f};
      #pragma unroll
      for(int ks=0;ks<6;ks++){
        bf8v b=*(const bf8v*)&ldsA[(nt*16+lr)*200 + ks*32 + lg*8];
        acc=MFMA(af[ks],b,acc);
      }
      acc1[mt][nt]=acc;
    }
  }
  __syncthreads();            // reuse ldsA as tL [32][392]
  for(int mt=0;mt<3;mt++){
    int m0=(wave+mt*4)*16;
    #pragma unroll
    for(int nt=0;nt<4;nt++){
      int n1=nt*16+lr; int kw=n1>>1, c=n1&1;
      #pragma unroll
      for(int reg=0;reg<4;reg++){
        int h=m0+4*lg+reg;
        ldsA[kw*392 + 2*h + c]=f2b(acc1[mt][nt][reg]);
      }
    }
  }
  __syncthreads();
  // ---- stage 2 ----
  for(int pp=0;pp<2;pp++){
    int p=wave+pp*4;
    int m0=(p>>2)*16, n0=(p&3)*16;
    f4v acc={0.f,0.f,0.f,0.f};
    #pragma unroll
    for(int ks=0;ks<12;ks++){
      bf8v a=*(const bf8v*)&ldsA[(m0+lr)*392 + ks*32 + lg*8];
      bf8v b=*(const bf8v*)(TBf2 + (n0+lr)*384 + ks*32 + lg*8);
      acc=MFMA(a,b,acc);
    }
    int n1=n0+lr; int kh=n1>>1, d=n1&1;
    #pragma unroll
    for(int reg=0;reg<4;reg++){
      int kw=m0+4*lg+reg;
      sX[(kh*32+kw)*2 + d]=acc[reg];
    }
  }
  __syncthreads();
  float* dst=Xm2+(size_t)bc*2048;
  for(int i=t;i<512;i+=256) *(float4*)(dst+i*4)=*(const float4*)(sX+i*4);
  // ---- gn1 stats ----
  #pragma unroll
  for(int o=32;o>0;o>>=1){ s_+=__shfl_down(s_,o); ss_+=__shfl_down(ss_,o); }
  if(l==0){ red[wave]=s_; red[4+wave]=ss_; }
  __syncthreads();
  if(t==0){
    part1[bc*2]  =red[0]+red[1]+red[2]+red[3];
    part1[bc*2+1]=red[4]+red[5]+red[6]+red[7];
  }
}

// ---------------- block-diagonal complex 2-layer MLP on modes -------------
__global__ __launch_bounds__(256) void mode_mlp(const float* __restrict__ Xm2, const float2* __restrict__ sb1,
    const float* __restrict__ w1, const float* __restrict__ b1,
    const float* __restrict__ w2, const float* __restrict__ b2,
    float* __restrict__ S2){
  __shared__ float w10[1024], w11[1024], w20[1024], w21[1024];
  __shared__ float b10[64], b11[64], b20[64], b21[64];
  __shared__ float2 sbl[64];
  __shared__ float xr[32][64], xi[32][64];
  __shared__ float o1r[32][64], o1i[32][64];
  int t=threadIdx.x;
  int b=blockIdx.x>>5, kh=blockIdx.x&31;
  for(int i=t;i<1024;i+=256){ w10[i]=w1[i]; w11[i]=w1[1024+i]; w20[i]=w2[i]; w21[i]=w2[1024+i]; }
  if(t<64){ b10[t]=b1[t]; b11[t]=b1[64+t]; b20[t]=b2[t]; b21[t]=b2[64+t]; sbl[t]=sb1[b*64+t]; }
  __syncthreads();
  for(int q=0;q<16;q++){
    int idx=q*256+t; int c=idx>>6, jj=idx&63;
    float2 s=sbl[c];
    float v=Xm2[((size_t)(b*64+c))*2048 + kh*64 + jj]*s.x;
    if(kh==0 && jj==0) v += 192.0f*s.y;
    if(jj&1) xi[jj>>1][c]=v; else xr[jj>>1][c]=v;
  }
  __syncthreads();
  int tl=t&63, n=tl>>4, o=tl&15, wb=n*256+o;
  #pragma unroll
  for(int it=0;it<8;it++){
    int kw=(t>>6)+it*4;
    float a_r=b10[tl], a_i=b11[tl];
    #pragma unroll
    for(int i=0;i<16;i++){
      float rr=xr[kw][n*16+i], im=xi[kw][n*16+i];
      float W0=w10[wb+i*16], W1=w11[wb+i*16];
      a_r=fmaf(rr,W0,fmaf(-im,W1,a_r));
      a_i=fmaf(im,W0,fmaf( rr,W1,a_i));
    }
    o1r[kw][tl]=gelu_f(a_r); o1i[kw][tl]=gelu_f(a_i);
  }
  __syncthreads();
  #pragma unroll
  for(int it=0;it<8;it++){
    int kw=(t>>6)+it*4;
    float c_r=b20[tl], c_i=b21[tl];
    #pragma unroll
    for(int i=0;i<16;i++){
      float rr=o1r[kw][n*16+i], im=o1i[kw][n*16+i];
      float W0=w20[wb+i*16], W1=w21[wb+i*16];
      c_r=fmaf(rr,W0,fmaf(-im,W1,c_r));
      c_i=fmaf(im,W0,fmaf( rr,W1,c_i));
    }
    xr[kw][tl]=c_r; xi[kw][tl]=c_i;
  }
  __syncthreads();
  for(int q=0;q<16;q++){
    int idx=q*256+t; int c=idx>>6, jj=idx&63;
    float v = (jj&1) ? xi[jj>>1][c] : xr[jj>>1][c];
    S2[((size_t)(b*64+c))*2048 + kh*64 + jj]=v;
  }
}

// ---------------- inverse DFT + residuals + gn2 stats ---------------------
__global__ __launch_bounds__(256) void inv_dft(const float* __restrict__ S2,
      const unsigned short* __restrict__ TAi, const unsigned short* __restrict__ TBi,
      const float* __restrict__ x, const float2* __restrict__ sb,
      float* __restrict__ h2, float* __restrict__ part2){
  __shared__ __align__(16) unsigned short Bs[64*72];
  __shared__ __align__(16) unsigned short GL[192*72];
  __shared__ float red[8];
  int t=threadIdx.x, bc=blockIdx.x;
  int wave=t>>6, l=t&63, lr=l&15, lg=l>>4;
  const float* sp=S2+(size_t)bc*2048;
  for(int i=t;i<1024;i+=256){
    int kh=i>>5, kw=i&31;
    float Sr=sp[(kh*32+kw)*2], Si=sp[(kh*32+kw)*2+1];
    unsigned short br=f2b(Sr), bi_=f2b(Si), nbi=f2b(-Si);
    Bs[(2*kw+0)*72 + 2*kh+0]=br;
    Bs[(2*kw+0)*72 + 2*kh+1]=nbi;
    Bs[(2*kw+1)*72 + 2*kh+0]=bi_;
    Bs[(2*kw+1)*72 + 2*kh+1]=br;
  }
  __syncthreads();
  for(int mt=0;mt<3;mt++){
    int m0=(wave+mt*4)*16;
    bf8v a0=*(const bf8v*)(TAi + (m0+lr)*64 + lg*8);
    bf8v a1=*(const bf8v*)(TAi + (m0+lr)*64 + 32 + lg*8);
    #pragma unroll
    for(int nt=0;nt<4;nt++){
      f4v acc={0.f,0.f,0.f,0.f};
      bf8v b0=*(const bf8v*)&Bs[(nt*16+lr)*72 + lg*8];
      bf8v b1=*(const bf8v*)&Bs[(nt*16+lr)*72 + 32 + lg*8];
      acc=MFMA(a0,b0,acc); acc=MFMA(a1,b1,acc);
      #pragma unroll
      for(int reg=0;reg<4;reg++)
        GL[(m0+4*lg+reg)*72 + nt*16+lr]=f2b(acc[reg]);
    }
  }
  __syncthreads();
  float2 sv=sb[bc];
  float cA=sv.x+1.0f, cB=sv.y;
  asm volatile("" : "+v"(cA), "+v"(cB));   // pin to VGPR (constant-bus fix)
  const float* xch=x+(size_t)bc*36864;
  float* och=h2+(size_t)bc*36864;
  float s_=0.f, ss_=0.f;
  for(int mt=0;mt<3;mt++){
    int m0=(wave+mt*4)*16;
    bf8v a0=*(const bf8v*)&GL[(m0+lr)*72 + lg*8];
    bf8v a1=*(const bf8v*)&GL[(m0+lr)*72 + 32 + lg*8];
    for(int nt=0;nt<12;nt++){
      int n0=nt*16;
      f4v acc={0.f,0.f,0.f,0.f};
      bf8v b0=*(const bf8v*)(TBi + (n0+lr)*64 + lg*8);
      bf8v b1=*(const bf8v*)(TBi + (n0+lr)*64 + 32 + lg*8);
      acc=MFMA(a0,b0,acc); acc=MFMA(a1,b1,acc);
      int w=n0+lr;
      #pragma unroll
      for(int reg=0;reg<4;reg++){
        int h=m0+4*lg+reg;
        int ga=h*192+w;
        float xv=xch[ga];
        float val=acc[reg]+fmaf(cA,xv,cB);
        och[ga]=val;
        s_+=val; ss_+=val*val;
      }
    }
  }
  #pragma unroll
  for(int o=32;o>0;o>>=1){ s_+=__shfl_down(s_,o); ss_+=__shfl_down(ss_,o); }
  if(l==0){ red[wave]=s_; red[4+wave]=ss_; }
  __syncthreads();
  if(t==0){
    part2[bc*2]  =red[0]+red[1]+red[2]+red[3];
    part2[bc*2+1]=red[4]+red[5]+red[6]+red[7];
  }
}

// ---------------- gf_k: gating means only (no feats materialization) ------
__global__ __launch_bounds__(256) void gf_k(const float* __restrict__ h2, const float2* __restrict__ sb,
    const unsigned short* __restrict__ wfe, const float* __restrict__ feb,
    float* __restrict__ gfp){
  __shared__ __align__(16) unsigned short A[128*72];
  __shared__ float sgf[64];
  int t=threadIdx.x;
  int blk=blockIdx.x, b=blk/288, tile=blk-b*288, hw0=tile*128;
  if(t<64) sgf[t]=0.f;
  for(int i=t;i<2048;i+=256){
    int c=i>>5, q=i&31;
    float2 s=sb[b*64+c];
    float4 v=*(const float4*)&h2[(size_t)(b*64+c)*36864 + hw0 + q*4];
    int px0=q*4, sw=((px0>>4)&3)<<3, cc=c^sw;
    A[(px0+0)*72+cc]=f2b(fmaf(v.x,s.x,s.y));
    A[(px0+1)*72+cc]=f2b(fmaf(v.y,s.x,s.y));
    A[(px0+2)*72+cc]=f2b(fmaf(v.z,s.x,s.y));
    A[(px0+3)*72+cc]=f2b(fmaf(v.w,s.x,s.y));
  }
  __syncthreads();
  int wave=t>>6, l=t&63, lr=l&15, lg=l>>4;
  int pxb=wave*32;
  bf8v af[2][2], bfv[4][2];
  #pragma unroll
  for(int fm=0;fm<2;fm++){
    int row=pxb+fm*16+lr, sw=((row>>4)&3)<<3;
    #pragma unroll
    for(int ks=0;ks<2;ks++) af[fm][ks]=*(const bf8v*)&A[row*72+((ks*32+lg*8)^sw)];
  }
  #pragma unroll
  for(int fn=0;fn<4;fn++)
    #pragma unroll
    for(int ks=0;ks<2;ks++)
      bfv[fn][ks]=*(const bf8v*)(wfe+(fn*16+lr)*64+ks*32+lg*8);
  float gsum[4]={0.f,0.f,0.f,0.f};
  #pragma unroll
  for(int fm=0;fm<2;fm++)
    #pragma unroll
    for(int fn=0;fn<4;fn++){
      f4v acc={0.f,0.f,0.f,0.f};
      acc=MFMA(af[fm][0],bfv[fn][0],acc);
      acc=MFMA(af[fm][1],bfv[fn][1],acc);
      float bs=feb[fn*16+lr];
      #pragma unroll
      for(int r=0;r<4;r++) gsum[fn]+=gelu_f(acc[r]+bs);
    }
  #pragma unroll
  for(int fn=0;fn<4;fn++){
    float v=gsum[fn];
    v+=__shfl_xor(v,16); v+=__shfl_xor(v,32);
    if(lg==0) atomicAdd(&sgf[fn*16+lr], v);
  }
  __syncthreads();
  if(t<64) atomicAdd(&gfp[b*64+t], sgf[t]);
}

// ---------------- gating MLP + top-4 softmax -> active-term list ----------
__global__ __launch_bounds__(128) void gating(const float* __restrict__ gfp,
  const float* __restrict__ g1w, const float* __restrict__ g1b,
  const float* __restrict__ bn1g, const float* __restrict__ bn1b, const float* __restrict__ bn1m, const float* __restrict__ bn1v,
  const float* __restrict__ cw1, const float* __restrict__ cb1, const float* __restrict__ cw2, const float* __restrict__ cb2,
  const float* __restrict__ g2w, const float* __restrict__ g2b,
  const float* __restrict__ bn2g, const float* __restrict__ bn2b, const float* __restrict__ bn2m, const float* __restrict__ bn2v,
  const float* __restrict__ g3w, const float* __restrict__ g3b, float2* __restrict__ act){
  __shared__ float gf[8][64];
  __shared__ float h1[8][128];
  __shared__ float a1[8][8];
  __shared__ float h2g[8][64];
  __shared__ float sc[8][16];
  int t=threadIdx.x;
  for(int i=t;i<512;i+=128) gf[i>>6][i&63]=gfp[i]*(1.0f/36864.0f);
  __syncthreads();
  for(int i=t;i<1024;i+=128){
    int b=i>>7, j=i&127;
    float s=g1b[j];
    for(int c=0;c<64;c++) s=fmaf(gf[b][c], g1w[j*64+c], s);
    s=(s-bn1m[j])*rsqrtf(bn1v[j]+1e-5f)*bn1g[j]+bn1b[j];
    h1[b][j]=gelu_f(s);
  }
  __syncthreads();
  if(t<64){
    int b=t>>3, k=t&7; float s=cb1[k];
    for(int j=0;j<128;j++) s=fmaf(h1[b][j], cw1[k*128+j], s);
    a1[b][k]=gelu_f(s);
  }
  __syncthreads();
  for(int i=t;i<1024;i+=128){
    int b=i>>7, j=i&127;
    float s=cb2[j];
    for(int k=0;k<8;k++) s=fmaf(a1[b][k], cw2[j*8+k], s);
    h1[b][j]=h1[b][j]/(1.0f+expf(-2.0f*s));
  }
  __syncthreads();
  for(int i=t;i<512;i+=128){
    int b=i>>6, j=i&63;
    float s=g2b[j];
    for(int k=0;k<128;k++) s=fmaf(h1[b][k], g2w[j*128+k], s);
    s=(s-bn2m[j])*rsqrtf(bn2v[j]+1e-5f)*bn2g[j]+bn2b[j];
    h2g[b][j]=gelu_f(s);
  }
  __syncthreads();
  {
    int b=t>>4, e=t&15;
    float s=g3b[e];
    for(int c=0;c<64;c++) s=fmaf(h2g[b][c], g3w[e*64+c], s);
    sc[b][e]=s;
  }
  __syncthreads();
  if(t<8){
    int b=t;
    float v[16];
    for(int e=0;e<16;e++) v[e]=sc[b][e];
    float vals[4]; int idx[4];
    for(int k=0;k<4;k++){
      float best=-1e30f; int bi=0;
      for(int e=0;e<16;e++) if(v[e]>best){best=v[e];bi=e;}
      vals[k]=best; idx[k]=bi; v[bi]=-1e30f;
    }
    float m=vals[0], ssum=0.f, w[4];
    for(int k=0;k<4;k++){ w[k]=expf((vals[k]-m)*0.5f); ssum+=w[k]; }
    act[b*6+0]=make_float2(0.5f, __int_as_float(0));
    act[b*6+1]=make_float2(0.5f, __int_as_float(1));
    for(int k=0;k<4;k++) act[b*6+2+k]=make_float2(w[k]/ssum, __int_as_float(2+idx[k]));
  }
}

// ---------------- fused feats-recompute + experts + residual --------------
// reads h2 (= out), recomputes feats tile in LDS, runs 6 active terms,
// writes out += expert_sum (coalesced RMW via LDS repack).
__global__ __launch_bounds__(256) void final_k(const float* __restrict__ h2, const float2* __restrict__ sb,
  const unsigned short* __restrict__ wfe, const float* __restrict__ feb,
  const unsigned short* __restrict__ wall, const float* __restrict__ ball,
  const float2* __restrict__ act, float* __restrict__ out){
  __shared__ __align__(16) unsigned short A[128*72];  // gn2(h2) tile -> feats tile -> float Fo[32][132]
  int t=threadIdx.x;
  int blk=blockIdx.x, b=blk/288, tile=blk-b*288, hw0=tile*128;
  // stage gn2(h2) tile (bf16, swizzled)
  for(int i=t;i<2048;i+=256){
    int c=i>>5, q=i&31;
    float2 s=sb[b*64+c];
    float4 v=*(const float4*)&h2[(size_t)(b*64+c)*36864 + hw0 + q*4];
    int px0=q*4, sw=((px0>>4)&3)<<3, cc=c^sw;
    A[(px0+0)*72+cc]=f2b(fmaf(v.x,s.x,s.y));
    A[(px0+1)*72+cc]=f2b(fmaf(v.y,s.x,s.y));
    A[(px0+2)*72+cc]=f2b(fmaf(v.z,s.x,s.y));
    A[(px0+3)*72+cc]=f2b(fmaf(v.w,s.x,s.y));
  }
  __syncthreads();
  int wave=t>>6, l=t&63, lr=l&15, lg=l>>4;
  int pxb=wave*32;
  // ---- recompute feats tile ----
  bf8v af[2][2], bfe[4][2];
  #pragma unroll
  for(int fm=0;fm<2;fm++){
    int row=pxb+fm*16+lr, sw=((row>>4)&3)<<3;
    #pragma unroll
    for(int ks=0;ks<2;ks++) af[fm][ks]=*(const bf8v*)&A[row*72+((ks*32+lg*8)^sw)];
  }
  #pragma unroll
  for(int fn=0;fn<4;fn++)
    #pragma unroll
    for(int ks=0;ks<2;ks++)
      bfe[fn][ks]=*(const bf8v*)(wfe+(fn*16+lr)*64+ks*32+lg*8);
  unsigned short pf[2][4][4];
  #pragma unroll
  for(int fm=0;fm<2;fm++)
    #pragma unroll
    for(int fn=0;fn<4;fn++){
      f4v acc={0.f,0.f,0.f,0.f};
      acc=MFMA(af[fm][0],bfe[fn][0],acc);
      acc=MFMA(af[fm][1],bfe[fn][1],acc);
      float bs=feb[fn*16+lr];
      #pragma unroll
      for(int r=0;r<4;r++) pf[fm][fn][r]=f2b(gelu_fast(acc[r]+bs));
    }
  __syncthreads();            // all reads of gn2-tile done
  #pragma unroll
  for(int fm=0;fm<2;fm++){
    int sw=(((pxb+fm*16)>>4)&3)<<3;     // px>>4 constant within fm block
    #pragma unroll
    for(int fn=0;fn<4;fn++){
      int cc=(fn*16+lr)^sw;
      #pragma unroll
      for(int r=0;r<4;r++)
        A[(pxb+fm*16+4*lg+r)*72+cc]=pf[fm][fn][r];
    }
  }
  __syncthreads();
  // ---- expert terms ----
  bf8v af2[2][2];
  #pragma unroll
  for(int fm=0;fm<2;fm++){
    int row=pxb+fm*16+lr, sw=((row>>4)&3)<<3;
    #pragma unroll
    for(int ks=0;ks<2;ks++) af2[fm][ks]=*(const bf8v*)&A[row*72+((ks*32+lg*8)^sw)];
  }
  float oa[2][4][4]={};
  #pragma unroll 2
  for(int j=0;j<6;j++){
    float2 aw=act[b*6+j];
    int term=__float_as_int(aw.y);
    float g=aw.x;
    const unsigned short* wp=wall+term*4096;
    const float* bp=ball+term*64;
    bf8v bfv[4][2];
    #pragma unroll
    for(int fn=0;fn<4;fn++)
      #pragma unroll
      for(int ks=0;ks<2;ks++)
        bfv[fn][ks]=*(const bf8v*)(wp+(fn*16+lr)*64+ks*32+lg*8);
    #pragma unroll
    for(int fm=0;fm<2;fm++)
      #pragma unroll
      for(int fn=0;fn<4;fn++){
        f4v acc={0.f,0.f,0.f,0.f};
        acc=MFMA(af2[fm][0],bfv[fn][0],acc);
        acc=MFMA(af2[fm][1],bfv[fn][1],acc);
        float bs=bp[fn*16+lr];
        #pragma unroll
        for(int r=0;r<4;r++)
          oa[fm][fn][r]=fmaf(g, gelu_fast(acc[r]+bs), oa[fm][fn][r]);
      }
  }
  // ---- coalesced output: repack via LDS, 2 halves of 32 oc ----
  float* Fo=(float*)A;          // 32*132=4224 floats fits in 4608
  #pragma unroll
  for(int half=0;half<2;half++){
    __syncthreads();
    #pragma unroll
    for(int fm=0;fm<2;fm++)
      #pragma unroll
      for(int fn2=0;fn2<2;fn2++){
        int fn=half*2+fn2;
        int ocl=fn2*16+lr;
        *(float4*)&Fo[ocl*132 + pxb + fm*16 + 4*lg] =
            make_float4(oa[fm][fn][0],oa[fm][fn][1],oa[fm][fn][2],oa[fm][fn][3]);
      }
    __syncthreads();
    for(int i=t;i<1024;i+=256){
      int ocl=i>>5, px0=(i&31)*4;
      int oc=half*32+ocl;
      size_t base=(size_t)(b*64+oc)*36864 + hw0 + px0;
      float4 rv=*(const float4*)&out[base];
      float4 ov=*(const float4*)&Fo[ocl*132+px0];
      *(float4*)&out[base]=make_float4(ov.x+rv.x,ov.y+rv.y,ov.z+rv.z,ov.w+rv.w);
    }
  }
}

extern "C" void kernel_launch(void* const* d_in, const int* in_sizes, int n_in,
                              void* d_out, int out_size, void* d_ws, size_t ws_size,
                              hipStream_t stream){
  const float* x    =(const float*)d_in[0];
  const float* gn1w =(const float*)d_in[1];
  const float* gn1b =(const float*)d_in[2];
  const float* aw1  =(const float*)d_in[3];
  const float* ab1  =(const float*)d_in[4];
  const float* aw2  =(const float*)d_in[5];
  const float* ab2  =(const float*)d_in[6];
  const float* gn2w =(const float*)d_in[7];
  const float* gn2b =(const float*)d_in[8];
  const float* few  =(const float*)d_in[9];
  const float* feb  =(const float*)d_in[10];
  const float* g1w  =(const float*)d_in[11];
  const float* g1b  =(const float*)d_in[12];
  const float* bn1g =(const float*)d_in[13];
  const float* bn1b =(const float*)d_in[14];
  const float* bn1m =(const float*)d_in[15];
  const float* bn1v =(const float*)d_in[16];
  const float* cw1  =(const float*)d_in[17];
  const float* cb1  =(const float*)d_in[18];
  const float* cw2  =(const float*)d_in[19];
  const float* cb2  =(const float*)d_in[20];
  const float* g2w  =(const float*)d_in[21];
  const float* g2b  =(const float*)d_in[22];
  const float* bn2g =(const float*)d_in[23];
  const float* bn2b =(const float*)d_in[24];
  const float* bn2m =(const float*)d_in[25];
  const float* bn2v =(const float*)d_in[26];
  const float* g3w  =(const float*)d_in[27];
  const float* g3b  =(const float*)d_in[28];
  const float* shw  =(const float*)d_in[29];
  const float* shb  =(const float*)d_in[30];
  const float* exw  =(const float*)d_in[31];
  const float* exb  =(const float*)d_in[32];

  float* out=(float*)d_out;
  float* ws=(float*)d_ws;

  // workspace layout (float offsets)
  float*  part1 = ws;                         // 1024
  float*  part2 = ws+1024;                    // 1024
  float2* sb1   = (float2*)(ws+2048);         // 512 float2
  float2* sb2   = (float2*)(ws+3072);         // 512 float2
  float2* act   = (float2*)(ws+4096);         // 48 float2
  float*  gfp   = ws+4224;                    // 512
  float*  Xm2   = ws+8192;                    // 1048576
  float*  S2    = ws+1056768;                 // 1048576
  unsigned short* Tbl  = (unsigned short*)(ws+2105344);  // 61440 shorts
  unsigned short* wall = (unsigned short*)(ws+2136064);  // 73728 shorts
  float*          ball = ws+2172928;                     // 1152
  unsigned short* wfe  = (unsigned short*)(ws+2174080);  // 4096 shorts
  const unsigned short* TBf1 = Tbl;
  const unsigned short* TBf2 = Tbl+12288;
  const unsigned short* TAi  = Tbl+36864;
  const unsigned short* TBi  = Tbl+49152;

  prep<<<64,256,0,stream>>>(shw, exw, shb, exb, few, Tbl, wall, ball, wfe, gfp);
  // AFNO on raw x (gn1 via linearity), emits gn1 stats
  fwd_dft <<<512,256,0,stream>>>(x, TBf1, TBf2, Xm2, part1);
  gn_finalize<<<1,64,0,stream>>>(part1, gn1w, gn1b, sb1);
  mode_mlp<<<256,256,0,stream>>>(Xm2, sb1, aw1, ab1, aw2, ab2, S2);
  inv_dft <<<512,256,0,stream>>>(S2, TAi, TBi, x, sb1, out, part2);  // h2 in d_out + gn2 stats
  gn_finalize<<<1,64,0,stream>>>(part2, gn2w, gn2b, sb2);
  // gating means (no feats materialization)
  gf_k<<<2304,256,0,stream>>>(out, sb2, wfe, feb, gfp);
  gating <<<1,128,0,stream>>>(gfp, g1w,g1b, bn1g,bn1b,bn1m,bn1v,
                              cw1,cb1,cw2,cb2, g2w,g2b, bn2g,bn2b,bn2m,bn2v,
                              g3w,g3b, act);
  // fused feats-recompute + shared/active experts + residual (in-place on d_out)
  final_k<<<2304,256,0,stream>>>(out, sb2, wfe, feb, wall, ball, act, out);
}

// Round 7
// 229.357 us; speedup vs baseline: 3.4643x; 1.0408x over previous
//
#include <hip/hip_runtime.h>
#include <math.h>

// Problem constants: B=8, C=64, H=W=192, HW=36864, MODES=32, NB=4, BS=16, E=16
#define TPI 6.283185307179586f

typedef __attribute__((ext_vector_type(8))) short bf8v;   // 8 bf16 (4 VGPRs)
typedef __attribute__((ext_vector_type(4))) float f4v;    // 4 fp32 acc

#define MFMA(a,b,c) __builtin_amdgcn_mfma_f32_16x16x32_bf16((a),(b),(c),0,0,0)

__device__ __forceinline__ float gelu_f(float v){          // exact (erf)
  return 0.5f*v*(1.0f+erff(v*0.7071067811865475f));
}
// tanh-form gelu via fast exp + fast rcp (no IEEE div): err <= ~3e-3 abs
__device__ __forceinline__ float gelu_fast(float x){
  float x2=x*x;
  float inner=fmaf(0.044715f*x2, x, x);
  float e=__expf(1.5957691216057308f*inner);   // exp(2*0.7978845608*inner)
  float r=__builtin_amdgcn_rcpf(1.0f+e);
  return fmaf(-x, r, x);                        // x*(1-r)
}
__device__ __forceinline__ unsigned short f2b(float f){   // f32 -> bf16 (RNE)
  union{float f; unsigned u;} v; v.f=f;
  unsigned r=v.u + 0x7FFFu + ((v.u>>16)&1u);
  return (unsigned short)(r>>16);
}

// ---------------- prep: twiddle tables + bf16 weights + zero gfp -----------
__global__ __launch_bounds__(256) void prep(const float* __restrict__ shw, const float* __restrict__ exw,
    const float* __restrict__ shb, const float* __restrict__ exb, const float* __restrict__ few,
    unsigned short* __restrict__ T, unsigned short* __restrict__ wall, float* __restrict__ ball,
    unsigned short* __restrict__ wfe, float* __restrict__ gfp){
  const float a = TPI/192.0f;
  int stride=gridDim.x*256;
  for(int i=blockIdx.x*256+threadIdx.x; i<61440; i+=stride){
    float v;
    if(i<12288){
      int n1=i/192, w=i%192; int kw=n1>>1, c=n1&1;
      int m=(kw*w)%192; float cs,sn; sincosf((float)m*a,&sn,&cs);
      v = c ? -sn : cs;
    } else if(i<36864){
      int j=i-12288; int n1=j/384, k1=j%384; int kh=n1>>1, d=n1&1; int h=k1>>1, c=k1&1;
      int m=(kh*h)%192; float cs,sn; sincosf((float)m*a,&sn,&cs);
      float e = d ? (c ? cs : -sn) : (c ? sn : cs);
      v = e*(1.0f/192.0f);
    } else if(i<49152){
      int j=i-36864; int h=j/64, k1=j%64; int kh=k1>>1, c=k1&1;
      int m=(h*kh)%192; float cs,sn; sincosf((float)m*a,&sn,&cs);
      v = c ? sn : cs;
    } else {
      int j=i-49152; int w=j/64, k1=j%64; int kw=k1>>1, d=k1&1;
      float f = kw ? (2.0f/192.0f) : (1.0f/192.0f);
      int m=(w*kw)%192; float cs,sn; sincosf((float)m*a,&sn,&cs);
      v = d ? -f*sn : f*cs;
    }
    T[i]=f2b(v);
  }
  for(int i=blockIdx.x*256+threadIdx.x;i<73728;i+=stride) wall[i]=f2b(i<8192?shw[i]:exw[i-8192]);
  for(int i=blockIdx.x*256+threadIdx.x;i<1152;i+=stride)  ball[i]=(i<128)?shb[i]:exb[i-128];
  for(int i=blockIdx.x*256+threadIdx.x;i<4096;i+=stride)  wfe[i]=f2b(few[i]);
  for(int i=blockIdx.x*256+threadIdx.x;i<512;i+=stride)   gfp[i]=0.f;
}

__global__ void gn_finalize(const float* __restrict__ part, const float* __restrict__ gw,
                            const float* __restrict__ gb, float2* __restrict__ sb){
  int g=threadIdx.x; if(g>=64) return;
  float S=0,SS=0;
  for(int j=0;j<8;j++){ S+=part[(g*8+j)*2]; SS+=part[(g*8+j)*2+1]; }
  const float inv=1.0f/294912.0f;
  float mean=S*inv, var=SS*inv-mean*mean;
  float rstd=rsqrtf(var+1e-5f);
  int b=g>>3, gg=g&7;
  for(int k=0;k<8;k++){
    int c=gg*8+k;
    float sc=rstd*gw[c];
    sb[b*64+c]=make_float2(sc, gb[c]-mean*sc);
  }
}

// ---------------- fwd DFT on RAW x (gn1 folded out via linearity) ---------
__global__ __launch_bounds__(256) void fwd_dft(const float* __restrict__ x,
      const unsigned short* __restrict__ TBf1, const unsigned short* __restrict__ TBf2,
      float* __restrict__ Xm2, float* __restrict__ part1){
  __shared__ __align__(16) unsigned short ldsA[64*200];  // Bt1 [64][200]; later tL [32][392]
  __shared__ __align__(16) float sX[2048];
  __shared__ float red[8];
  int t=threadIdx.x, bc=blockIdx.x;
  int wave=t>>6, l=t&63, lr=l&15, lg=l>>4;
  const float* xch = x + (size_t)bc*36864;
  for(int i=t;i<1536;i+=256){
    int row=i/24, chunk=i%24;
    *(uint4*)&ldsA[row*200 + chunk*8] = *(const uint4*)(TBf1 + row*192 + chunk*8);
  }
  __syncthreads();
  float s_=0.f, ss_=0.f;
  // ---- stage 1 ----
  f4v acc1[3][4];
  for(int mt=0;mt<3;mt++){
    int m0=(wave+mt*4)*16;
    const float* xrow = xch + (m0+lr)*192 + lg*8;
    bf8v af[6];
    #pragma unroll
    for(int ks=0;ks<6;ks++){
      float4 u0=*(const float4*)(xrow+ks*32);
      float4 u1=*(const float4*)(xrow+ks*32+4);
      s_ += u0.x+u0.y+u0.z+u0.w+u1.x+u1.y+u1.z+u1.w;
      ss_+= u0.x*u0.x+u0.y*u0.y+u0.z*u0.z+u0.w*u0.w
           +u1.x*u1.x+u1.y*u1.y+u1.z*u1.z+u1.w*u1.w;
      bf8v a;
      a[0]=(short)f2b(u0.x); a[1]=(short)f2b(u0.y); a[2]=(short)f2b(u0.z); a[3]=(short)f2b(u0.w);
      a[4]=(short)f2b(u1.x); a[5]=(short)f2b(u1.y); a[6]=(short)f2b(u1.z); a[7]=(short)f2b(u1.w);
      af[ks]=a;
    }
    #pragma unroll
    for(int nt=0;nt<4;nt++){
      f4v acc={0.f,0.f,0.f,0.f};
      #pragma unroll
      for(int ks=0;ks<6;ks++){
        bf8v b=*(const bf8v*)&ldsA[(nt*16+lr)*200 + ks*32 + lg*8];
        acc=MFMA(af[ks],b,acc);
      }
      acc1[mt][nt]=acc;
    }
  }
  __syncthreads();            // reuse ldsA as tL [32][392]
  for(int mt=0;mt<3;mt++){
    int m0=(wave+mt*4)*16;
    #pragma unroll
    for(int nt=0;nt<4;nt++){
      int n1=nt*16+lr; int kw=n1>>1, c=n1&1;
      #pragma unroll
      for(int reg=0;reg<4;reg++){
        int h=m0+4*lg+reg;
        ldsA[kw*392 + 2*h + c]=f2b(acc1[mt][nt][reg]);
      }
    }
  }
  __syncthreads();
  // ---- stage 2 ----
  for(int pp=0;pp<2;pp++){
    int p=wave+pp*4;
    int m0=(p>>2)*16, n0=(p&3)*16;
    f4v acc={0.f,0.f,0.f,0.f};
    #pragma unroll
    for(int ks=0;ks<12;ks++){
      bf8v a=*(const bf8v*)&ldsA[(m0+lr)*392 + ks*32 + lg*8];
      bf8v b=*(const bf8v*)(TBf2 + (n0+lr)*384 + ks*32 + lg*8);
      acc=MFMA(a,b,acc);
    }
    int n1=n0+lr; int kh=n1>>1, d=n1&1;
    #pragma unroll
    for(int reg=0;reg<4;reg++){
      int kw=m0+4*lg+reg;
      sX[(kh*32+kw)*2 + d]=acc[reg];
    }
  }
  __syncthreads();
  float* dst=Xm2+(size_t)bc*2048;
  for(int i=t;i<512;i+=256) *(float4*)(dst+i*4)=*(const float4*)(sX+i*4);
  // ---- gn1 stats ----
  #pragma unroll
  for(int o=32;o>0;o>>=1){ s_+=__shfl_down(s_,o); ss_+=__shfl_down(ss_,o); }
  if(l==0){ red[wave]=s_; red[4+wave]=ss_; }
  __syncthreads();
  if(t==0){
    part1[bc*2]  =red[0]+red[1]+red[2]+red[3];
    part1[bc*2+1]=red[4]+red[5]+red[6]+red[7];
  }
}

// ---------------- block-diagonal complex 2-layer MLP on modes -------------
__global__ __launch_bounds__(256) void mode_mlp(const float* __restrict__ Xm2, const float2* __restrict__ sb1,
    const float* __restrict__ w1, const float* __restrict__ b1,
    const float* __restrict__ w2, const float* __restrict__ b2,
    float* __restrict__ S2){
  __shared__ float w10[1024], w11[1024], w20[1024], w21[1024];
  __shared__ float b10[64], b11[64], b20[64], b21[64];
  __shared__ float2 sbl[64];
  __shared__ float xr[32][64], xi[32][64];
  __shared__ float o1r[32][64], o1i[32][64];
  int t=threadIdx.x;
  int b=blockIdx.x>>5, kh=blockIdx.x&31;
  for(int i=t;i<1024;i+=256){ w10[i]=w1[i]; w11[i]=w1[1024+i]; w20[i]=w2[i]; w21[i]=w2[1024+i]; }
  if(t<64){ b10[t]=b1[t]; b11[t]=b1[64+t]; b20[t]=b2[t]; b21[t]=b2[64+t]; sbl[t]=sb1[b*64+t]; }
  __syncthreads();
  for(int q=0;q<16;q++){
    int idx=q*256+t; int c=idx>>6, jj=idx&63;
    float2 s=sbl[c];
    float v=Xm2[((size_t)(b*64+c))*2048 + kh*64 + jj]*s.x;
    if(kh==0 && jj==0) v += 192.0f*s.y;
    if(jj&1) xi[jj>>1][c]=v; else xr[jj>>1][c]=v;
  }
  __syncthreads();
  int tl=t&63, n=tl>>4, o=tl&15, wb=n*256+o;
  #pragma unroll
  for(int it=0;it<8;it++){
    int kw=(t>>6)+it*4;
    float a_r=b10[tl], a_i=b11[tl];
    #pragma unroll
    for(int i=0;i<16;i++){
      float rr=xr[kw][n*16+i], im=xi[kw][n*16+i];
      float W0=w10[wb+i*16], W1=w11[wb+i*16];
      a_r=fmaf(rr,W0,fmaf(-im,W1,a_r));
      a_i=fmaf(im,W0,fmaf( rr,W1,a_i));
    }
    o1r[kw][tl]=gelu_f(a_r); o1i[kw][tl]=gelu_f(a_i);
  }
  __syncthreads();
  #pragma unroll
  for(int it=0;it<8;it++){
    int kw=(t>>6)+it*4;
    float c_r=b20[tl], c_i=b21[tl];
    #pragma unroll
    for(int i=0;i<16;i++){
      float rr=o1r[kw][n*16+i], im=o1i[kw][n*16+i];
      float W0=w20[wb+i*16], W1=w21[wb+i*16];
      c_r=fmaf(rr,W0,fmaf(-im,W1,c_r));
      c_i=fmaf(im,W0,fmaf( rr,W1,c_i));
    }
    xr[kw][tl]=c_r; xi[kw][tl]=c_i;
  }
  __syncthreads();
  for(int q=0;q<16;q++){
    int idx=q*256+t; int c=idx>>6, jj=idx&63;
    float v = (jj&1) ? xi[jj>>1][c] : xr[jj>>1][c];
    S2[((size_t)(b*64+c))*2048 + kh*64 + jj]=v;
  }
}

// ---------------- inverse DFT + residuals + gn2 stats ---------------------
__global__ __launch_bounds__(256) void inv_dft(const float* __restrict__ S2,
      const unsigned short* __restrict__ TAi, const unsigned short* __restrict__ TBi,
      const float* __restrict__ x, const float2* __restrict__ sb,
      float* __restrict__ h2, float* __restrict__ part2){
  __shared__ __align__(16) unsigned short Bs[64*72];
  __shared__ __align__(16) unsigned short GL[192*72];
  __shared__ float red[8];
  int t=threadIdx.x, bc=blockIdx.x;
  int wave=t>>6, l=t&63, lr=l&15, lg=l>>4;
  const float* sp=S2+(size_t)bc*2048;
  for(int i=t;i<1024;i+=256){
    int kh=i>>5, kw=i&31;
    float Sr=sp[(kh*32+kw)*2], Si=sp[(kh*32+kw)*2+1];
    unsigned short br=f2b(Sr), bi_=f2b(Si), nbi=f2b(-Si);
    Bs[(2*kw+0)*72 + 2*kh+0]=br;
    Bs[(2*kw+0)*72 + 2*kh+1]=nbi;
    Bs[(2*kw+1)*72 + 2*kh+0]=bi_;
    Bs[(2*kw+1)*72 + 2*kh+1]=br;
  }
  __syncthreads();
  for(int mt=0;mt<3;mt++){
    int m0=(wave+mt*4)*16;
    bf8v a0=*(const bf8v*)(TAi + (m0+lr)*64 + lg*8);
    bf8v a1=*(const bf8v*)(TAi + (m0+lr)*64 + 32 + lg*8);
    #pragma unroll
    for(int nt=0;nt<4;nt++){
      f4v acc={0.f,0.f,0.f,0.f};
      bf8v b0=*(const bf8v*)&Bs[(nt*16+lr)*72 + lg*8];
      bf8v b1=*(const bf8v*)&Bs[(nt*16+lr)*72 + 32 + lg*8];
      acc=MFMA(a0,b0,acc); acc=MFMA(a1,b1,acc);
      #pragma unroll
      for(int reg=0;reg<4;reg++)
        GL[(m0+4*lg+reg)*72 + nt*16+lr]=f2b(acc[reg]);
    }
  }
  __syncthreads();
  float2 sv=sb[bc];
  float cA=sv.x+1.0f, cB=sv.y;
  asm volatile("" : "+v"(cA), "+v"(cB));   // pin to VGPR (constant-bus fix)
  const float* xch=x+(size_t)bc*36864;
  float* och=h2+(size_t)bc*36864;
  float s_=0.f, ss_=0.f;
  for(int mt=0;mt<3;mt++){
    int m0=(wave+mt*4)*16;
    bf8v a0=*(const bf8v*)&GL[(m0+lr)*72 + lg*8];
    bf8v a1=*(const bf8v*)&GL[(m0+lr)*72 + 32 + lg*8];
    for(int nt=0;nt<12;nt++){
      int n0=nt*16;
      f4v acc={0.f,0.f,0.f,0.f};
      bf8v b0=*(const bf8v*)(TBi + (n0+lr)*64 + lg*8);
      bf8v b1=*(const bf8v*)(TBi + (n0+lr)*64 + 32 + lg*8);
      acc=MFMA(a0,b0,acc); acc=MFMA(a1,b1,acc);
      int w=n0+lr;
      #pragma unroll
      for(int reg=0;reg<4;reg++){
        int h=m0+4*lg+reg;
        int ga=h*192+w;
        float xv=xch[ga];
        float val=acc[reg]+fmaf(cA,xv,cB);
        och[ga]=val;
        s_+=val; ss_+=val*val;
      }
    }
  }
  #pragma unroll
  for(int o=32;o>0;o>>=1){ s_+=__shfl_down(s_,o); ss_+=__shfl_down(ss_,o); }
  if(l==0){ red[wave]=s_; red[4+wave]=ss_; }
  __syncthreads();
  if(t==0){
    part2[bc*2]  =red[0]+red[1]+red[2]+red[3];
    part2[bc*2+1]=red[4]+red[5]+red[6]+red[7];
  }
}

// ---------------- gf_k: gating means only (no feats materialization) ------
__global__ __launch_bounds__(256,4) void gf_k(const float* __restrict__ h2, const float2* __restrict__ sb,
    const unsigned short* __restrict__ wfe, const float* __restrict__ feb,
    float* __restrict__ gfp){
  __shared__ __align__(16) unsigned short A[128*72];
  __shared__ float sgf[64];
  int t=threadIdx.x;
  int blk=blockIdx.x, b=blk/288, tile=blk-b*288, hw0=tile*128;
  if(t<64) sgf[t]=0.f;
  for(int i=t;i<2048;i+=256){
    int c=i>>5, q=i&31;
    float2 s=sb[b*64+c];
    float4 v=*(const float4*)&h2[(size_t)(b*64+c)*36864 + hw0 + q*4];
    int px0=q*4, sw=((px0>>4)&3)<<3, cc=c^sw;
    A[(px0+0)*72+cc]=f2b(fmaf(v.x,s.x,s.y));
    A[(px0+1)*72+cc]=f2b(fmaf(v.y,s.x,s.y));
    A[(px0+2)*72+cc]=f2b(fmaf(v.z,s.x,s.y));
    A[(px0+3)*72+cc]=f2b(fmaf(v.w,s.x,s.y));
  }
  __syncthreads();
  int wave=t>>6, l=t&63, lr=l&15, lg=l>>4;
  int pxb=wave*32;
  bf8v af[2][2];
  #pragma unroll
  for(int fm=0;fm<2;fm++){
    int row=pxb+fm*16+lr, sw=((row>>4)&3)<<3;
    #pragma unroll
    for(int ks=0;ks<2;ks++) af[fm][ks]=*(const bf8v*)&A[row*72+((ks*32+lg*8)^sw)];
  }
  float gsum[4]={0.f,0.f,0.f,0.f};
  #pragma unroll
  for(int fn=0;fn<4;fn++){
    bf8v b0=*(const bf8v*)(wfe+(fn*16+lr)*64+lg*8);
    bf8v b1=*(const bf8v*)(wfe+(fn*16+lr)*64+32+lg*8);
    float bs=feb[fn*16+lr];
    #pragma unroll
    for(int fm=0;fm<2;fm++){
      f4v acc={0.f,0.f,0.f,0.f};
      acc=MFMA(af[fm][0],b0,acc);
      acc=MFMA(af[fm][1],b1,acc);
      #pragma unroll
      for(int r=0;r<4;r++) gsum[fn]+=gelu_f(acc[r]+bs);
    }
  }
  #pragma unroll
  for(int fn=0;fn<4;fn++){
    float v=gsum[fn];
    v+=__shfl_xor(v,16); v+=__shfl_xor(v,32);
    if(lg==0) atomicAdd(&sgf[fn*16+lr], v);
  }
  __syncthreads();
  if(t<64) atomicAdd(&gfp[b*64+t], sgf[t]);
}

// ---------------- gating MLP + top-4 softmax -> active-term list ----------
__global__ __launch_bounds__(128) void gating(const float* __restrict__ gfp,
  const float* __restrict__ g1w, const float* __restrict__ g1b,
  const float* __restrict__ bn1g, const float* __restrict__ bn1b, const float* __restrict__ bn1m, const float* __restrict__ bn1v,
  const float* __restrict__ cw1, const float* __restrict__ cb1, const float* __restrict__ cw2, const float* __restrict__ cb2,
  const float* __restrict__ g2w, const float* __restrict__ g2b,
  const float* __restrict__ bn2g, const float* __restrict__ bn2b, const float* __restrict__ bn2m, const float* __restrict__ bn2v,
  const float* __restrict__ g3w, const float* __restrict__ g3b, float2* __restrict__ act){
  __shared__ float gf[8][64];
  __shared__ float h1[8][128];
  __shared__ float a1[8][8];
  __shared__ float h2g[8][64];
  __shared__ float sc[8][16];
  int t=threadIdx.x;
  for(int i=t;i<512;i+=128) gf[i>>6][i&63]=gfp[i]*(1.0f/36864.0f);
  __syncthreads();
  for(int i=t;i<1024;i+=128){
    int b=i>>7, j=i&127;
    float s=g1b[j];
    for(int c=0;c<64;c++) s=fmaf(gf[b][c], g1w[j*64+c], s);
    s=(s-bn1m[j])*rsqrtf(bn1v[j]+1e-5f)*bn1g[j]+bn1b[j];
    h1[b][j]=gelu_f(s);
  }
  __syncthreads();
  if(t<64){
    int b=t>>3, k=t&7; float s=cb1[k];
    for(int j=0;j<128;j++) s=fmaf(h1[b][j], cw1[k*128+j], s);
    a1[b][k]=gelu_f(s);
  }
  __syncthreads();
  for(int i=t;i<1024;i+=128){
    int b=i>>7, j=i&127;
    float s=cb2[j];
    for(int k=0;k<8;k++) s=fmaf(a1[b][k], cw2[j*8+k], s);
    h1[b][j]=h1[b][j]/(1.0f+expf(-2.0f*s));
  }
  __syncthreads();
  for(int i=t;i<512;i+=128){
    int b=i>>6, j=i&63;
    float s=g2b[j];
    for(int k=0;k<128;k++) s=fmaf(h1[b][k], g2w[j*128+k], s);
    s=(s-bn2m[j])*rsqrtf(bn2v[j]+1e-5f)*bn2g[j]+bn2b[j];
    h2g[b][j]=gelu_f(s);
  }
  __syncthreads();
  {
    int b=t>>4, e=t&15;
    float s=g3b[e];
    for(int c=0;c<64;c++) s=fmaf(h2g[b][c], g3w[e*64+c], s);
    sc[b][e]=s;
  }
  __syncthreads();
  if(t<8){
    int b=t;
    float v[16];
    for(int e=0;e<16;e++) v[e]=sc[b][e];
    float vals[4]; int idx[4];
    for(int k=0;k<4;k++){
      float best=-1e30f; int bi=0;
      for(int e=0;e<16;e++) if(v[e]>best){best=v[e];bi=e;}
      vals[k]=best; idx[k]=bi; v[bi]=-1e30f;
    }
    float m=vals[0], ssum=0.f, w[4];
    for(int k=0;k<4;k++){ w[k]=expf((vals[k]-m)*0.5f); ssum+=w[k]; }
    act[b*6+0]=make_float2(0.5f, __int_as_float(0));
    act[b*6+1]=make_float2(0.5f, __int_as_float(1));
    for(int k=0;k<4;k++) act[b*6+2+k]=make_float2(w[k]/ssum, __int_as_float(2+idx[k]));
  }
}

// ---------------- fused feats-recompute + experts + residual --------------
// reads h2 (= out), recomputes feats tile in LDS, runs 6 active terms,
// writes out += expert_sum (coalesced RMW via LDS repack).
// Register-lean: per-wave-private LDS rows -> no pf buffer, no mid barriers;
// fn-outer weight loads (8 live regs instead of 32). launch_bounds(256,4)
// caps unified VGPR+AGPR at 128 -> 4 waves/SIMD.
__global__ __launch_bounds__(256,4) void final_k(const float* __restrict__ h2, const float2* __restrict__ sb,
  const unsigned short* __restrict__ wfe, const float* __restrict__ feb,
  const unsigned short* __restrict__ wall, const float* __restrict__ ball,
  const float2* __restrict__ act, float* __restrict__ out){
  __shared__ __align__(16) unsigned short A[128*72];  // gn2 tile -> feats tile -> float Fo[32][132]
  int t=threadIdx.x;
  int blk=blockIdx.x, b=blk/288, tile=blk-b*288, hw0=tile*128;
  // stage gn2(h2) tile (bf16, swizzled)
  for(int i=t;i<2048;i+=256){
    int c=i>>5, q=i&31;
    float2 s=sb[b*64+c];
    float4 v=*(const float4*)&h2[(size_t)(b*64+c)*36864 + hw0 + q*4];
    int px0=q*4, sw=((px0>>4)&3)<<3, cc=c^sw;
    A[(px0+0)*72+cc]=f2b(fmaf(v.x,s.x,s.y));
    A[(px0+1)*72+cc]=f2b(fmaf(v.y,s.x,s.y));
    A[(px0+2)*72+cc]=f2b(fmaf(v.z,s.x,s.y));
    A[(px0+3)*72+cc]=f2b(fmaf(v.w,s.x,s.y));
  }
  __syncthreads();
  int wave=t>>6, l=t&63, lr=l&15, lg=l>>4;
  int pxb=wave*32;
  // ---- recompute feats tile (wave-private rows: no barriers needed) ----
  {
    bf8v af[2][2];
    #pragma unroll
    for(int fm=0;fm<2;fm++){
      int row=pxb+fm*16+lr, sw=((row>>4)&3)<<3;
      #pragma unroll
      for(int ks=0;ks<2;ks++) af[fm][ks]=*(const bf8v*)&A[row*72+((ks*32+lg*8)^sw)];
    }
    #pragma unroll
    for(int fn=0;fn<4;fn++){
      bf8v b0=*(const bf8v*)(wfe+(fn*16+lr)*64+lg*8);
      bf8v b1=*(const bf8v*)(wfe+(fn*16+lr)*64+32+lg*8);
      float bs=feb[fn*16+lr];
      #pragma unroll
      for(int fm=0;fm<2;fm++){
        f4v acc={0.f,0.f,0.f,0.f};
        acc=MFMA(af[fm][0],b0,acc);
        acc=MFMA(af[fm][1],b1,acc);
        int swm=(((pxb+fm*16)>>4)&3)<<3;
        int cc=(fn*16+lr)^swm;
        #pragma unroll
        for(int r=0;r<4;r++)
          A[(pxb+fm*16+4*lg+r)*72+cc]=f2b(gelu_fast(acc[r]+bs));
      }
    }
  }
  // ---- expert terms (reads own rows written above; in-wave order ok) ----
  bf8v af2[2][2];
  #pragma unroll
  for(int fm=0;fm<2;fm++){
    int row=pxb+fm*16+lr, sw=((row>>4)&3)<<3;
    #pragma unroll
    for(int ks=0;ks<2;ks++) af2[fm][ks]=*(const bf8v*)&A[row*72+((ks*32+lg*8)^sw)];
  }
  float oa[2][4][4]={};
  for(int j=0;j<6;j++){
    float2 aw=act[b*6+j];
    int term=__float_as_int(aw.y);
    float g=aw.x;
    const unsigned short* wp=wall+term*4096;
    const float* bp=ball+term*64;
    #pragma unroll
    for(int fn=0;fn<4;fn++){
      bf8v b0=*(const bf8v*)(wp+(fn*16+lr)*64+lg*8);
      bf8v b1=*(const bf8v*)(wp+(fn*16+lr)*64+32+lg*8);
      float bs=bp[fn*16+lr];
      #pragma unroll
      for(int fm=0;fm<2;fm++){
        f4v acc={0.f,0.f,0.f,0.f};
        acc=MFMA(af2[fm][0],b0,acc);
        acc=MFMA(af2[fm][1],b1,acc);
        #pragma unroll
        for(int r=0;r<4;r++)
          oa[fm][fn][r]=fmaf(g, gelu_fast(acc[r]+bs), oa[fm][fn][r]);
      }
    }
  }
  // ---- coalesced output: repack via LDS, 2 halves of 32 oc ----
  float* Fo=(float*)A;          // 32*132=4224 floats fits in 4608
  #pragma unroll
  for(int half=0;half<2;half++){
    __syncthreads();
    #pragma unroll
    for(int fm=0;fm<2;fm++)
      #pragma unroll
      for(int fn2=0;fn2<2;fn2++){
        int fn=half*2+fn2;
        int ocl=fn2*16+lr;
        *(float4*)&Fo[ocl*132 + pxb + fm*16 + 4*lg] =
            make_float4(oa[fm][fn][0],oa[fm][fn][1],oa[fm][fn][2],oa[fm][fn][3]);
      }
    __syncthreads();
    for(int i=t;i<1024;i+=256){
      int ocl=i>>5, px0=(i&31)*4;
      int oc=half*32+ocl;
      size_t base=(size_t)(b*64+oc)*36864 + hw0 + px0;
      float4 rv=*(const float4*)&out[base];
      float4 ov=*(const float4*)&Fo[ocl*132+px0];
      *(float4*)&out[base]=make_float4(ov.x+rv.x,ov.y+rv.y,ov.z+rv.z,ov.w+rv.w);
    }
  }
}

extern "C" void kernel_launch(void* const* d_in, const int* in_sizes, int n_in,
                              void* d_out, int out_size, void* d_ws, size_t ws_size,
                              hipStream_t stream){
  const float* x    =(const float*)d_in[0];
  const float* gn1w =(const float*)d_in[1];
  const float* gn1b =(const float*)d_in[2];
  const float* aw1  =(const float*)d_in[3];
  const float* ab1  =(const float*)d_in[4];
  const float* aw2  =(const float*)d_in[5];
  const float* ab2  =(const float*)d_in[6];
  const float* gn2w =(const float*)d_in[7];
  const float* gn2b =(const float*)d_in[8];
  const float* few  =(const float*)d_in[9];
  const float* feb  =(const float*)d_in[10];
  const float* g1w  =(const float*)d_in[11];
  const float* g1b  =(const float*)d_in[12];
  const float* bn1g =(const float*)d_in[13];
  const float* bn1b =(const float*)d_in[14];
  const float* bn1m =(const float*)d_in[15];
  const float* bn1v =(const float*)d_in[16];
  const float* cw1  =(const float*)d_in[17];
  const float* cb1  =(const float*)d_in[18];
  const float* cw2  =(const float*)d_in[19];
  const float* cb2  =(const float*)d_in[20];
  const float* g2w  =(const float*)d_in[21];
  const float* g2b  =(const float*)d_in[22];
  const float* bn2g =(const float*)d_in[23];
  const float* bn2b =(const float*)d_in[24];
  const float* bn2m =(const float*)d_in[25];
  const float* bn2v =(const float*)d_in[26];
  const float* g3w  =(const float*)d_in[27];
  const float* g3b  =(const float*)d_in[28];
  const float* shw  =(const float*)d_in[29];
  const float* shb  =(const float*)d_in[30];
  const float* exw  =(const float*)d_in[31];
  const float* exb  =(const float*)d_in[32];

  float* out=(float*)d_out;
  float* ws=(float*)d_ws;

  // workspace layout (float offsets)
  float*  part1 = ws;                         // 1024
  float*  part2 = ws+1024;                    // 1024
  float2* sb1   = (float2*)(ws+2048);         // 512 float2
  float2* sb2   = (float2*)(ws+3072);         // 512 float2
  float2* act   = (float2*)(ws+4096);         // 48 float2
  float*  gfp   = ws+4224;                    // 512
  float*  Xm2   = ws+8192;                    // 1048576
  float*  S2    = ws+1056768;                 // 1048576
  unsigned short* Tbl  = (unsigned short*)(ws+2105344);  // 61440 shorts
  unsigned short* wall = (unsigned short*)(ws+2136064);  // 73728 shorts
  float*          ball = ws+2172928;                     // 1152
  unsigned short* wfe  = (unsigned short*)(ws+2174080);  // 4096 shorts
  const unsigned short* TBf1 = Tbl;
  const unsigned short* TBf2 = Tbl+12288;
  const unsigned short* TAi  = Tbl+36864;
  const unsigned short* TBi  = Tbl+49152;

  prep<<<64,256,0,stream>>>(shw, exw, shb, exb, few, Tbl, wall, ball, wfe, gfp);
  // AFNO on raw x (gn1 via linearity), emits gn1 stats
  fwd_dft <<<512,256,0,stream>>>(x, TBf1, TBf2, Xm2, part1);
  gn_finalize<<<1,64,0,stream>>>(part1, gn1w, gn1b, sb1);
  mode_mlp<<<256,256,0,stream>>>(Xm2, sb1, aw1, ab1, aw2, ab2, S2);
  inv_dft <<<512,256,0,stream>>>(S2, TAi, TBi, x, sb1, out, part2);  // h2 in d_out + gn2 stats
  gn_finalize<<<1,64,0,stream>>>(part2, gn2w, gn2b, sb2);
  // gating means (no feats materialization)
  gf_k<<<2304,256,0,stream>>>(out, sb2, wfe, feb, gfp);
  gating <<<1,128,0,stream>>>(gfp, g1w,g1b, bn1g,bn1b,bn1m,bn1v,
                              cw1,cb1,cw2,cb2, g2w,g2b, bn2g,bn2b,bn2m,bn2v,
                              g3w,g3b, act);
  // fused feats-recompute + shared/active experts + residual (in-place on d_out)
  final_k<<<2304,256,0,stream>>>(out, sb2, wfe, feb, wall, ball, act, out);
}

// Round 8
// 223.927 us; speedup vs baseline: 3.5483x; 1.0242x over previous
//
#include <hip/hip_runtime.h>
#include <math.h>

// Problem constants: B=8, C=64, H=W=192, HW=36864, MODES=32, NB=4, BS=16, E=16
#define TPI 6.283185307179586f

typedef __attribute__((ext_vector_type(8))) short bf8v;   // 8 bf16 (4 VGPRs)
typedef __attribute__((ext_vector_type(4))) float f4v;    // 4 fp32 acc

#define MFMA(a,b,c) __builtin_amdgcn_mfma_f32_16x16x32_bf16((a),(b),(c),0,0,0)

__device__ __forceinline__ float gelu_f(float v){          // exact (erf)
  return 0.5f*v*(1.0f+erff(v*0.7071067811865475f));
}
// tanh-form gelu via fast exp + fast rcp (no IEEE div): err ~5e-4 abs
__device__ __forceinline__ float gelu_fast(float x){
  float x2=x*x;
  float inner=fmaf(0.044715f*x2, x, x);
  float e=__expf(1.5957691216057308f*inner);   // exp(2*0.7978845608*inner)
  float r=__builtin_amdgcn_rcpf(1.0f+e);
  return fmaf(-x, r, x);                        // x*(1-r)
}
// sigmoid-form gelu: x*sigmoid(1.702x). 3 VALU + 2 trans; err <= ~0.0203 abs
__device__ __forceinline__ float gelu_sig(float x){
  float e=__expf(-1.702f*x);
  return x*__builtin_amdgcn_rcpf(1.0f+e);
}
__device__ __forceinline__ unsigned short f2b(float f){   // f32 -> bf16 (RNE)
  union{float f; unsigned u;} v; v.f=f;
  unsigned r=v.u + 0x7FFFu + ((v.u>>16)&1u);
  return (unsigned short)(r>>16);
}

// ---------------- prep: twiddle tables + bf16 weights + zero gfp -----------
__global__ __launch_bounds__(256) void prep(const float* __restrict__ shw, const float* __restrict__ exw,
    const float* __restrict__ shb, const float* __restrict__ exb, const float* __restrict__ few,
    unsigned short* __restrict__ T, unsigned short* __restrict__ wall, float* __restrict__ ball,
    unsigned short* __restrict__ wfe, float* __restrict__ gfp){
  const float a = TPI/192.0f;
  int stride=gridDim.x*256;
  for(int i=blockIdx.x*256+threadIdx.x; i<61440; i+=stride){
    float v;
    if(i<12288){
      int n1=i/192, w=i%192; int kw=n1>>1, c=n1&1;
      int m=(kw*w)%192; float cs,sn; sincosf((float)m*a,&sn,&cs);
      v = c ? -sn : cs;
    } else if(i<36864){
      int j=i-12288; int n1=j/384, k1=j%384; int kh=n1>>1, d=n1&1; int h=k1>>1, c=k1&1;
      int m=(kh*h)%192; float cs,sn; sincosf((float)m*a,&sn,&cs);
      float e = d ? (c ? cs : -sn) : (c ? sn : cs);
      v = e*(1.0f/192.0f);
    } else if(i<49152){
      int j=i-36864; int h=j/64, k1=j%64; int kh=k1>>1, c=k1&1;
      int m=(h*kh)%192; float cs,sn; sincosf((float)m*a,&sn,&cs);
      v = c ? sn : cs;
    } else {
      int j=i-49152; int w=j/64, k1=j%64; int kw=k1>>1, d=k1&1;
      float f = kw ? (2.0f/192.0f) : (1.0f/192.0f);
      int m=(w*kw)%192; float cs,sn; sincosf((float)m*a,&sn,&cs);
      v = d ? -f*sn : f*cs;
    }
    T[i]=f2b(v);
  }
  for(int i=blockIdx.x*256+threadIdx.x;i<73728;i+=stride) wall[i]=f2b(i<8192?shw[i]:exw[i-8192]);
  for(int i=blockIdx.x*256+threadIdx.x;i<1152;i+=stride)  ball[i]=(i<128)?shb[i]:exb[i-128];
  for(int i=blockIdx.x*256+threadIdx.x;i<4096;i+=stride)  wfe[i]=f2b(few[i]);
  for(int i=blockIdx.x*256+threadIdx.x;i<512;i+=stride)   gfp[i]=0.f;
}

__global__ void gn_finalize(const float* __restrict__ part, const float* __restrict__ gw,
                            const float* __restrict__ gb, float2* __restrict__ sb){
  int g=threadIdx.x; if(g>=64) return;
  float S=0,SS=0;
  for(int j=0;j<8;j++){ S+=part[(g*8+j)*2]; SS+=part[(g*8+j)*2+1]; }
  const float inv=1.0f/294912.0f;
  float mean=S*inv, var=SS*inv-mean*mean;
  float rstd=rsqrtf(var+1e-5f);
  int b=g>>3, gg=g&7;
  for(int k=0;k<8;k++){
    int c=gg*8+k;
    float sc=rstd*gw[c];
    sb[b*64+c]=make_float2(sc, gb[c]-mean*sc);
  }
}

// ---------------- fwd DFT on RAW x (gn1 folded out via linearity) ---------
__global__ __launch_bounds__(256) void fwd_dft(const float* __restrict__ x,
      const unsigned short* __restrict__ TBf1, const unsigned short* __restrict__ TBf2,
      float* __restrict__ Xm2, float* __restrict__ part1){
  __shared__ __align__(16) unsigned short ldsA[64*200];  // Bt1 [64][200]; later tL [32][392]
  __shared__ __align__(16) float sX[2048];
  __shared__ float red[8];
  int t=threadIdx.x, bc=blockIdx.x;
  int wave=t>>6, l=t&63, lr=l&15, lg=l>>4;
  const float* xch = x + (size_t)bc*36864;
  for(int i=t;i<1536;i+=256){
    int row=i/24, chunk=i%24;
    *(uint4*)&ldsA[row*200 + chunk*8] = *(const uint4*)(TBf1 + row*192 + chunk*8);
  }
  __syncthreads();
  float s_=0.f, ss_=0.f;
  // ---- stage 1 ----
  f4v acc1[3][4];
  for(int mt=0;mt<3;mt++){
    int m0=(wave+mt*4)*16;
    const float* xrow = xch + (m0+lr)*192 + lg*8;
    bf8v af[6];
    #pragma unroll
    for(int ks=0;ks<6;ks++){
      float4 u0=*(const float4*)(xrow+ks*32);
      float4 u1=*(const float4*)(xrow+ks*32+4);
      s_ += u0.x+u0.y+u0.z+u0.w+u1.x+u1.y+u1.z+u1.w;
      ss_+= u0.x*u0.x+u0.y*u0.y+u0.z*u0.z+u0.w*u0.w
           +u1.x*u1.x+u1.y*u1.y+u1.z*u1.z+u1.w*u1.w;
      bf8v a;
      a[0]=(short)f2b(u0.x); a[1]=(short)f2b(u0.y); a[2]=(short)f2b(u0.z); a[3]=(short)f2b(u0.w);
      a[4]=(short)f2b(u1.x); a[5]=(short)f2b(u1.y); a[6]=(short)f2b(u1.z); a[7]=(short)f2b(u1.w);
      af[ks]=a;
    }
    #pragma unroll
    for(int nt=0;nt<4;nt++){
      f4v acc={0.f,0.f,0.f,0.f};
      #pragma unroll
      for(int ks=0;ks<6;ks++){
        bf8v b=*(const bf8v*)&ldsA[(nt*16+lr)*200 + ks*32 + lg*8];
        acc=MFMA(af[ks],b,acc);
      }
      acc1[mt][nt]=acc;
    }
  }
  __syncthreads();            // reuse ldsA as tL [32][392]
  for(int mt=0;mt<3;mt++){
    int m0=(wave+mt*4)*16;
    #pragma unroll
    for(int nt=0;nt<4;nt++){
      int n1=nt*16+lr; int kw=n1>>1, c=n1&1;
      #pragma unroll
      for(int reg=0;reg<4;reg++){
        int h=m0+4*lg+reg;
        ldsA[kw*392 + 2*h + c]=f2b(acc1[mt][nt][reg]);
      }
    }
  }
  __syncthreads();
  // ---- stage 2 ----
  for(int pp=0;pp<2;pp++){
    int p=wave+pp*4;
    int m0=(p>>2)*16, n0=(p&3)*16;
    f4v acc={0.f,0.f,0.f,0.f};
    #pragma unroll
    for(int ks=0;ks<12;ks++){
      bf8v a=*(const bf8v*)&ldsA[(m0+lr)*392 + ks*32 + lg*8];
      bf8v b=*(const bf8v*)(TBf2 + (n0+lr)*384 + ks*32 + lg*8);
      acc=MFMA(a,b,acc);
    }
    int n1=n0+lr; int kh=n1>>1, d=n1&1;
    #pragma unroll
    for(int reg=0;reg<4;reg++){
      int kw=m0+4*lg+reg;
      sX[(kh*32+kw)*2 + d]=acc[reg];
    }
  }
  __syncthreads();
  float* dst=Xm2+(size_t)bc*2048;
  for(int i=t;i<512;i+=256) *(float4*)(dst+i*4)=*(const float4*)(sX+i*4);
  // ---- gn1 stats ----
  #pragma unroll
  for(int o=32;o>0;o>>=1){ s_+=__shfl_down(s_,o); ss_+=__shfl_down(ss_,o); }
  if(l==0){ red[wave]=s_; red[4+wave]=ss_; }
  __syncthreads();
  if(t==0){
    part1[bc*2]  =red[0]+red[1]+red[2]+red[3];
    part1[bc*2+1]=red[4]+red[5]+red[6]+red[7];
  }
}

// ---------------- block-diagonal complex 2-layer MLP on modes -------------
__global__ __launch_bounds__(256) void mode_mlp(const float* __restrict__ Xm2, const float2* __restrict__ sb1,
    const float* __restrict__ w1, const float* __restrict__ b1,
    const float* __restrict__ w2, const float* __restrict__ b2,
    float* __restrict__ S2){
  __shared__ float w10[1024], w11[1024], w20[1024], w21[1024];
  __shared__ float b10[64], b11[64], b20[64], b21[64];
  __shared__ float2 sbl[64];
  __shared__ float xr[32][64], xi[32][64];
  __shared__ float o1r[32][64], o1i[32][64];
  int t=threadIdx.x;
  int b=blockIdx.x>>5, kh=blockIdx.x&31;
  for(int i=t;i<1024;i+=256){ w10[i]=w1[i]; w11[i]=w1[1024+i]; w20[i]=w2[i]; w21[i]=w2[1024+i]; }
  if(t<64){ b10[t]=b1[t]; b11[t]=b1[64+t]; b20[t]=b2[t]; b21[t]=b2[64+t]; sbl[t]=sb1[b*64+t]; }
  __syncthreads();
  for(int q=0;q<16;q++){
    int idx=q*256+t; int c=idx>>6, jj=idx&63;
    float2 s=sbl[c];
    float v=Xm2[((size_t)(b*64+c))*2048 + kh*64 + jj]*s.x;
    if(kh==0 && jj==0) v += 192.0f*s.y;
    if(jj&1) xi[jj>>1][c]=v; else xr[jj>>1][c]=v;
  }
  __syncthreads();
  int tl=t&63, n=tl>>4, o=tl&15, wb=n*256+o;
  #pragma unroll
  for(int it=0;it<8;it++){
    int kw=(t>>6)+it*4;
    float a_r=b10[tl], a_i=b11[tl];
    #pragma unroll
    for(int i=0;i<16;i++){
      float rr=xr[kw][n*16+i], im=xi[kw][n*16+i];
      float W0=w10[wb+i*16], W1=w11[wb+i*16];
      a_r=fmaf(rr,W0,fmaf(-im,W1,a_r));
      a_i=fmaf(im,W0,fmaf( rr,W1,a_i));
    }
    o1r[kw][tl]=gelu_f(a_r); o1i[kw][tl]=gelu_f(a_i);
  }
  __syncthreads();
  #pragma unroll
  for(int it=0;it<8;it++){
    int kw=(t>>6)+it*4;
    float c_r=b20[tl], c_i=b21[tl];
    #pragma unroll
    for(int i=0;i<16;i++){
      float rr=o1r[kw][n*16+i], im=o1i[kw][n*16+i];
      float W0=w20[wb+i*16], W1=w21[wb+i*16];
      c_r=fmaf(rr,W0,fmaf(-im,W1,c_r));
      c_i=fmaf(im,W0,fmaf( rr,W1,c_i));
    }
    xr[kw][tl]=c_r; xi[kw][tl]=c_i;
  }
  __syncthreads();
  for(int q=0;q<16;q++){
    int idx=q*256+t; int c=idx>>6, jj=idx&63;
    float v = (jj&1) ? xi[jj>>1][c] : xr[jj>>1][c];
    S2[((size_t)(b*64+c))*2048 + kh*64 + jj]=v;
  }
}

// ---------------- inverse DFT + residuals + gn2 stats ---------------------
__global__ __launch_bounds__(256) void inv_dft(const float* __restrict__ S2,
      const unsigned short* __restrict__ TAi, const unsigned short* __restrict__ TBi,
      const float* __restrict__ x, const float2* __restrict__ sb,
      float* __restrict__ h2, float* __restrict__ part2){
  __shared__ __align__(16) unsigned short Bs[64*72];
  __shared__ __align__(16) unsigned short GL[192*72];
  __shared__ float red[8];
  int t=threadIdx.x, bc=blockIdx.x;
  int wave=t>>6, l=t&63, lr=l&15, lg=l>>4;
  const float* sp=S2+(size_t)bc*2048;
  for(int i=t;i<1024;i+=256){
    int kh=i>>5, kw=i&31;
    float Sr=sp[(kh*32+kw)*2], Si=sp[(kh*32+kw)*2+1];
    unsigned short br=f2b(Sr), bi_=f2b(Si), nbi=f2b(-Si);
    Bs[(2*kw+0)*72 + 2*kh+0]=br;
    Bs[(2*kw+0)*72 + 2*kh+1]=nbi;
    Bs[(2*kw+1)*72 + 2*kh+0]=bi_;
    Bs[(2*kw+1)*72 + 2*kh+1]=br;
  }
  __syncthreads();
  for(int mt=0;mt<3;mt++){
    int m0=(wave+mt*4)*16;
    bf8v a0=*(const bf8v*)(TAi + (m0+lr)*64 + lg*8);
    bf8v a1=*(const bf8v*)(TAi + (m0+lr)*64 + 32 + lg*8);
    #pragma unroll
    for(int nt=0;nt<4;nt++){
      f4v acc={0.f,0.f,0.f,0.f};
      bf8v b0=*(const bf8v*)&Bs[(nt*16+lr)*72 + lg*8];
      bf8v b1=*(const bf8v*)&Bs[(nt*16+lr)*72 + 32 + lg*8];
      acc=MFMA(a0,b0,acc); acc=MFMA(a1,b1,acc);
      #pragma unroll
      for(int reg=0;reg<4;reg++)
        GL[(m0+4*lg+reg)*72 + nt*16+lr]=f2b(acc[reg]);
    }
  }
  __syncthreads();
  float2 sv=sb[bc];
  float cA=sv.x+1.0f, cB=sv.y;
  asm volatile("" : "+v"(cA), "+v"(cB));   // pin to VGPR (constant-bus fix)
  const float* xch=x+(size_t)bc*36864;
  float* och=h2+(size_t)bc*36864;
  float s_=0.f, ss_=0.f;
  for(int mt=0;mt<3;mt++){
    int m0=(wave+mt*4)*16;
    bf8v a0=*(const bf8v*)&GL[(m0+lr)*72 + lg*8];
    bf8v a1=*(const bf8v*)&GL[(m0+lr)*72 + 32 + lg*8];
    for(int nt=0;nt<12;nt++){
      int n0=nt*16;
      f4v acc={0.f,0.f,0.f,0.f};
      bf8v b0=*(const bf8v*)(TBi + (n0+lr)*64 + lg*8);
      bf8v b1=*(const bf8v*)(TBi + (n0+lr)*64 + 32 + lg*8);
      acc=MFMA(a0,b0,acc); acc=MFMA(a1,b1,acc);
      int w=n0+lr;
      #pragma unroll
      for(int reg=0;reg<4;reg++){
        int h=m0+4*lg+reg;
        int ga=h*192+w;
        float xv=xch[ga];
        float val=acc[reg]+fmaf(cA,xv,cB);
        och[ga]=val;
        s_+=val; ss_+=val*val;
      }
    }
  }
  #pragma unroll
  for(int o=32;o>0;o>>=1){ s_+=__shfl_down(s_,o); ss_+=__shfl_down(ss_,o); }
  if(l==0){ red[wave]=s_; red[4+wave]=ss_; }
  __syncthreads();
  if(t==0){
    part2[bc*2]  =red[0]+red[1]+red[2]+red[3];
    part2[bc*2+1]=red[4]+red[5]+red[6]+red[7];
  }
}

// ---------------- gf_k: gating means only (no feats materialization) ------
__global__ __launch_bounds__(256,4) void gf_k(const float* __restrict__ h2, const float2* __restrict__ sb,
    const unsigned short* __restrict__ wfe, const float* __restrict__ feb,
    float* __restrict__ gfp){
  __shared__ __align__(16) unsigned short A[128*72];
  __shared__ float sgf[64];
  int t=threadIdx.x;
  int blk=blockIdx.x, b=blk/288, tile=blk-b*288, hw0=tile*128;
  if(t<64) sgf[t]=0.f;
  for(int i=t;i<2048;i+=256){
    int c=i>>5, q=i&31;
    float2 s=sb[b*64+c];
    float4 v=*(const float4*)&h2[(size_t)(b*64+c)*36864 + hw0 + q*4];
    int px0=q*4, sw=((px0>>4)&3)<<3, cc=c^sw;
    A[(px0+0)*72+cc]=f2b(fmaf(v.x,s.x,s.y));
    A[(px0+1)*72+cc]=f2b(fmaf(v.y,s.x,s.y));
    A[(px0+2)*72+cc]=f2b(fmaf(v.z,s.x,s.y));
    A[(px0+3)*72+cc]=f2b(fmaf(v.w,s.x,s.y));
  }
  __syncthreads();
  int wave=t>>6, l=t&63, lr=l&15, lg=l>>4;
  int pxb=wave*32;
  bf8v af[2][2];
  #pragma unroll
  for(int fm=0;fm<2;fm++){
    int row=pxb+fm*16+lr, sw=((row>>4)&3)<<3;
    #pragma unroll
    for(int ks=0;ks<2;ks++) af[fm][ks]=*(const bf8v*)&A[row*72+((ks*32+lg*8)^sw)];
  }
  float gsum[4]={0.f,0.f,0.f,0.f};
  #pragma unroll
  for(int fn=0;fn<4;fn++){
    bf8v b0=*(const bf8v*)(wfe+(fn*16+lr)*64+lg*8);
    bf8v b1=*(const bf8v*)(wfe+(fn*16+lr)*64+32+lg*8);
    float bs=feb[fn*16+lr];
    #pragma unroll
    for(int fm=0;fm<2;fm++){
      f4v acc={0.f,0.f,0.f,0.f};
      acc=MFMA(af[fm][0],b0,acc);
      acc=MFMA(af[fm][1],b1,acc);
      #pragma unroll
      for(int r=0;r<4;r++) gsum[fn]+=gelu_fast(acc[r]+bs);
    }
  }
  #pragma unroll
  for(int fn=0;fn<4;fn++){
    float v=gsum[fn];
    v+=__shfl_xor(v,16); v+=__shfl_xor(v,32);
    if(lg==0) atomicAdd(&sgf[fn*16+lr], v);
  }
  __syncthreads();
  if(t<64) atomicAdd(&gfp[b*64+t], sgf[t]);
}

// ---------------- gating MLP + top-4 softmax -> active-term list ----------
__global__ __launch_bounds__(128) void gating(const float* __restrict__ gfp,
  const float* __restrict__ g1w, const float* __restrict__ g1b,
  const float* __restrict__ bn1g, const float* __restrict__ bn1b, const float* __restrict__ bn1m, const float* __restrict__ bn1v,
  const float* __restrict__ cw1, const float* __restrict__ cb1, const float* __restrict__ cw2, const float* __restrict__ cb2,
  const float* __restrict__ g2w, const float* __restrict__ g2b,
  const float* __restrict__ bn2g, const float* __restrict__ bn2b, const float* __restrict__ bn2m, const float* __restrict__ bn2v,
  const float* __restrict__ g3w, const float* __restrict__ g3b, float2* __restrict__ act){
  __shared__ float gf[8][64];
  __shared__ float h1[8][128];
  __shared__ float a1[8][8];
  __shared__ float h2g[8][64];
  __shared__ float sc[8][16];
  int t=threadIdx.x;
  for(int i=t;i<512;i+=128) gf[i>>6][i&63]=gfp[i]*(1.0f/36864.0f);
  __syncthreads();
  for(int i=t;i<1024;i+=128){
    int b=i>>7, j=i&127;
    float s=g1b[j];
    for(int c=0;c<64;c++) s=fmaf(gf[b][c], g1w[j*64+c], s);
    s=(s-bn1m[j])*rsqrtf(bn1v[j]+1e-5f)*bn1g[j]+bn1b[j];
    h1[b][j]=gelu_f(s);
  }
  __syncthreads();
  if(t<64){
    int b=t>>3, k=t&7; float s=cb1[k];
    for(int j=0;j<128;j++) s=fmaf(h1[b][j], cw1[k*128+j], s);
    a1[b][k]=gelu_f(s);
  }
  __syncthreads();
  for(int i=t;i<1024;i+=128){
    int b=i>>7, j=i&127;
    float s=cb2[j];
    for(int k=0;k<8;k++) s=fmaf(a1[b][k], cw2[j*8+k], s);
    h1[b][j]=h1[b][j]/(1.0f+expf(-2.0f*s));
  }
  __syncthreads();
  for(int i=t;i<512;i+=128){
    int b=i>>6, j=i&63;
    float s=g2b[j];
    for(int k=0;k<128;k++) s=fmaf(h1[b][k], g2w[j*128+k], s);
    s=(s-bn2m[j])*rsqrtf(bn2v[j]+1e-5f)*bn2g[j]+bn2b[j];
    h2g[b][j]=gelu_f(s);
  }
  __syncthreads();
  {
    int b=t>>4, e=t&15;
    float s=g3b[e];
    for(int c=0;c<64;c++) s=fmaf(h2g[b][c], g3w[e*64+c], s);
    sc[b][e]=s;
  }
  __syncthreads();
  if(t<8){
    int b=t;
    float v[16];
    for(int e=0;e<16;e++) v[e]=sc[b][e];
    float vals[4]; int idx[4];
    for(int k=0;k<4;k++){
      float best=-1e30f; int bi=0;
      for(int e=0;e<16;e++) if(v[e]>best){best=v[e];bi=e;}
      vals[k]=best; idx[k]=bi; v[bi]=-1e30f;
    }
    float m=vals[0], ssum=0.f, w[4];
    for(int k=0;k<4;k++){ w[k]=expf((vals[k]-m)*0.5f); ssum+=w[k]; }
    act[b*6+0]=make_float2(0.5f, __int_as_float(0));
    act[b*6+1]=make_float2(0.5f, __int_as_float(1));
    for(int k=0;k<4;k++) act[b*6+2+k]=make_float2(w[k]/ssum, __int_as_float(2+idx[k]));
  }
}

// ---------------- fused feats-recompute + experts + residual --------------
// Term loop moved INSIDE the oc-half loop: oa[2][2][4] = 16 regs (was 32),
// unified VGPR+AGPR ~100 -> 4-5 waves/SIMD. Expert gelu = sigmoid form.
__global__ __launch_bounds__(256,4) void final_k(const float* __restrict__ h2, const float2* __restrict__ sb,
  const unsigned short* __restrict__ wfe, const float* __restrict__ feb,
  const unsigned short* __restrict__ wall, const float* __restrict__ ball,
  const float2* __restrict__ act, float* __restrict__ out){
  __shared__ __align__(16) unsigned short A[128*72];  // gn2 tile -> feats tile -> float Fo[32][132]
  int t=threadIdx.x;
  int blk=blockIdx.x, b=blk/288, tile=blk-b*288, hw0=tile*128;
  // stage gn2(h2) tile (bf16, swizzled)
  for(int i=t;i<2048;i+=256){
    int c=i>>5, q=i&31;
    float2 s=sb[b*64+c];
    float4 v=*(const float4*)&h2[(size_t)(b*64+c)*36864 + hw0 + q*4];
    int px0=q*4, sw=((px0>>4)&3)<<3, cc=c^sw;
    A[(px0+0)*72+cc]=f2b(fmaf(v.x,s.x,s.y));
    A[(px0+1)*72+cc]=f2b(fmaf(v.y,s.x,s.y));
    A[(px0+2)*72+cc]=f2b(fmaf(v.z,s.x,s.y));
    A[(px0+3)*72+cc]=f2b(fmaf(v.w,s.x,s.y));
  }
  __syncthreads();
  int wave=t>>6, l=t&63, lr=l&15, lg=l>>4;
  int pxb=wave*32;
  // ---- recompute feats tile (wave-private rows: no barriers needed) ----
  {
    bf8v af[2][2];
    #pragma unroll
    for(int fm=0;fm<2;fm++){
      int row=pxb+fm*16+lr, sw=((row>>4)&3)<<3;
      #pragma unroll
      for(int ks=0;ks<2;ks++) af[fm][ks]=*(const bf8v*)&A[row*72+((ks*32+lg*8)^sw)];
    }
    #pragma unroll
    for(int fn=0;fn<4;fn++){
      bf8v b0=*(const bf8v*)(wfe+(fn*16+lr)*64+lg*8);
      bf8v b1=*(const bf8v*)(wfe+(fn*16+lr)*64+32+lg*8);
      float bs=feb[fn*16+lr];
      #pragma unroll
      for(int fm=0;fm<2;fm++){
        f4v acc={0.f,0.f,0.f,0.f};
        acc=MFMA(af[fm][0],b0,acc);
        acc=MFMA(af[fm][1],b1,acc);
        int swm=(((pxb+fm*16)>>4)&3)<<3;
        int cc=(fn*16+lr)^swm;
        #pragma unroll
        for(int r=0;r<4;r++)
          A[(pxb+fm*16+4*lg+r)*72+cc]=f2b(gelu_fast(acc[r]+bs));
      }
    }
  }
  // ---- feats fragments (own rows; in-wave LDS order ok, no barrier) ----
  bf8v af2[2][2];
  #pragma unroll
  for(int fm=0;fm<2;fm++){
    int row=pxb+fm*16+lr, sw=((row>>4)&3)<<3;
    #pragma unroll
    for(int ks=0;ks<2;ks++) af2[fm][ks]=*(const bf8v*)&A[row*72+((ks*32+lg*8)^sw)];
  }
  // ---- per oc-half: 6 terms -> repack -> coalesced RMW ----
  float* Fo=(float*)A;          // 32*132=4224 floats fits in 4608
  #pragma unroll
  for(int half=0;half<2;half++){
    float oa[2][2][4]={};       // [fm][fn2][r] -- 16 regs
    for(int j=0;j<6;j++){
      float2 aw=act[b*6+j];
      int term=__float_as_int(aw.y);
      float g=aw.x;
      const unsigned short* wp=wall+term*4096;
      const float* bp=ball+term*64;
      #pragma unroll
      for(int fn2=0;fn2<2;fn2++){
        int fn=half*2+fn2;
        bf8v b0=*(const bf8v*)(wp+(fn*16+lr)*64+lg*8);
        bf8v b1=*(const bf8v*)(wp+(fn*16+lr)*64+32+lg*8);
        float bs=bp[fn*16+lr];
        #pragma unroll
        for(int fm=0;fm<2;fm++){
          f4v acc={0.f,0.f,0.f,0.f};
          acc=MFMA(af2[fm][0],b0,acc);
          acc=MFMA(af2[fm][1],b1,acc);
          #pragma unroll
          for(int r=0;r<4;r++)
            oa[fm][fn2][r]=fmaf(g, gelu_sig(acc[r]+bs), oa[fm][fn2][r]);
        }
      }
    }
    __syncthreads();            // feats reads (all waves) done; Fo may clobber A
    #pragma unroll
    for(int fm=0;fm<2;fm++)
      #pragma unroll
      for(int fn2=0;fn2<2;fn2++){
        int ocl=fn2*16+lr;
        *(float4*)&Fo[ocl*132 + pxb + fm*16 + 4*lg] =
            make_float4(oa[fm][fn2][0],oa[fm][fn2][1],oa[fm][fn2][2],oa[fm][fn2][3]);
      }
    __syncthreads();
    for(int i=t;i<1024;i+=256){
      int ocl=i>>5, px0=(i&31)*4;
      int oc=half*32+ocl;
      size_t base=(size_t)(b*64+oc)*36864 + hw0 + px0;
      float4 rv=*(const float4*)&out[base];
      float4 ov=*(const float4*)&Fo[ocl*132+px0];
      *(float4*)&out[base]=make_float4(ov.x+rv.x,ov.y+rv.y,ov.z+rv.z,ov.w+rv.w);
    }
  }
}

extern "C" void kernel_launch(void* const* d_in, const int* in_sizes, int n_in,
                              void* d_out, int out_size, void* d_ws, size_t ws_size,
                              hipStream_t stream){
  const float* x    =(const float*)d_in[0];
  const float* gn1w =(const float*)d_in[1];
  const float* gn1b =(const float*)d_in[2];
  const float* aw1  =(const float*)d_in[3];
  const float* ab1  =(const float*)d_in[4];
  const float* aw2  =(const float*)d_in[5];
  const float* ab2  =(const float*)d_in[6];
  const float* gn2w =(const float*)d_in[7];
  const float* gn2b =(const float*)d_in[8];
  const float* few  =(const float*)d_in[9];
  const float* feb  =(const float*)d_in[10];
  const float* g1w  =(const float*)d_in[11];
  const float* g1b  =(const float*)d_in[12];
  const float* bn1g =(const float*)d_in[13];
  const float* bn1b =(const float*)d_in[14];
  const float* bn1m =(const float*)d_in[15];
  const float* bn1v =(const float*)d_in[16];
  const float* cw1  =(const float*)d_in[17];
  const float* cb1  =(const float*)d_in[18];
  const float* cw2  =(const float*)d_in[19];
  const float* cb2  =(const float*)d_in[20];
  const float* g2w  =(const float*)d_in[21];
  const float* g2b  =(const float*)d_in[22];
  const float* bn2g =(const float*)d_in[23];
  const float* bn2b =(const float*)d_in[24];
  const float* bn2m =(const float*)d_in[25];
  const float* bn2v =(const float*)d_in[26];
  const float* g3w  =(const float*)d_in[27];
  const float* g3b  =(const float*)d_in[28];
  const float* shw  =(const float*)d_in[29];
  const float* shb  =(const float*)d_in[30];
  const float* exw  =(const float*)d_in[31];
  const float* exb  =(const float*)d_in[32];

  float* out=(float*)d_out;
  float* ws=(float*)d_ws;

  // workspace layout (float offsets)
  float*  part1 = ws;                         // 1024
  float*  part2 = ws+1024;                    // 1024
  float2* sb1   = (float2*)(ws+2048);         // 512 float2
  float2* sb2   = (float2*)(ws+3072);         // 512 float2
  float2* act   = (float2*)(ws+4096);         // 48 float2
  float*  gfp   = ws+4224;                    // 512
  float*  Xm2   = ws+8192;                    // 1048576
  float*  S2    = ws+1056768;                 // 1048576
  unsigned short* Tbl  = (unsigned short*)(ws+2105344);  // 61440 shorts
  unsigned short* wall = (unsigned short*)(ws+2136064);  // 73728 shorts
  float*          ball = ws+2172928;                     // 1152
  unsigned short* wfe  = (unsigned short*)(ws+2174080);  // 4096 shorts
  const unsigned short* TBf1 = Tbl;
  const unsigned short* TBf2 = Tbl+12288;
  const unsigned short* TAi  = Tbl+36864;
  const unsigned short* TBi  = Tbl+49152;

  prep<<<64,256,0,stream>>>(shw, exw, shb, exb, few, Tbl, wall, ball, wfe, gfp);
  // AFNO on raw x (gn1 via linearity), emits gn1 stats
  fwd_dft <<<512,256,0,stream>>>(x, TBf1, TBf2, Xm2, part1);
  gn_finalize<<<1,64,0,stream>>>(part1, gn1w, gn1b, sb1);
  mode_mlp<<<256,256,0,stream>>>(Xm2, sb1, aw1, ab1, aw2, ab2, S2);
  inv_dft <<<512,256,0,stream>>>(S2, TAi, TBi, x, sb1, out, part2);  // h2 in d_out + gn2 stats
  gn_finalize<<<1,64,0,stream>>>(part2, gn2w, gn2b, sb2);
  // gating means (no feats materialization)
  gf_k<<<2304,256,0,stream>>>(out, sb2, wfe, feb, gfp);
  gating <<<1,128,0,stream>>>(gfp, g1w,g1b, bn1g,bn1b,bn1m,bn1v,
                              cw1,cb1,cw2,cb2, g2w,g2b, bn2g,bn2b,bn2m,bn2v,
                              g3w,g3b, act);
  // fused feats-recompute + shared/active experts + residual (in-place on d_out)
  final_k<<<2304,256,0,stream>>>(out, sb2, wfe, feb, wall, ball, act, out);
}